// Round 4
// baseline (2829.657 us; speedup 1.0000x reference)
//
#include <hip/hip_runtime.h>
#include <math.h>

#define BATCH 8
#define LSEQ 512
#define LAGENT 256
#define DMODEL 512
#define DINNER 1024
#define DSTATE 16
#define DTRANK 32
#define NHEAD 4
#define DHEAD 128
#define NLANES 6

typedef __attribute__((ext_vector_type(8))) short bf16x8;
typedef __attribute__((ext_vector_type(4))) float f32x4;

// Exact 3-way bf16 split: x = h + m + l + O(2^-24 |x|); all subtractions exact.
__device__ __forceinline__ void split3(float x, short& h, short& m, short& l)
{
    unsigned hb = __float_as_uint(x) & 0xFFFF0000u;
    h = (short)(hb >> 16);
    float r1 = x - __uint_as_float(hb);
    unsigned mb = __float_as_uint(r1) & 0xFFFF0000u;
    m = (short)(mb >> 16);
    float r2 = r1 - __uint_as_float(mb);
    l = (short)(__float_as_uint(r2) >> 16);
}

// ---------------- bf16x6 emulated-fp32 MFMA GEMM ----------------
// C[M,N] = act(A[M,K](lda) @ W[K,N] + bias) (+C if addC); BN=128 fixed.
// act: 0 = none, 1 = softplus
template<int BM, int WM, int WN>
__global__ __launch_bounds__(256)
void gemm_mfma(const float* __restrict__ A, int lda,
               const float* __restrict__ W,
               const float* __restrict__ bias,
               float* __restrict__ C, int ldc,
               int M, int N, int K, int act, int addC)
{
    constexpr int BN = 128;
    constexpr int MT = BM / WM / 16;   // m-frags per wave
    constexpr int NT = BN / WN / 16;   // n-frags per wave
    __shared__ short As[3][BM][32];    // [plane][m][k]
    __shared__ short Bs[3][BN][32];    // [plane][n][k]  (W transposed into LDS)
    const int tid = threadIdx.x;
    const int w = tid >> 6, lane = tid & 63;
    const int lrow = lane & 15, quad = lane >> 4;
    const int wm = (w % WM) * (BM / WM);
    const int wn = (w / WM) * (BN / WN);
    const int m0 = blockIdx.y * BM, n0 = blockIdx.x * BN;

    f32x4 acc[MT][NT] = {};

    for (int k0 = 0; k0 < K; k0 += 32) {
        __syncthreads();
        // ---- stage A tile (BM x 32), split into 3 bf16 planes ----
        {
            int kq = (tid & 7) * 4;
            int row = tid >> 3;           // 0..31
#pragma unroll
            for (int i = 0; i < BM / 32; ++i) {
                int r = row + 32 * i;
                float4 v = *(const float4*)&A[(size_t)(m0 + r) * lda + k0 + kq];
                short h[4], mm_[4], l[4];
                split3(v.x, h[0], mm_[0], l[0]);
                split3(v.y, h[1], mm_[1], l[1]);
                split3(v.z, h[2], mm_[2], l[2]);
                split3(v.w, h[3], mm_[3], l[3]);
                *(short4*)&As[0][r][kq] = make_short4(h[0], h[1], h[2], h[3]);
                *(short4*)&As[1][r][kq] = make_short4(mm_[0], mm_[1], mm_[2], mm_[3]);
                *(short4*)&As[2][r][kq] = make_short4(l[0], l[1], l[2], l[3]);
            }
        }
        // ---- stage B tile (32 x 128) transposed to [n][k], 3 planes ----
        {
            int nc = (tid & 31) * 4;
            int kk = (tid >> 5) * 2;      // 0,2,..,14
#pragma unroll
            for (int i = 0; i < 2; ++i) {
                int k1 = kk + 16 * i;
                float4 v0 = *(const float4*)&W[(size_t)(k0 + k1) * N + n0 + nc];
                float4 v1 = *(const float4*)&W[(size_t)(k0 + k1 + 1) * N + n0 + nc];
                const float e0[4] = {v0.x, v0.y, v0.z, v0.w};
                const float e1[4] = {v1.x, v1.y, v1.z, v1.w};
#pragma unroll
                for (int e = 0; e < 4; ++e) {
                    short h0, m0_, l0, h1, m1_, l1;
                    split3(e0[e], h0, m0_, l0);
                    split3(e1[e], h1, m1_, l1);
                    *(short2*)&Bs[0][nc + e][k1] = make_short2(h0, h1);
                    *(short2*)&Bs[1][nc + e][k1] = make_short2(m0_, m1_);
                    *(short2*)&Bs[2][nc + e][k1] = make_short2(l0, l1);
                }
            }
        }
        __syncthreads();

        // ---- compute: 6 products (hh, mh, lh, hm, mm, hl) ----
        bf16x8 af[3][MT];
#pragma unroll
        for (int p = 0; p < 3; ++p)
#pragma unroll
            for (int i = 0; i < MT; ++i)
                af[p][i] = *(const bf16x8*)&As[p][wm + 16 * i + lrow][quad * 8];

#pragma unroll
        for (int pb = 0; pb < 3; ++pb) {
            bf16x8 bfr[NT];
#pragma unroll
            for (int j = 0; j < NT; ++j)
                bfr[j] = *(const bf16x8*)&Bs[pb][wn + 16 * j + lrow][quad * 8];
            const int npa = (pb == 0) ? 3 : (pb == 1 ? 2 : 1);
#pragma unroll
            for (int pa = 0; pa < 3; ++pa) {
                if (pa >= npa) break;
#pragma unroll
                for (int i = 0; i < MT; ++i)
#pragma unroll
                    for (int j = 0; j < NT; ++j)
                        acc[i][j] = __builtin_amdgcn_mfma_f32_16x16x32_bf16(
                            af[pa][i], bfr[j], acc[i][j], 0, 0, 0);
            }
        }
    }

    // ---- epilogue: C/D layout col=lane&15, row=quad*4+reg ----
#pragma unroll
    for (int i = 0; i < MT; ++i) {
        int mbase = m0 + wm + 16 * i + quad * 4;
#pragma unroll
        for (int j = 0; j < NT; ++j) {
            int n = n0 + wn + 16 * j + lrow;
            float bv = bias ? bias[n] : 0.f;
#pragma unroll
            for (int r = 0; r < 4; ++r) {
                size_t off = (size_t)(mbase + r) * ldc + n;
                float v = acc[i][j][r] + bv;
                if (act == 1) v = (v > 20.f) ? v : log1pf(__expf(v));
                if (addC) v += C[off];
                C[off] = v;
            }
        }
    }
}

// ---------------- generic tiled fp32 GEMM (small shapes) ----------------
#define BKK 16
__global__ __launch_bounds__(256)
void gemm_k(const float* __restrict__ A, int lda,
            const float* __restrict__ W,
            const float* __restrict__ bias,
            float* __restrict__ C, int ldc,
            int M, int N, int K, int act, int addC)
{
    __shared__ float Asf[BKK][64 + 4];
    __shared__ float Bsf[BKK][64 + 4];
    const int tid = threadIdx.x;
    const int tx = tid & 15, ty = tid >> 4;
    const int m0 = blockIdx.y * 64, n0 = blockIdx.x * 64;
    float acc[4][4] = {{0.f}};

    for (int k0 = 0; k0 < K; k0 += BKK) {
#pragma unroll
        for (int j = 0; j < 4; ++j) {
            int idx = tid + 256 * j;
            int m = idx >> 4, kk = idx & 15;
            Asf[kk][m] = A[(size_t)(m0 + m) * lda + k0 + kk];
        }
#pragma unroll
        for (int j = 0; j < 4; ++j) {
            int idx = tid + 256 * j;
            int kk = idx >> 6, n = idx & 63;
            Bsf[kk][n] = W[(size_t)(k0 + kk) * N + n0 + n];
        }
        __syncthreads();
#pragma unroll
        for (int kk = 0; kk < BKK; ++kk) {
            float a[4], b[4];
#pragma unroll
            for (int e = 0; e < 4; ++e) a[e] = Asf[kk][ty * 4 + e];
#pragma unroll
            for (int e = 0; e < 4; ++e) b[e] = Bsf[kk][tx * 4 + e];
#pragma unroll
            for (int i = 0; i < 4; ++i)
#pragma unroll
                for (int j = 0; j < 4; ++j)
                    acc[i][j] = fmaf(a[i], b[j], acc[i][j]);
        }
        __syncthreads();
    }

#pragma unroll
    for (int i = 0; i < 4; ++i) {
        int row = m0 + ty * 4 + i;
#pragma unroll
        for (int j = 0; j < 4; ++j) {
            int col = n0 + tx * 4 + j;
            float v = acc[i][j];
            if (bias) v += bias[col];
            if (act == 1) v = (v > 20.f) ? v : log1pf(expf(v));
            size_t off = (size_t)row * ldc + col;
            if (addC) v += C[off];
            C[off] = v;
        }
    }
}

// ---------------- RMSNorm: one wave per row of 512 ----------------
__global__ __launch_bounds__(256)
void rmsnorm_k(const float* __restrict__ X, const float* __restrict__ w,
               float* __restrict__ O)
{
    int wid = threadIdx.x >> 6, lane = threadIdx.x & 63;
    int row = blockIdx.x * 4 + wid;
    const float* xr = X + (size_t)row * DMODEL;
    float v[8];
    float ss = 0.f;
#pragma unroll
    for (int j = 0; j < 8; ++j) { v[j] = xr[lane + 64 * j]; ss = fmaf(v[j], v[j], ss); }
#pragma unroll
    for (int off = 32; off >= 1; off >>= 1) ss += __shfl_xor(ss, off);
    float scale = rsqrtf(ss * (1.f / 512.f) + 1e-5f);
    float* orow = O + (size_t)row * DMODEL;
#pragma unroll
    for (int j = 0; j < 8; ++j) orow[lane + 64 * j] = v[j] * scale * w[lane + 64 * j];
}

// ---------------- causal depthwise conv (K=4) + SiLU ----------------
__global__ __launch_bounds__(256)
void conv_silu_k(const float* __restrict__ XZ, const float* __restrict__ cw,
                 const float* __restrict__ cb, float* __restrict__ XC)
{
    int idx = blockIdx.x * 256 + threadIdx.x;   // b*L*D enumeration, d fastest
    int d = idx & 1023;
    int t = (idx >> 10) & 511;
    int b = idx >> 19;
    float s = cb[d];
#pragma unroll
    for (int k = 0; k < 4; ++k) {
        int tt = t + k - 3;
        if (tt >= 0)
            s = fmaf(cw[d * 4 + k], XZ[((size_t)(b * 512 + tt)) * 2048 + d], s);
    }
    XC[idx] = s / (1.f + expf(-s));
}

// ---------------- chunked selective scan ----------------
__global__ __launch_bounds__(256)
void scan1_k(const float* __restrict__ DELTA, const float* __restrict__ XC,
             const float* __restrict__ DBL, const float* __restrict__ A_log,
             const float* __restrict__ Dsk, float* __restrict__ Y,
             float* __restrict__ SC, float* __restrict__ DS)
{
    int tid = threadIdx.x;
    int n = tid & 15;
    int G = blockIdx.x * 16 + (tid >> 4);   // (b*8+chunk)*1024 + d
    int d = G & 1023;
    int bc = G >> 10;
    int chunk = bc & 7;
    int b = bc >> 3;
    float Ac = -__expf(A_log[d * 16 + n]);
    float Dv = Dsk[d];
    int t0 = chunk * 64;
    const float* dptr  = DELTA + ((size_t)(b * 512 + t0)) * 1024 + d;
    const float* uptr  = XC    + ((size_t)(b * 512 + t0)) * 1024 + d;
    const float* blptr = DBL   + ((size_t)(b * 512 + t0)) * 64;
    float* yptr        = Y     + ((size_t)(b * 512 + t0)) * 1024 + d;
    float h = 0.f, dsum = 0.f;
    for (int t = 0; t < 64; ++t) {
        float delta = dptr[t * 1024];
        float u = uptr[t * 1024];
        float Bv = blptr[t * 64 + 32 + n];
        float Cv = blptr[t * 64 + 48 + n];
        dsum += delta;
        h = fmaf(__expf(delta * Ac), h, delta * u * Bv);
        float p = h * Cv;
        p += __shfl_xor(p, 1);
        p += __shfl_xor(p, 2);
        p += __shfl_xor(p, 4);
        p += __shfl_xor(p, 8);
        if (n == 0) yptr[t * 1024] = fmaf(u, Dv, p);
    }
    SC[((size_t)((b * 1024 + d) * 16 + n)) * 8 + chunk] = h;
    if (n == 0) DS[(size_t)(b * 1024 + d) * 8 + chunk] = dsum;
}

__global__ __launch_bounds__(256)
void scan2_k(const float* __restrict__ A_log, float* __restrict__ SCH0,
             const float* __restrict__ DS)
{
    int gid = blockIdx.x * 256 + threadIdx.x;   // (b*1024+d)*16 + n
    int n = gid & 15;
    int bd = gid >> 4;
    int d = bd & 1023;
    float Ac = -__expf(A_log[d * 16 + n]);
    float carry = 0.f;
    float* sc = SCH0 + (size_t)gid * 8;
    const float* ds = DS + (size_t)bd * 8;
#pragma unroll
    for (int c = 0; c < 8; ++c) {
        float s = sc[c];
        sc[c] = carry;
        carry = fmaf(__expf(Ac * ds[c]), carry, s);
    }
}

__global__ __launch_bounds__(256)
void scan3_k(const float* __restrict__ DELTA, const float* __restrict__ DBL,
             const float* __restrict__ A_log, const float* __restrict__ H0,
             const float* __restrict__ XZ, float* __restrict__ Y)
{
    int tid = threadIdx.x;
    int n = tid & 15;
    int G = blockIdx.x * 16 + (tid >> 4);   // (b*8+chunk)*1024 + d
    int d = G & 1023;
    int bc = G >> 10;
    int chunk = bc & 7;
    int b = bc >> 3;
    float Ac = -__expf(A_log[d * 16 + n]);
    float h0 = H0[((size_t)((b * 1024 + d) * 16 + n)) * 8 + chunk];
    int t0 = chunk * 64;
    const float* dptr  = DELTA + ((size_t)(b * 512 + t0)) * 1024 + d;
    const float* blptr = DBL   + ((size_t)(b * 512 + t0)) * 64;
    const float* zptr  = XZ    + ((size_t)(b * 512 + t0)) * 2048 + 1024 + d;
    float* yptr        = Y     + ((size_t)(b * 512 + t0)) * 1024 + d;
    float cum = 0.f;
    for (int t = 0; t < 64; ++t) {
        float delta = dptr[t * 1024];
        float Cv = blptr[t * 64 + 48 + n];
        cum += delta;
        float p = h0 * __expf(Ac * cum) * Cv;
        p += __shfl_xor(p, 1);
        p += __shfl_xor(p, 2);
        p += __shfl_xor(p, 4);
        p += __shfl_xor(p, 8);
        if (n == 0) {
            float z = zptr[t * 2048];
            float yv = yptr[t * 1024] + p;
            yptr[t * 1024] = yv * (z / (1.f + __expf(-z)));
        }
    }
}

// ---------------- attention: block per (b, h, 16 q-rows) ----------------
__global__ __launch_bounds__(256)
void attn_k(const float* __restrict__ Q, const float* __restrict__ K,
            const float* __restrict__ V, float* __restrict__ CTX)
{
    __shared__ float Qs[16][128];
    __shared__ float Ks[64][129];
    __shared__ float S[16][257];
    int b = blockIdx.z, h = blockIdx.y, q0 = blockIdx.x * 16;
    int tid = threadIdx.x;

#pragma unroll
    for (int j = 0; j < 8; ++j) {
        int idx = tid + 256 * j;
        int qi = idx >> 7, dd = idx & 127;
        Qs[qi][dd] = Q[((size_t)(b * 512 + q0 + qi)) * 512 + h * 128 + dd];
    }
    const float scale = 0.08838834764831845f;

    for (int kb = 0; kb < 4; ++kb) {
        __syncthreads();
#pragma unroll
        for (int j = 0; j < 32; ++j) {
            int idx = tid + 256 * j;
            int ki = idx >> 7, dd = idx & 127;
            Ks[ki][dd] = K[((size_t)(b * 256 + kb * 64 + ki)) * 512 + h * 128 + dd];
        }
        __syncthreads();
        int kl = tid & 63, qb = tid >> 6;
        float sacc[4] = {0.f, 0.f, 0.f, 0.f};
        for (int dd = 0; dd < 128; ++dd) {
            float kvv = Ks[kl][dd];
#pragma unroll
            for (int p = 0; p < 4; ++p)
                sacc[p] = fmaf(Qs[qb * 4 + p][dd], kvv, sacc[p]);
        }
#pragma unroll
        for (int p = 0; p < 4; ++p)
            S[qb * 4 + p][kb * 64 + kl] = sacc[p] * scale;
    }
    __syncthreads();

    {
        int row = tid >> 4, sub = tid & 15;
        float mx = -1e30f;
        for (int j = sub; j < 256; j += 16) mx = fmaxf(mx, S[row][j]);
        mx = fmaxf(mx, __shfl_xor(mx, 1));
        mx = fmaxf(mx, __shfl_xor(mx, 2));
        mx = fmaxf(mx, __shfl_xor(mx, 4));
        mx = fmaxf(mx, __shfl_xor(mx, 8));
        float sum = 0.f;
        for (int j = sub; j < 256; j += 16) {
            float e = __expf(S[row][j] - mx);
            S[row][j] = e;
            sum += e;
        }
        sum += __shfl_xor(sum, 1);
        sum += __shfl_xor(sum, 2);
        sum += __shfl_xor(sum, 4);
        sum += __shfl_xor(sum, 8);
        float inv = 1.f / sum;
        for (int j = sub; j < 256; j += 16) S[row][j] *= inv;
    }
    __syncthreads();

    int dd = tid & 127, qsel = tid >> 7;
    float acc[8];
#pragma unroll
    for (int p = 0; p < 8; ++p) acc[p] = 0.f;
    for (int kk = 0; kk < 256; ++kk) {
        float vv = V[((size_t)(b * 256 + kk)) * 512 + h * 128 + dd];
#pragma unroll
        for (int p = 0; p < 8; ++p)
            acc[p] = fmaf(S[qsel * 8 + p][kk], vv, acc[p]);
    }
#pragma unroll
    for (int p = 0; p < 8; ++p) {
        int qi = qsel * 8 + p;
        CTX[((size_t)(b * 512 + q0 + qi)) * 512 + h * 128 + dd] = acc[p];
    }
}

// ---------------- final linear (512->6) + argmax, one wave per row ----------------
__global__ __launch_bounds__(256)
void head_k(const float* __restrict__ T2, const float* __restrict__ Wout,
            const float* __restrict__ bout, float* __restrict__ out)
{
    int wid = threadIdx.x >> 6, lane = threadIdx.x & 63;
    int row = blockIdx.x * 4 + wid;
    float acc[6] = {0.f, 0.f, 0.f, 0.f, 0.f, 0.f};
    const float* tr = T2 + (size_t)row * 512;
#pragma unroll
    for (int j = 0; j < 8; ++j) {
        int k = lane + 64 * j;
        float t = tr[k];
#pragma unroll
        for (int c = 0; c < 6; ++c) acc[c] = fmaf(t, Wout[k * 6 + c], acc[c]);
    }
#pragma unroll
    for (int c = 0; c < 6; ++c) {
#pragma unroll
        for (int off = 32; off >= 1; off >>= 1) acc[c] += __shfl_xor(acc[c], off);
    }
    if (lane == 0) {
        float best = -1e30f;
        int bi = 0;
#pragma unroll
        for (int c = 0; c < 6; ++c) {
            float v = acc[c] + bout[c];
            out[(size_t)row * 6 + c] = v;
            if (v > best) { best = v; bi = c; }
        }
        out[(size_t)4096 * 6 + row] = (float)bi;
    }
}

extern "C" void kernel_launch(void* const* d_in, const int* in_sizes, int n_in,
                              void* d_out, int out_size, void* d_ws, size_t ws_size,
                              hipStream_t stream)
{
    (void)in_sizes; (void)n_in; (void)out_size; (void)ws_size;
    const float* agent      = (const float*)d_in[0];
    const float* lane       = (const float*)d_in[1];
    const float* lane_in_W  = (const float*)d_in[2];
    const float* lane_in_b  = (const float*)d_in[3];
    const float* norm_w     = (const float*)d_in[4];
    const float* in_proj_W  = (const float*)d_in[5];
    const float* conv_w     = (const float*)d_in[6];
    const float* conv_b     = (const float*)d_in[7];
    const float* x_proj_W   = (const float*)d_in[8];
    const float* dt_proj_W  = (const float*)d_in[9];
    const float* dt_proj_b  = (const float*)d_in[10];
    const float* A_log      = (const float*)d_in[11];
    const float* D_skip     = (const float*)d_in[12];
    const float* out_proj_W = (const float*)d_in[13];
    const float* final_norm_w = (const float*)d_in[14];
    const float* Wq = (const float*)d_in[15];
    const float* Wk = (const float*)d_in[16];
    const float* Wv = (const float*)d_in[17];
    const float* Wo = (const float*)d_in[18];
    const float* bq = (const float*)d_in[19];
    const float* bk = (const float*)d_in[20];
    const float* bv = (const float*)d_in[21];
    const float* bo = (const float*)d_in[22];
    const float* lin_in_W  = (const float*)d_in[23];
    const float* lin_in_b  = (const float*)d_in[24];
    const float* lin_out_W = (const float*)d_in[25];
    const float* lin_out_b = (const float*)d_in[26];

    // Workspace: same 97 MB footprint that passed tripwires in rounds 1/3.
    float* ws = (float*)d_ws;
    float* X     = ws;                      // 2M floats (4096 x 512)
    float* H     = X + (1 << 21);           // 2M (rmsnorm out; dead during scans)
    float* XZ    = H + (1 << 21);           // 8M  (4096 x 2048)
    float* XC    = XZ + (1 << 23);          // 4M  (4096 x 1024)
    float* DELTA = XC + (1 << 22);          // 4M
    float* Y     = DELTA + (1 << 22);       // 4M
    float* DBL   = Y + (1 << 22);           // 256K (4096 x 64)
    float* SCb   = H;                       // 1M  chunk states -> carries (aliases H)
    float* DSb   = H + (1 << 20);           // 64K delta sums (aliases H)
    float* Qb  = XZ;                        // 2M
    float* Kb  = XZ + (1 << 21);            // 1M (2048 x 512)
    float* Vb  = Kb + (1 << 20);            // 1M
    float* CTX = Vb + (1 << 20);            // 2M
    float* AO  = CTX + (1 << 21);           // 2M
    float* T2  = XC;                        // 2M

    dim3 blk(256);

    // x = lane_features @ lane_in_W + b   (4096x128 @ 128x512)
    gemm_mfma<64, 1, 4><<<dim3(4, 64), blk, 0, stream>>>(
        lane, 128, lane_in_W, lane_in_b, X, 512, 4096, 512, 128, 0, 0);

    for (int i = 0; i < 4; ++i) {
        rmsnorm_k<<<1024, blk, 0, stream>>>(X, norm_w + i * 512, H);
        // xz = h @ in_proj  (4096x512 @ 512x2048)
        gemm_mfma<128, 2, 2><<<dim3(16, 32), blk, 0, stream>>>(
            H, 512, in_proj_W + (size_t)i * 512 * 2048, nullptr, XZ, 2048,
            4096, 2048, 512, 0, 0);
        conv_silu_k<<<16384, blk, 0, stream>>>(XZ, conv_w + i * 4096, conv_b + i * 1024, XC);
        // dbl = xc @ x_proj  (4096x1024 @ 1024x64)  -- N=64, fp32 kernel
        gemm_k<<<dim3(1, 64), blk, 0, stream>>>(XC, 1024, x_proj_W + (size_t)i * 1024 * 64,
                                                nullptr, DBL, 64, 4096, 64, 1024, 0, 0);
        // delta = softplus(dt @ dt_proj + b)  (4096x32 @ 32x1024)
        gemm_mfma<64, 1, 4><<<dim3(8, 64), blk, 0, stream>>>(
            DBL, 64, dt_proj_W + (size_t)i * 32 * 1024, dt_proj_b + i * 1024,
            DELTA, 1024, 4096, 1024, 32, 1, 0);
        // chunked scan (3 phases) + fused gating
        scan1_k<<<4096, blk, 0, stream>>>(DELTA, XC, DBL, A_log + (size_t)i * 1024 * 16,
                                          D_skip + i * 1024, Y, SCb, DSb);
        scan2_k<<<512, blk, 0, stream>>>(A_log + (size_t)i * 1024 * 16, SCb, DSb);
        scan3_k<<<4096, blk, 0, stream>>>(DELTA, DBL, A_log + (size_t)i * 1024 * 16,
                                          SCb, XZ, Y);
        // x += ygated @ out_proj  (4096x1024 @ 1024x512)
        gemm_mfma<64, 1, 4><<<dim3(4, 64), blk, 0, stream>>>(
            Y, 1024, out_proj_W + (size_t)i * 1024 * 512, nullptr, X, 512,
            4096, 512, 1024, 0, 1);
    }

    rmsnorm_k<<<1024, blk, 0, stream>>>(X, final_norm_w, H);   // enhanced

    gemm_mfma<64, 1, 4><<<dim3(4, 64), blk, 0, stream>>>(
        H, 512, Wq, bq, Qb, 512, 4096, 512, 512, 0, 0);
    gemm_mfma<64, 1, 4><<<dim3(4, 32), blk, 0, stream>>>(
        agent, 512, Wk, bk, Kb, 512, 2048, 512, 512, 0, 0);
    gemm_mfma<64, 1, 4><<<dim3(4, 32), blk, 0, stream>>>(
        agent, 512, Wv, bv, Vb, 512, 2048, 512, 512, 0, 0);
    attn_k<<<dim3(32, 4, 8), blk, 0, stream>>>(Qb, Kb, Vb, CTX);
    gemm_mfma<64, 1, 4><<<dim3(4, 64), blk, 0, stream>>>(
        CTX, 512, Wo, bo, AO, 512, 4096, 512, 512, 0, 0);
    gemm_mfma<64, 1, 4><<<dim3(4, 64), blk, 0, stream>>>(
        AO, 512, lin_in_W, lin_in_b, T2, 512, 4096, 512, 512, 0, 0);
    head_k<<<1024, blk, 0, stream>>>(T2, lin_out_W, lin_out_b, (float*)d_out);
}

// Round 5
// 2113.479 us; speedup vs baseline: 1.3389x; 1.3389x over previous
//
#include <hip/hip_runtime.h>
#include <math.h>

#define BATCH 8
#define LSEQ 512
#define LAGENT 256
#define DMODEL 512
#define DINNER 1024
#define DSTATE 16
#define DTRANK 32
#define NHEAD 4
#define DHEAD 128
#define NLANES 6

typedef __attribute__((ext_vector_type(8))) short bf16x8;
typedef __attribute__((ext_vector_type(4))) float f32x4;

// Exact 3-way bf16 split: x = h + m + l + O(2^-24 |x|); all subtractions exact.
__device__ __forceinline__ void split3(float x, short& h, short& m, short& l)
{
    unsigned hb = __float_as_uint(x) & 0xFFFF0000u;
    h = (short)(hb >> 16);
    float r1 = x - __uint_as_float(hb);
    unsigned mb = __float_as_uint(r1) & 0xFFFF0000u;
    m = (short)(mb >> 16);
    float r2 = r1 - __uint_as_float(mb);
    l = (short)(__float_as_uint(r2) >> 16);
}

// ---------------- bf16x6 emulated-fp32 MFMA GEMM, fragment-linear LDS ----------------
// C[M,N] = act(A[M,K](lda) @ W[K,N] + bias) (+C if addC)
// LDS layout: per 16(m|n) x 32(k) slab, lane l's 8 fragment shorts at slab*520 + l*8
// => ds_read_b128 at consecutive 16B per lane (conflict-free, m97 pattern).
// Slab stride 520 shorts = 260 dwords (16B aligned, !=0 mod 32 for write stagger).
template<int BM, int BN, int WM, int WN>
__global__ __launch_bounds__(256)
void gemm6(const float* __restrict__ A, int lda,
           const float* __restrict__ W,
           const float* __restrict__ bias,
           float* __restrict__ C, int ldc,
           int M, int N, int K, int act, int addC)
{
    constexpr int MT = BM / WM / 16;      // m-slabs per wave
    constexpr int NT = BN / WN / 16;      // n-slabs per wave
    constexpr int ASL = BM / 16;          // A slabs per tile
    constexpr int BSL = BN / 16;
    __shared__ short Asl[3][ASL * 520];
    __shared__ short Bsl[3][BSL * 520];

    const int tid = threadIdx.x;
    const int w = tid >> 6, lane = tid & 63;
    const int lrow = lane & 15, quad = lane >> 4;
    const int aslab0 = (w % WM) * MT;
    const int bslab0 = (w / WM) * NT;
    const int m0 = blockIdx.y * BM, n0 = blockIdx.x * BN;

    f32x4 acc[MT][NT] = {};

    for (int k0 = 0; k0 < K; k0 += 32) {
        __syncthreads();
        // ---- stage A tile (BM x 32): float4 along k -> short4 per plane ----
#pragma unroll
        for (int i = 0; i < BM / 32; ++i) {
            int v = tid + 256 * i;
            int row = v >> 3;             // 8 float4 per 32-wide row
            int kq = (v & 7) * 4;
            float4 val = *(const float4*)&A[(size_t)(m0 + row) * lda + k0 + kq];
            int off = (row >> 4) * 520 + (((kq >> 3) << 4) + (row & 15)) * 8 + (kq & 7);
            short h[4], mm_[4], l[4];
            split3(val.x, h[0], mm_[0], l[0]);
            split3(val.y, h[1], mm_[1], l[1]);
            split3(val.z, h[2], mm_[2], l[2]);
            split3(val.w, h[3], mm_[3], l[3]);
            *(short4*)&Asl[0][off] = make_short4(h[0], h[1], h[2], h[3]);
            *(short4*)&Asl[1][off] = make_short4(mm_[0], mm_[1], mm_[2], mm_[3]);
            *(short4*)&Asl[2][off] = make_short4(l[0], l[1], l[2], l[3]);
        }
        // ---- stage B tile (32 x BN): two k-rows x 4 n -> short2 per (n,plane) ----
        constexpr int NPQS = (BN == 128) ? 5 : 4;   // log2(BN/4)
#pragma unroll
        for (int i = 0; i < BN / 64; ++i) {
            int v = tid + 256 * i;
            int kp = v >> NPQS;           // 0..15 k-pair
            int nc = (v & ((1 << NPQS) - 1)) * 4;
            int k1 = kp * 2;
            float4 r0 = *(const float4*)&W[(size_t)(k0 + k1) * N + n0 + nc];
            float4 r1 = *(const float4*)&W[(size_t)(k0 + k1 + 1) * N + n0 + nc];
            const float e0[4] = {r0.x, r0.y, r0.z, r0.w};
            const float e1[4] = {r1.x, r1.y, r1.z, r1.w};
#pragma unroll
            for (int e = 0; e < 4; ++e) {
                int n = nc + e;
                int off = (n >> 4) * 520 + (((k1 >> 3) << 4) + (n & 15)) * 8 + (k1 & 7);
                short h0, m0_, l0, h1, m1_, l1;
                split3(e0[e], h0, m0_, l0);
                split3(e1[e], h1, m1_, l1);
                *(short2*)&Bsl[0][off] = make_short2(h0, h1);
                *(short2*)&Bsl[1][off] = make_short2(m0_, m1_);
                *(short2*)&Bsl[2][off] = make_short2(l0, l1);
            }
        }
        __syncthreads();

        // ---- compute: 6 products (hh, mh, lh, hm, mm, hl) ----
        bf16x8 af[3][MT];
#pragma unroll
        for (int p = 0; p < 3; ++p)
#pragma unroll
            for (int i = 0; i < MT; ++i)
                af[p][i] = *(const bf16x8*)&Asl[p][(aslab0 + i) * 520 + lane * 8];

#pragma unroll
        for (int pb = 0; pb < 3; ++pb) {
            bf16x8 bfr[NT];
#pragma unroll
            for (int j = 0; j < NT; ++j)
                bfr[j] = *(const bf16x8*)&Bsl[pb][(bslab0 + j) * 520 + lane * 8];
            const int npa = (pb == 0) ? 3 : (pb == 1 ? 2 : 1);
#pragma unroll
            for (int pa = 0; pa < 3; ++pa) {
                if (pa >= npa) break;
#pragma unroll
                for (int i = 0; i < MT; ++i)
#pragma unroll
                    for (int j = 0; j < NT; ++j)
                        acc[i][j] = __builtin_amdgcn_mfma_f32_16x16x32_bf16(
                            af[pa][i], bfr[j], acc[i][j], 0, 0, 0);
            }
        }
    }

    // ---- epilogue: C/D layout col=lane&15, row=quad*4+reg ----
#pragma unroll
    for (int i = 0; i < MT; ++i) {
        int mbase = m0 + (aslab0 + i) * 16 + quad * 4;
#pragma unroll
        for (int j = 0; j < NT; ++j) {
            int n = n0 + (bslab0 + j) * 16 + lrow;
            float bv = bias ? bias[n] : 0.f;
#pragma unroll
            for (int r = 0; r < 4; ++r) {
                size_t off = (size_t)(mbase + r) * ldc + n;
                float v = acc[i][j][r] + bv;
                if (act == 1) v = (v > 20.f) ? v : log1pf(__expf(v));
                if (addC) v += C[off];
                C[off] = v;
            }
        }
    }
}

// ---------------- generic tiled fp32 GEMM (x_proj only: N=64) ----------------
#define BKK 16
__global__ __launch_bounds__(256)
void gemm_k(const float* __restrict__ A, int lda,
            const float* __restrict__ W,
            const float* __restrict__ bias,
            float* __restrict__ C, int ldc,
            int M, int N, int K, int act, int addC)
{
    __shared__ float Asf[BKK][64 + 4];
    __shared__ float Bsf[BKK][64 + 4];
    const int tid = threadIdx.x;
    const int tx = tid & 15, ty = tid >> 4;
    const int m0 = blockIdx.y * 64, n0 = blockIdx.x * 64;
    float acc[4][4] = {{0.f}};

    for (int k0 = 0; k0 < K; k0 += BKK) {
#pragma unroll
        for (int j = 0; j < 4; ++j) {
            int idx = tid + 256 * j;
            int m = idx >> 4, kk = idx & 15;
            Asf[kk][m] = A[(size_t)(m0 + m) * lda + k0 + kk];
        }
#pragma unroll
        for (int j = 0; j < 4; ++j) {
            int idx = tid + 256 * j;
            int kk = idx >> 6, n = idx & 63;
            Bsf[kk][n] = W[(size_t)(k0 + kk) * N + n0 + n];
        }
        __syncthreads();
#pragma unroll
        for (int kk = 0; kk < BKK; ++kk) {
            float a[4], b[4];
#pragma unroll
            for (int e = 0; e < 4; ++e) a[e] = Asf[kk][ty * 4 + e];
#pragma unroll
            for (int e = 0; e < 4; ++e) b[e] = Bsf[kk][tx * 4 + e];
#pragma unroll
            for (int i = 0; i < 4; ++i)
#pragma unroll
                for (int j = 0; j < 4; ++j)
                    acc[i][j] = fmaf(a[i], b[j], acc[i][j]);
        }
        __syncthreads();
    }

#pragma unroll
    for (int i = 0; i < 4; ++i) {
        int row = m0 + ty * 4 + i;
#pragma unroll
        for (int j = 0; j < 4; ++j) {
            int col = n0 + tx * 4 + j;
            float v = acc[i][j];
            if (bias) v += bias[col];
            if (act == 1) v = (v > 20.f) ? v : log1pf(expf(v));
            size_t off = (size_t)row * ldc + col;
            if (addC) v += C[off];
            C[off] = v;
        }
    }
}

// ---------------- RMSNorm: one wave per row of 512 ----------------
__global__ __launch_bounds__(256)
void rmsnorm_k(const float* __restrict__ X, const float* __restrict__ w,
               float* __restrict__ O)
{
    int wid = threadIdx.x >> 6, lane = threadIdx.x & 63;
    int row = blockIdx.x * 4 + wid;
    const float* xr = X + (size_t)row * DMODEL;
    float v[8];
    float ss = 0.f;
#pragma unroll
    for (int j = 0; j < 8; ++j) { v[j] = xr[lane + 64 * j]; ss = fmaf(v[j], v[j], ss); }
#pragma unroll
    for (int off = 32; off >= 1; off >>= 1) ss += __shfl_xor(ss, off);
    float scale = rsqrtf(ss * (1.f / 512.f) + 1e-5f);
    float* orow = O + (size_t)row * DMODEL;
#pragma unroll
    for (int j = 0; j < 8; ++j) orow[lane + 64 * j] = v[j] * scale * w[lane + 64 * j];
}

// ---------------- causal depthwise conv (K=4) + SiLU ----------------
__global__ __launch_bounds__(256)
void conv_silu_k(const float* __restrict__ XZ, const float* __restrict__ cw,
                 const float* __restrict__ cb, float* __restrict__ XC)
{
    int idx = blockIdx.x * 256 + threadIdx.x;   // b*L*D enumeration, d fastest
    int d = idx & 1023;
    int t = (idx >> 10) & 511;
    int b = idx >> 19;
    float s = cb[d];
#pragma unroll
    for (int k = 0; k < 4; ++k) {
        int tt = t + k - 3;
        if (tt >= 0)
            s = fmaf(cw[d * 4 + k], XZ[((size_t)(b * 512 + tt)) * 2048 + d], s);
    }
    XC[idx] = s / (1.f + expf(-s));
}

// ---------------- chunked selective scan ----------------
__global__ __launch_bounds__(256)
void scan1_k(const float* __restrict__ DELTA, const float* __restrict__ XC,
             const float* __restrict__ DBL, const float* __restrict__ A_log,
             const float* __restrict__ Dsk, float* __restrict__ Y,
             float* __restrict__ SC, float* __restrict__ DS)
{
    int tid = threadIdx.x;
    int n = tid & 15;
    int G = blockIdx.x * 16 + (tid >> 4);   // (b*8+chunk)*1024 + d
    int d = G & 1023;
    int bc = G >> 10;
    int chunk = bc & 7;
    int b = bc >> 3;
    float Ac = -__expf(A_log[d * 16 + n]);
    float Dv = Dsk[d];
    int t0 = chunk * 64;
    const float* dptr  = DELTA + ((size_t)(b * 512 + t0)) * 1024 + d;
    const float* uptr  = XC    + ((size_t)(b * 512 + t0)) * 1024 + d;
    const float* blptr = DBL   + ((size_t)(b * 512 + t0)) * 64;
    float* yptr        = Y     + ((size_t)(b * 512 + t0)) * 1024 + d;
    float h = 0.f, dsum = 0.f;
    for (int t = 0; t < 64; ++t) {
        float delta = dptr[t * 1024];
        float u = uptr[t * 1024];
        float Bv = blptr[t * 64 + 32 + n];
        float Cv = blptr[t * 64 + 48 + n];
        dsum += delta;
        h = fmaf(__expf(delta * Ac), h, delta * u * Bv);
        float p = h * Cv;
        p += __shfl_xor(p, 1);
        p += __shfl_xor(p, 2);
        p += __shfl_xor(p, 4);
        p += __shfl_xor(p, 8);
        if (n == 0) yptr[t * 1024] = fmaf(u, Dv, p);
    }
    SC[((size_t)((b * 1024 + d) * 16 + n)) * 8 + chunk] = h;
    if (n == 0) DS[(size_t)(b * 1024 + d) * 8 + chunk] = dsum;
}

__global__ __launch_bounds__(256)
void scan2_k(const float* __restrict__ A_log, float* __restrict__ SCH0,
             const float* __restrict__ DS)
{
    int gid = blockIdx.x * 256 + threadIdx.x;   // (b*1024+d)*16 + n
    int n = gid & 15;
    int bd = gid >> 4;
    int d = bd & 1023;
    float Ac = -__expf(A_log[d * 16 + n]);
    float carry = 0.f;
    float* sc = SCH0 + (size_t)gid * 8;
    const float* ds = DS + (size_t)bd * 8;
#pragma unroll
    for (int c = 0; c < 8; ++c) {
        float s = sc[c];
        sc[c] = carry;
        carry = fmaf(__expf(Ac * ds[c]), carry, s);
    }
}

__global__ __launch_bounds__(256)
void scan3_k(const float* __restrict__ DELTA, const float* __restrict__ DBL,
             const float* __restrict__ A_log, const float* __restrict__ H0,
             const float* __restrict__ XZ, float* __restrict__ Y)
{
    int tid = threadIdx.x;
    int n = tid & 15;
    int G = blockIdx.x * 16 + (tid >> 4);   // (b*8+chunk)*1024 + d
    int d = G & 1023;
    int bc = G >> 10;
    int chunk = bc & 7;
    int b = bc >> 3;
    float Ac = -__expf(A_log[d * 16 + n]);
    float h0 = H0[((size_t)((b * 1024 + d) * 16 + n)) * 8 + chunk];
    int t0 = chunk * 64;
    const float* dptr  = DELTA + ((size_t)(b * 512 + t0)) * 1024 + d;
    const float* blptr = DBL   + ((size_t)(b * 512 + t0)) * 64;
    const float* zptr  = XZ    + ((size_t)(b * 512 + t0)) * 2048 + 1024 + d;
    float* yptr        = Y     + ((size_t)(b * 512 + t0)) * 1024 + d;
    float cum = 0.f;
    for (int t = 0; t < 64; ++t) {
        float delta = dptr[t * 1024];
        float Cv = blptr[t * 64 + 48 + n];
        cum += delta;
        float p = h0 * __expf(Ac * cum) * Cv;
        p += __shfl_xor(p, 1);
        p += __shfl_xor(p, 2);
        p += __shfl_xor(p, 4);
        p += __shfl_xor(p, 8);
        if (n == 0) {
            float z = zptr[t * 2048];
            float yv = yptr[t * 1024] + p;
            yptr[t * 1024] = yv * (z / (1.f + __expf(-z)));
        }
    }
}

// ---------------- attention: block per (b, h, 16 q-rows) ----------------
__global__ __launch_bounds__(256)
void attn_k(const float* __restrict__ Q, const float* __restrict__ K,
            const float* __restrict__ V, float* __restrict__ CTX)
{
    __shared__ float Qs[16][128];
    __shared__ float Ks[64][129];
    __shared__ float S[16][257];
    int b = blockIdx.z, h = blockIdx.y, q0 = blockIdx.x * 16;
    int tid = threadIdx.x;

#pragma unroll
    for (int j = 0; j < 8; ++j) {
        int idx = tid + 256 * j;
        int qi = idx >> 7, dd = idx & 127;
        Qs[qi][dd] = Q[((size_t)(b * 512 + q0 + qi)) * 512 + h * 128 + dd];
    }
    const float scale = 0.08838834764831845f;

    for (int kb = 0; kb < 4; ++kb) {
        __syncthreads();
#pragma unroll
        for (int j = 0; j < 32; ++j) {
            int idx = tid + 256 * j;
            int ki = idx >> 7, dd = idx & 127;
            Ks[ki][dd] = K[((size_t)(b * 256 + kb * 64 + ki)) * 512 + h * 128 + dd];
        }
        __syncthreads();
        int kl = tid & 63, qb = tid >> 6;
        float sacc[4] = {0.f, 0.f, 0.f, 0.f};
        for (int dd = 0; dd < 128; ++dd) {
            float kvv = Ks[kl][dd];
#pragma unroll
            for (int p = 0; p < 4; ++p)
                sacc[p] = fmaf(Qs[qb * 4 + p][dd], kvv, sacc[p]);
        }
#pragma unroll
        for (int p = 0; p < 4; ++p)
            S[qb * 4 + p][kb * 64 + kl] = sacc[p] * scale;
    }
    __syncthreads();

    {
        int row = tid >> 4, sub = tid & 15;
        float mx = -1e30f;
        for (int j = sub; j < 256; j += 16) mx = fmaxf(mx, S[row][j]);
        mx = fmaxf(mx, __shfl_xor(mx, 1));
        mx = fmaxf(mx, __shfl_xor(mx, 2));
        mx = fmaxf(mx, __shfl_xor(mx, 4));
        mx = fmaxf(mx, __shfl_xor(mx, 8));
        float sum = 0.f;
        for (int j = sub; j < 256; j += 16) {
            float e = __expf(S[row][j] - mx);
            S[row][j] = e;
            sum += e;
        }
        sum += __shfl_xor(sum, 1);
        sum += __shfl_xor(sum, 2);
        sum += __shfl_xor(sum, 4);
        sum += __shfl_xor(sum, 8);
        float inv = 1.f / sum;
        for (int j = sub; j < 256; j += 16) S[row][j] *= inv;
    }
    __syncthreads();

    int dd = tid & 127, qsel = tid >> 7;
    float acc[8];
#pragma unroll
    for (int p = 0; p < 8; ++p) acc[p] = 0.f;
    for (int kk = 0; kk < 256; ++kk) {
        float vv = V[((size_t)(b * 256 + kk)) * 512 + h * 128 + dd];
#pragma unroll
        for (int p = 0; p < 8; ++p)
            acc[p] = fmaf(S[qsel * 8 + p][kk], vv, acc[p]);
    }
#pragma unroll
    for (int p = 0; p < 8; ++p) {
        int qi = qsel * 8 + p;
        CTX[((size_t)(b * 512 + q0 + qi)) * 512 + h * 128 + dd] = acc[p];
    }
}

// ---------------- final linear (512->6) + argmax, one wave per row ----------------
__global__ __launch_bounds__(256)
void head_k(const float* __restrict__ T2, const float* __restrict__ Wout,
            const float* __restrict__ bout, float* __restrict__ out)
{
    int wid = threadIdx.x >> 6, lane = threadIdx.x & 63;
    int row = blockIdx.x * 4 + wid;
    float acc[6] = {0.f, 0.f, 0.f, 0.f, 0.f, 0.f};
    const float* tr = T2 + (size_t)row * 512;
#pragma unroll
    for (int j = 0; j < 8; ++j) {
        int k = lane + 64 * j;
        float t = tr[k];
#pragma unroll
        for (int c = 0; c < 6; ++c) acc[c] = fmaf(t, Wout[k * 6 + c], acc[c]);
    }
#pragma unroll
    for (int c = 0; c < 6; ++c) {
#pragma unroll
        for (int off = 32; off >= 1; off >>= 1) acc[c] += __shfl_xor(acc[c], off);
    }
    if (lane == 0) {
        float best = -1e30f;
        int bi = 0;
#pragma unroll
        for (int c = 0; c < 6; ++c) {
            float v = acc[c] + bout[c];
            out[(size_t)row * 6 + c] = v;
            if (v > best) { best = v; bi = c; }
        }
        out[(size_t)4096 * 6 + row] = (float)bi;
    }
}

extern "C" void kernel_launch(void* const* d_in, const int* in_sizes, int n_in,
                              void* d_out, int out_size, void* d_ws, size_t ws_size,
                              hipStream_t stream)
{
    (void)in_sizes; (void)n_in; (void)out_size; (void)ws_size;
    const float* agent      = (const float*)d_in[0];
    const float* lane       = (const float*)d_in[1];
    const float* lane_in_W  = (const float*)d_in[2];
    const float* lane_in_b  = (const float*)d_in[3];
    const float* norm_w     = (const float*)d_in[4];
    const float* in_proj_W  = (const float*)d_in[5];
    const float* conv_w     = (const float*)d_in[6];
    const float* conv_b     = (const float*)d_in[7];
    const float* x_proj_W   = (const float*)d_in[8];
    const float* dt_proj_W  = (const float*)d_in[9];
    const float* dt_proj_b  = (const float*)d_in[10];
    const float* A_log      = (const float*)d_in[11];
    const float* D_skip     = (const float*)d_in[12];
    const float* out_proj_W = (const float*)d_in[13];
    const float* final_norm_w = (const float*)d_in[14];
    const float* Wq = (const float*)d_in[15];
    const float* Wk = (const float*)d_in[16];
    const float* Wv = (const float*)d_in[17];
    const float* Wo = (const float*)d_in[18];
    const float* bq = (const float*)d_in[19];
    const float* bk = (const float*)d_in[20];
    const float* bv = (const float*)d_in[21];
    const float* bo = (const float*)d_in[22];
    const float* lin_in_W  = (const float*)d_in[23];
    const float* lin_in_b  = (const float*)d_in[24];
    const float* lin_out_W = (const float*)d_in[25];
    const float* lin_out_b = (const float*)d_in[26];

    // Workspace: same 97 MB footprint that passed tripwires (rounds 1/3/4).
    float* ws = (float*)d_ws;
    float* X     = ws;                      // 2M floats (4096 x 512)
    float* H     = X + (1 << 21);           // 2M (rmsnorm out; dead during scans)
    float* XZ    = H + (1 << 21);           // 8M  (4096 x 2048)
    float* XC    = XZ + (1 << 23);          // 4M  (4096 x 1024)
    float* DELTA = XC + (1 << 22);          // 4M
    float* Y     = DELTA + (1 << 22);       // 4M
    float* DBL   = Y + (1 << 22);           // 256K (4096 x 64)
    float* SCb   = H;                       // 1M  chunk states -> carries (aliases H)
    float* DSb   = H + (1 << 20);           // 64K delta sums (aliases H)
    float* Qb  = XZ;                        // 2M
    float* Kb  = XZ + (1 << 21);            // 1M (2048 x 512)
    float* Vb  = Kb + (1 << 20);            // 1M
    float* CTX = Vb + (1 << 20);            // 2M
    float* AO  = CTX + (1 << 21);           // 2M
    float* T2  = XC;                        // 2M

    dim3 blk(256);

    // x = lane_features @ lane_in_W + b   (4096x128 @ 128x512)
    gemm6<64, 64, 2, 2><<<dim3(8, 64), blk, 0, stream>>>(
        lane, 128, lane_in_W, lane_in_b, X, 512, 4096, 512, 128, 0, 0);

    for (int i = 0; i < 4; ++i) {
        rmsnorm_k<<<1024, blk, 0, stream>>>(X, norm_w + i * 512, H);
        // xz = h @ in_proj  (4096x512 @ 512x2048)
        gemm6<128, 128, 2, 2><<<dim3(16, 32), blk, 0, stream>>>(
            H, 512, in_proj_W + (size_t)i * 512 * 2048, nullptr, XZ, 2048,
            4096, 2048, 512, 0, 0);
        conv_silu_k<<<16384, blk, 0, stream>>>(XZ, conv_w + i * 4096, conv_b + i * 1024, XC);
        // dbl = xc @ x_proj  (4096x1024 @ 1024x64)  -- N=64, fp32 kernel
        gemm_k<<<dim3(1, 64), blk, 0, stream>>>(XC, 1024, x_proj_W + (size_t)i * 1024 * 64,
                                                nullptr, DBL, 64, 4096, 64, 1024, 0, 0);
        // delta = softplus(dt @ dt_proj + b)  (4096x32 @ 32x1024)
        gemm6<64, 64, 2, 2><<<dim3(16, 64), blk, 0, stream>>>(
            DBL, 64, dt_proj_W + (size_t)i * 32 * 1024, dt_proj_b + i * 1024,
            DELTA, 1024, 4096, 1024, 32, 1, 0);
        // chunked scan (3 phases) + fused gating
        scan1_k<<<4096, blk, 0, stream>>>(DELTA, XC, DBL, A_log + (size_t)i * 1024 * 16,
                                          D_skip + i * 1024, Y, SCb, DSb);
        scan2_k<<<512, blk, 0, stream>>>(A_log + (size_t)i * 1024 * 16, SCb, DSb);
        scan3_k<<<4096, blk, 0, stream>>>(DELTA, DBL, A_log + (size_t)i * 1024 * 16,
                                          SCb, XZ, Y);
        // x += ygated @ out_proj  (4096x1024 @ 1024x512)
        gemm6<64, 64, 2, 2><<<dim3(8, 64), blk, 0, stream>>>(
            Y, 1024, out_proj_W + (size_t)i * 1024 * 512, nullptr, X, 512,
            4096, 512, 1024, 0, 1);
    }

    rmsnorm_k<<<1024, blk, 0, stream>>>(X, final_norm_w, H);   // enhanced

    gemm6<64, 64, 2, 2><<<dim3(8, 64), blk, 0, stream>>>(
        H, 512, Wq, bq, Qb, 512, 4096, 512, 512, 0, 0);
    gemm6<64, 64, 2, 2><<<dim3(8, 32), blk, 0, stream>>>(
        agent, 512, Wk, bk, Kb, 512, 2048, 512, 512, 0, 0);
    gemm6<64, 64, 2, 2><<<dim3(8, 32), blk, 0, stream>>>(
        agent, 512, Wv, bv, Vb, 512, 2048, 512, 512, 0, 0);
    attn_k<<<dim3(32, 4, 8), blk, 0, stream>>>(Qb, Kb, Vb, CTX);
    gemm6<64, 64, 2, 2><<<dim3(8, 64), blk, 0, stream>>>(
        CTX, 512, Wo, bo, AO, 512, 4096, 512, 512, 0, 0);
    gemm6<64, 64, 2, 2><<<dim3(8, 64), blk, 0, stream>>>(
        AO, 512, lin_in_W, lin_in_b, T2, 512, 4096, 512, 512, 0, 0);
    head_k<<<1024, blk, 0, stream>>>(T2, lin_out_W, lin_out_b, (float*)d_out);
}

// Round 6
// 1644.558 us; speedup vs baseline: 1.7206x; 1.2851x over previous
//
#include <hip/hip_runtime.h>
#include <math.h>

#define BATCH 8
#define LSEQ 512
#define LAGENT 256
#define DMODEL 512
#define DINNER 1024
#define DSTATE 16
#define DTRANK 32
#define NHEAD 4
#define DHEAD 128
#define NLANES 6

typedef __attribute__((ext_vector_type(8))) short bf16x8;
typedef __attribute__((ext_vector_type(4))) float f32x4;

// Exact 3-way bf16 split: x = h + m + l + O(2^-24 |x|); all subtractions exact.
__device__ __forceinline__ void split3(float x, short& h, short& m, short& l)
{
    unsigned hb = __float_as_uint(x) & 0xFFFF0000u;
    h = (short)(hb >> 16);
    float r1 = x - __uint_as_float(hb);
    unsigned mb = __float_as_uint(r1) & 0xFFFF0000u;
    m = (short)(mb >> 16);
    float r2 = r1 - __uint_as_float(mb);
    l = (short)(__float_as_uint(r2) >> 16);
}

// ---------------- bf16x6 emulated-fp32 MFMA GEMM, fragment-linear LDS ----------------
template<int BM, int BN, int WM, int WN>
__global__ __launch_bounds__(256)
void gemm6(const float* __restrict__ A, int lda,
           const float* __restrict__ W,
           const float* __restrict__ bias,
           float* __restrict__ C, int ldc,
           int M, int N, int K, int act, int addC)
{
    constexpr int MT = BM / WM / 16;
    constexpr int NT = BN / WN / 16;
    constexpr int ASL = BM / 16;
    constexpr int BSL = BN / 16;
    __shared__ short Asl[3][ASL * 520];
    __shared__ short Bsl[3][BSL * 520];

    const int tid = threadIdx.x;
    const int w = tid >> 6, lane = tid & 63;
    const int lrow = lane & 15, quad = lane >> 4;
    const int aslab0 = (w % WM) * MT;
    const int bslab0 = (w / WM) * NT;
    const int m0 = blockIdx.y * BM, n0 = blockIdx.x * BN;

    f32x4 acc[MT][NT] = {};

    for (int k0 = 0; k0 < K; k0 += 32) {
        __syncthreads();
#pragma unroll
        for (int i = 0; i < BM / 32; ++i) {
            int v = tid + 256 * i;
            int row = v >> 3;
            int kq = (v & 7) * 4;
            float4 val = *(const float4*)&A[(size_t)(m0 + row) * lda + k0 + kq];
            int off = (row >> 4) * 520 + (((kq >> 3) << 4) + (row & 15)) * 8 + (kq & 7);
            short h[4], mm_[4], l[4];
            split3(val.x, h[0], mm_[0], l[0]);
            split3(val.y, h[1], mm_[1], l[1]);
            split3(val.z, h[2], mm_[2], l[2]);
            split3(val.w, h[3], mm_[3], l[3]);
            *(short4*)&Asl[0][off] = make_short4(h[0], h[1], h[2], h[3]);
            *(short4*)&Asl[1][off] = make_short4(mm_[0], mm_[1], mm_[2], mm_[3]);
            *(short4*)&Asl[2][off] = make_short4(l[0], l[1], l[2], l[3]);
        }
        constexpr int NPQS = (BN == 128) ? 5 : 4;
#pragma unroll
        for (int i = 0; i < BN / 64; ++i) {
            int v = tid + 256 * i;
            int kp = v >> NPQS;
            int nc = (v & ((1 << NPQS) - 1)) * 4;
            int k1 = kp * 2;
            float4 r0 = *(const float4*)&W[(size_t)(k0 + k1) * N + n0 + nc];
            float4 r1 = *(const float4*)&W[(size_t)(k0 + k1 + 1) * N + n0 + nc];
            const float e0[4] = {r0.x, r0.y, r0.z, r0.w};
            const float e1[4] = {r1.x, r1.y, r1.z, r1.w};
#pragma unroll
            for (int e = 0; e < 4; ++e) {
                int n = nc + e;
                int off = (n >> 4) * 520 + (((k1 >> 3) << 4) + (n & 15)) * 8 + (k1 & 7);
                short h0, m0_, l0, h1, m1_, l1;
                split3(e0[e], h0, m0_, l0);
                split3(e1[e], h1, m1_, l1);
                *(short2*)&Bsl[0][off] = make_short2(h0, h1);
                *(short2*)&Bsl[1][off] = make_short2(m0_, m1_);
                *(short2*)&Bsl[2][off] = make_short2(l0, l1);
            }
        }
        __syncthreads();

        bf16x8 af[3][MT];
#pragma unroll
        for (int p = 0; p < 3; ++p)
#pragma unroll
            for (int i = 0; i < MT; ++i)
                af[p][i] = *(const bf16x8*)&Asl[p][(aslab0 + i) * 520 + lane * 8];

#pragma unroll
        for (int pb = 0; pb < 3; ++pb) {
            bf16x8 bfr[NT];
#pragma unroll
            for (int j = 0; j < NT; ++j)
                bfr[j] = *(const bf16x8*)&Bsl[pb][(bslab0 + j) * 520 + lane * 8];
            const int npa = (pb == 0) ? 3 : (pb == 1 ? 2 : 1);
#pragma unroll
            for (int pa = 0; pa < 3; ++pa) {
                if (pa >= npa) break;
#pragma unroll
                for (int i = 0; i < MT; ++i)
#pragma unroll
                    for (int j = 0; j < NT; ++j)
                        acc[i][j] = __builtin_amdgcn_mfma_f32_16x16x32_bf16(
                            af[pa][i], bfr[j], acc[i][j], 0, 0, 0);
            }
        }
    }

#pragma unroll
    for (int i = 0; i < MT; ++i) {
        int mbase = m0 + (aslab0 + i) * 16 + quad * 4;
#pragma unroll
        for (int j = 0; j < NT; ++j) {
            int n = n0 + (bslab0 + j) * 16 + lrow;
            float bv = bias ? bias[n] : 0.f;
#pragma unroll
            for (int r = 0; r < 4; ++r) {
                size_t off = (size_t)(mbase + r) * ldc + n;
                float v = acc[i][j][r] + bv;
                if (act == 1) v = (v > 20.f) ? v : log1pf(__expf(v));
                if (addC) v += C[off];
                C[off] = v;
            }
        }
    }
}

// ---------------- generic tiled fp32 GEMM (x_proj only: N=64) ----------------
#define BKK 16
__global__ __launch_bounds__(256)
void gemm_k(const float* __restrict__ A, int lda,
            const float* __restrict__ W,
            const float* __restrict__ bias,
            float* __restrict__ C, int ldc,
            int M, int N, int K, int act, int addC)
{
    __shared__ float Asf[BKK][64 + 4];
    __shared__ float Bsf[BKK][64 + 4];
    const int tid = threadIdx.x;
    const int tx = tid & 15, ty = tid >> 4;
    const int m0 = blockIdx.y * 64, n0 = blockIdx.x * 64;
    float acc[4][4] = {{0.f}};

    for (int k0 = 0; k0 < K; k0 += BKK) {
#pragma unroll
        for (int j = 0; j < 4; ++j) {
            int idx = tid + 256 * j;
            int m = idx >> 4, kk = idx & 15;
            Asf[kk][m] = A[(size_t)(m0 + m) * lda + k0 + kk];
        }
#pragma unroll
        for (int j = 0; j < 4; ++j) {
            int idx = tid + 256 * j;
            int kk = idx >> 6, n = idx & 63;
            Bsf[kk][n] = W[(size_t)(k0 + kk) * N + n0 + n];
        }
        __syncthreads();
#pragma unroll
        for (int kk = 0; kk < BKK; ++kk) {
            float a[4], b[4];
#pragma unroll
            for (int e = 0; e < 4; ++e) a[e] = Asf[kk][ty * 4 + e];
#pragma unroll
            for (int e = 0; e < 4; ++e) b[e] = Bsf[kk][tx * 4 + e];
#pragma unroll
            for (int i = 0; i < 4; ++i)
#pragma unroll
                for (int j = 0; j < 4; ++j)
                    acc[i][j] = fmaf(a[i], b[j], acc[i][j]);
        }
        __syncthreads();
    }

#pragma unroll
    for (int i = 0; i < 4; ++i) {
        int row = m0 + ty * 4 + i;
#pragma unroll
        for (int j = 0; j < 4; ++j) {
            int col = n0 + tx * 4 + j;
            float v = acc[i][j];
            if (bias) v += bias[col];
            if (act == 1) v = (v > 20.f) ? v : log1pf(expf(v));
            size_t off = (size_t)row * ldc + col;
            if (addC) v += C[off];
            C[off] = v;
        }
    }
}

// ---------------- RMSNorm: one wave per row of 512 ----------------
__global__ __launch_bounds__(256)
void rmsnorm_k(const float* __restrict__ X, const float* __restrict__ w,
               float* __restrict__ O)
{
    int wid = threadIdx.x >> 6, lane = threadIdx.x & 63;
    int row = blockIdx.x * 4 + wid;
    const float* xr = X + (size_t)row * DMODEL;
    float v[8];
    float ss = 0.f;
#pragma unroll
    for (int j = 0; j < 8; ++j) { v[j] = xr[lane + 64 * j]; ss = fmaf(v[j], v[j], ss); }
#pragma unroll
    for (int off = 32; off >= 1; off >>= 1) ss += __shfl_xor(ss, off);
    float scale = rsqrtf(ss * (1.f / 512.f) + 1e-5f);
    float* orow = O + (size_t)row * DMODEL;
#pragma unroll
    for (int j = 0; j < 8; ++j) orow[lane + 64 * j] = v[j] * scale * w[lane + 64 * j];
}

// ---------------- causal depthwise conv (K=4) + SiLU ----------------
__global__ __launch_bounds__(256)
void conv_silu_k(const float* __restrict__ XZ, const float* __restrict__ cw,
                 const float* __restrict__ cb, float* __restrict__ XC)
{
    int idx = blockIdx.x * 256 + threadIdx.x;
    int d = idx & 1023;
    int t = (idx >> 10) & 511;
    int b = idx >> 19;
    float s = cb[d];
#pragma unroll
    for (int k = 0; k < 4; ++k) {
        int tt = t + k - 3;
        if (tt >= 0)
            s = fmaf(cw[d * 4 + k], XZ[((size_t)(b * 512 + tt)) * 2048 + d], s);
    }
    XC[idx] = s / (1.f + expf(-s));
}

// ---------------- chunked selective scan: thread per (b,chunk,d), 16 states in regs ----
// Phase 1: local scan (h0=0) -> local y (+u*D), chunk-end states SC[b][chunk][d][n],
//          delta-sum DS[b][chunk][d]. All global accesses coalesced along d.
__global__ __launch_bounds__(128)
void scan1_k(const float* __restrict__ DELTA, const float* __restrict__ XC,
             const float* __restrict__ DBL, const float* __restrict__ A_log,
             const float* __restrict__ Dsk, float* __restrict__ Y,
             float* __restrict__ SC, float* __restrict__ DS)
{
    __shared__ float BC[64][32];       // [t][0:16)=B, [16:32)=C  (broadcast reads)
    const int tid = threadIdx.x;
    const int d = blockIdx.x * 128 + tid;
    const int chunk = blockIdx.y;
    const int b = blockIdx.z;
    const int t0 = chunk * 64;

#pragma unroll
    for (int i = 0; i < 16; ++i) {
        int idx = tid + 128 * i;
        int t = idx >> 5, j = idx & 31;
        BC[t][j] = DBL[(size_t)(b * 512 + t0 + t) * 64 + 32 + j];
    }
    float Ac[16];
#pragma unroll
    for (int n = 0; n < 16; ++n) Ac[n] = -__expf(A_log[d * 16 + n]);
    float Dv = Dsk[d];
    __syncthreads();

    const float* dp = DELTA + ((size_t)(b * 512 + t0)) * 1024 + d;
    const float* up = XC    + ((size_t)(b * 512 + t0)) * 1024 + d;
    float* yp       = Y     + ((size_t)(b * 512 + t0)) * 1024 + d;

    float h[16];
#pragma unroll
    for (int n = 0; n < 16; ++n) h[n] = 0.f;
    float dsum = 0.f;

#pragma unroll 2
    for (int t = 0; t < 64; ++t) {
        float delta = dp[t * 1024];
        float u = up[t * 1024];
        dsum += delta;
        float du = delta * u;
        float y = 0.f;
#pragma unroll
        for (int n = 0; n < 16; ++n) {
            h[n] = fmaf(__expf(delta * Ac[n]), h[n], du * BC[t][n]);
            y = fmaf(h[n], BC[t][16 + n], y);
        }
        yp[t * 1024] = fmaf(u, Dv, y);
    }

    float* sc = SC + ((size_t)((b * 8 + chunk) * 1024 + d)) * 16;
#pragma unroll
    for (int n = 0; n < 16; ++n) sc[n] = h[n];
    DS[(size_t)(b * 8 + chunk) * 1024 + d] = dsum;
}

// Phase 2: inter-chunk carry, in-place over SC. thread per (b,d,n), n fastest.
__global__ __launch_bounds__(256)
void scan2_k(const float* __restrict__ A_log, float* __restrict__ SC,
             const float* __restrict__ DS)
{
    int gid = blockIdx.x * 256 + threadIdx.x;   // b*16384 + d*16 + n
    int n = gid & 15;
    int d = (gid >> 4) & 1023;
    int b = gid >> 14;
    float Ac = -__expf(A_log[d * 16 + n]);
    float carry = 0.f;
#pragma unroll
    for (int c = 0; c < 8; ++c) {
        size_t off = ((size_t)((b * 8 + c) * 1024 + d)) * 16 + n;
        float s = SC[off];
        SC[off] = carry;
        carry = fmaf(__expf(Ac * DS[(size_t)(b * 8 + c) * 1024 + d]), carry, s);
    }
}

// Phase 3: y += sum_n h0[n]*exp(Ac[n]*cumDelta_t)*C_t[n], then gate by silu(z).
__global__ __launch_bounds__(128)
void scan3_k(const float* __restrict__ DELTA, const float* __restrict__ DBL,
             const float* __restrict__ A_log, const float* __restrict__ H0,
             const float* __restrict__ XZ, float* __restrict__ Y)
{
    __shared__ float Cs[64][16];
    const int tid = threadIdx.x;
    const int d = blockIdx.x * 128 + tid;
    const int chunk = blockIdx.y;
    const int b = blockIdx.z;
    const int t0 = chunk * 64;

#pragma unroll
    for (int i = 0; i < 8; ++i) {
        int idx = tid + 128 * i;
        int t = idx >> 4, j = idx & 15;
        Cs[t][j] = DBL[(size_t)(b * 512 + t0 + t) * 64 + 48 + j];
    }
    float Ac[16], h0[16];
#pragma unroll
    for (int n = 0; n < 16; ++n) Ac[n] = -__expf(A_log[d * 16 + n]);
    const float* h0p = H0 + ((size_t)((b * 8 + chunk) * 1024 + d)) * 16;
#pragma unroll
    for (int n = 0; n < 16; ++n) h0[n] = h0p[n];
    __syncthreads();

    const float* dp = DELTA + ((size_t)(b * 512 + t0)) * 1024 + d;
    const float* zp = XZ    + ((size_t)(b * 512 + t0)) * 2048 + 1024 + d;
    float* yp       = Y     + ((size_t)(b * 512 + t0)) * 1024 + d;

    float cum = 0.f;
    if (chunk == 0) {
        // h0 == 0: gating only
#pragma unroll 2
        for (int t = 0; t < 64; ++t) {
            float z = zp[t * 2048];
            yp[t * 1024] *= z / (1.f + __expf(-z));
        }
    } else {
#pragma unroll 2
        for (int t = 0; t < 64; ++t) {
            float delta = dp[t * 1024];
            cum += delta;
            float p = 0.f;
#pragma unroll
            for (int n = 0; n < 16; ++n)
                p = fmaf(h0[n] * __expf(Ac[n] * cum), Cs[t][n], p);
            float z = zp[t * 2048];
            float yv = yp[t * 1024] + p;
            yp[t * 1024] = yv * (z / (1.f + __expf(-z)));
        }
    }
}

// ---------------- attention: block per (b, h, 16 q-rows) ----------------
__global__ __launch_bounds__(256)
void attn_k(const float* __restrict__ Q, const float* __restrict__ K,
            const float* __restrict__ V, float* __restrict__ CTX)
{
    __shared__ float Qs[16][128];
    __shared__ float Ks[64][129];
    __shared__ float S[16][257];
    int b = blockIdx.z, h = blockIdx.y, q0 = blockIdx.x * 16;
    int tid = threadIdx.x;

#pragma unroll
    for (int j = 0; j < 8; ++j) {
        int idx = tid + 256 * j;
        int qi = idx >> 7, dd = idx & 127;
        Qs[qi][dd] = Q[((size_t)(b * 512 + q0 + qi)) * 512 + h * 128 + dd];
    }
    const float scale = 0.08838834764831845f;

    for (int kb = 0; kb < 4; ++kb) {
        __syncthreads();
#pragma unroll
        for (int j = 0; j < 32; ++j) {
            int idx = tid + 256 * j;
            int ki = idx >> 7, dd = idx & 127;
            Ks[ki][dd] = K[((size_t)(b * 256 + kb * 64 + ki)) * 512 + h * 128 + dd];
        }
        __syncthreads();
        int kl = tid & 63, qb = tid >> 6;
        float sacc[4] = {0.f, 0.f, 0.f, 0.f};
        for (int dd = 0; dd < 128; ++dd) {
            float kvv = Ks[kl][dd];
#pragma unroll
            for (int p = 0; p < 4; ++p)
                sacc[p] = fmaf(Qs[qb * 4 + p][dd], kvv, sacc[p]);
        }
#pragma unroll
        for (int p = 0; p < 4; ++p)
            S[qb * 4 + p][kb * 64 + kl] = sacc[p] * scale;
    }
    __syncthreads();

    {
        int row = tid >> 4, sub = tid & 15;
        float mx = -1e30f;
        for (int j = sub; j < 256; j += 16) mx = fmaxf(mx, S[row][j]);
        mx = fmaxf(mx, __shfl_xor(mx, 1));
        mx = fmaxf(mx, __shfl_xor(mx, 2));
        mx = fmaxf(mx, __shfl_xor(mx, 4));
        mx = fmaxf(mx, __shfl_xor(mx, 8));
        float sum = 0.f;
        for (int j = sub; j < 256; j += 16) {
            float e = __expf(S[row][j] - mx);
            S[row][j] = e;
            sum += e;
        }
        sum += __shfl_xor(sum, 1);
        sum += __shfl_xor(sum, 2);
        sum += __shfl_xor(sum, 4);
        sum += __shfl_xor(sum, 8);
        float inv = 1.f / sum;
        for (int j = sub; j < 256; j += 16) S[row][j] *= inv;
    }
    __syncthreads();

    int dd = tid & 127, qsel = tid >> 7;
    float acc[8];
#pragma unroll
    for (int p = 0; p < 8; ++p) acc[p] = 0.f;
    for (int kk = 0; kk < 256; ++kk) {
        float vv = V[((size_t)(b * 256 + kk)) * 512 + h * 128 + dd];
#pragma unroll
        for (int p = 0; p < 8; ++p)
            acc[p] = fmaf(S[qsel * 8 + p][kk], vv, acc[p]);
    }
#pragma unroll
    for (int p = 0; p < 8; ++p) {
        int qi = qsel * 8 + p;
        CTX[((size_t)(b * 512 + q0 + qi)) * 512 + h * 128 + dd] = acc[p];
    }
}

// ---------------- final linear (512->6) + argmax, one wave per row ----------------
__global__ __launch_bounds__(256)
void head_k(const float* __restrict__ T2, const float* __restrict__ Wout,
            const float* __restrict__ bout, float* __restrict__ out)
{
    int wid = threadIdx.x >> 6, lane = threadIdx.x & 63;
    int row = blockIdx.x * 4 + wid;
    float acc[6] = {0.f, 0.f, 0.f, 0.f, 0.f, 0.f};
    const float* tr = T2 + (size_t)row * 512;
#pragma unroll
    for (int j = 0; j < 8; ++j) {
        int k = lane + 64 * j;
        float t = tr[k];
#pragma unroll
        for (int c = 0; c < 6; ++c) acc[c] = fmaf(t, Wout[k * 6 + c], acc[c]);
    }
#pragma unroll
    for (int c = 0; c < 6; ++c) {
#pragma unroll
        for (int off = 32; off >= 1; off >>= 1) acc[c] += __shfl_xor(acc[c], off);
    }
    if (lane == 0) {
        float best = -1e30f;
        int bi = 0;
#pragma unroll
        for (int c = 0; c < 6; ++c) {
            float v = acc[c] + bout[c];
            out[(size_t)row * 6 + c] = v;
            if (v > best) { best = v; bi = c; }
        }
        out[(size_t)4096 * 6 + row] = (float)bi;
    }
}

extern "C" void kernel_launch(void* const* d_in, const int* in_sizes, int n_in,
                              void* d_out, int out_size, void* d_ws, size_t ws_size,
                              hipStream_t stream)
{
    (void)in_sizes; (void)n_in; (void)out_size; (void)ws_size;
    const float* agent      = (const float*)d_in[0];
    const float* lane       = (const float*)d_in[1];
    const float* lane_in_W  = (const float*)d_in[2];
    const float* lane_in_b  = (const float*)d_in[3];
    const float* norm_w     = (const float*)d_in[4];
    const float* in_proj_W  = (const float*)d_in[5];
    const float* conv_w     = (const float*)d_in[6];
    const float* conv_b     = (const float*)d_in[7];
    const float* x_proj_W   = (const float*)d_in[8];
    const float* dt_proj_W  = (const float*)d_in[9];
    const float* dt_proj_b  = (const float*)d_in[10];
    const float* A_log      = (const float*)d_in[11];
    const float* D_skip     = (const float*)d_in[12];
    const float* out_proj_W = (const float*)d_in[13];
    const float* final_norm_w = (const float*)d_in[14];
    const float* Wq = (const float*)d_in[15];
    const float* Wk = (const float*)d_in[16];
    const float* Wv = (const float*)d_in[17];
    const float* Wo = (const float*)d_in[18];
    const float* bq = (const float*)d_in[19];
    const float* bk = (const float*)d_in[20];
    const float* bv = (const float*)d_in[21];
    const float* bo = (const float*)d_in[22];
    const float* lin_in_W  = (const float*)d_in[23];
    const float* lin_in_b  = (const float*)d_in[24];
    const float* lin_out_W = (const float*)d_in[25];
    const float* lin_out_b = (const float*)d_in[26];

    // Workspace: same 97 MB footprint that passed tripwires (rounds 1/3/4/5).
    float* ws = (float*)d_ws;
    float* X     = ws;                      // 2M floats (4096 x 512)
    float* H     = X + (1 << 21);           // 2M (rmsnorm out; dead during scans)
    float* XZ    = H + (1 << 21);           // 8M  (4096 x 2048)
    float* XC    = XZ + (1 << 23);          // 4M  (4096 x 1024)
    float* DELTA = XC + (1 << 22);          // 4M
    float* Y     = DELTA + (1 << 22);       // 4M
    float* DBL   = Y + (1 << 22);           // 256K (4096 x 64)
    float* SCb   = H;                       // 1M  SC[b][chunk][d][n] (aliases H)
    float* DSb   = H + (1 << 20);           // 64K DS[b][chunk][d]   (aliases H)
    float* Qb  = XZ;                        // 2M
    float* Kb  = XZ + (1 << 21);            // 1M (2048 x 512)
    float* Vb  = Kb + (1 << 20);            // 1M
    float* CTX = Vb + (1 << 20);            // 2M
    float* AO  = CTX + (1 << 21);           // 2M
    float* T2  = XC;                        // 2M

    dim3 blk(256);
    dim3 sblk(128);
    dim3 sgrid(8, 8, 8);                    // (d-group, chunk, b)

    // x = lane_features @ lane_in_W + b   (4096x128 @ 128x512)
    gemm6<64, 64, 2, 2><<<dim3(8, 64), blk, 0, stream>>>(
        lane, 128, lane_in_W, lane_in_b, X, 512, 4096, 512, 128, 0, 0);

    for (int i = 0; i < 4; ++i) {
        rmsnorm_k<<<1024, blk, 0, stream>>>(X, norm_w + i * 512, H);
        // xz = h @ in_proj  (4096x512 @ 512x2048)
        gemm6<128, 128, 2, 2><<<dim3(16, 32), blk, 0, stream>>>(
            H, 512, in_proj_W + (size_t)i * 512 * 2048, nullptr, XZ, 2048,
            4096, 2048, 512, 0, 0);
        conv_silu_k<<<16384, blk, 0, stream>>>(XZ, conv_w + i * 4096, conv_b + i * 1024, XC);
        // dbl = xc @ x_proj  (4096x1024 @ 1024x64)  -- N=64, fp32 kernel
        gemm_k<<<dim3(1, 64), blk, 0, stream>>>(XC, 1024, x_proj_W + (size_t)i * 1024 * 64,
                                                nullptr, DBL, 64, 4096, 64, 1024, 0, 0);
        // delta = softplus(dt @ dt_proj + b)  (4096x32 @ 32x1024)
        gemm6<64, 64, 2, 2><<<dim3(16, 64), blk, 0, stream>>>(
            DBL, 64, dt_proj_W + (size_t)i * 32 * 1024, dt_proj_b + i * 1024,
            DELTA, 1024, 4096, 1024, 32, 1, 0);
        // chunked scan (3 phases) + fused gating
        scan1_k<<<sgrid, sblk, 0, stream>>>(DELTA, XC, DBL, A_log + (size_t)i * 1024 * 16,
                                            D_skip + i * 1024, Y, SCb, DSb);
        scan2_k<<<512, blk, 0, stream>>>(A_log + (size_t)i * 1024 * 16, SCb, DSb);
        scan3_k<<<sgrid, sblk, 0, stream>>>(DELTA, DBL, A_log + (size_t)i * 1024 * 16,
                                            SCb, XZ, Y);
        // x += ygated @ out_proj  (4096x1024 @ 1024x512)
        gemm6<64, 64, 2, 2><<<dim3(8, 64), blk, 0, stream>>>(
            Y, 1024, out_proj_W + (size_t)i * 1024 * 512, nullptr, X, 512,
            4096, 512, 1024, 0, 1);
    }

    rmsnorm_k<<<1024, blk, 0, stream>>>(X, final_norm_w, H);   // enhanced

    gemm6<64, 64, 2, 2><<<dim3(8, 64), blk, 0, stream>>>(
        H, 512, Wq, bq, Qb, 512, 4096, 512, 512, 0, 0);
    gemm6<64, 64, 2, 2><<<dim3(8, 32), blk, 0, stream>>>(
        agent, 512, Wk, bk, Kb, 512, 2048, 512, 512, 0, 0);
    gemm6<64, 64, 2, 2><<<dim3(8, 32), blk, 0, stream>>>(
        agent, 512, Wv, bv, Vb, 512, 2048, 512, 512, 0, 0);
    attn_k<<<dim3(32, 4, 8), blk, 0, stream>>>(Qb, Kb, Vb, CTX);
    gemm6<64, 64, 2, 2><<<dim3(8, 64), blk, 0, stream>>>(
        CTX, 512, Wo, bo, AO, 512, 4096, 512, 512, 0, 0);
    gemm6<64, 64, 2, 2><<<dim3(8, 64), blk, 0, stream>>>(
        AO, 512, lin_in_W, lin_in_b, T2, 512, 4096, 512, 512, 0, 0);
    head_k<<<1024, blk, 0, stream>>>(T2, lin_out_W, lin_out_b, (float*)d_out);
}

// Round 7
// 1578.823 us; speedup vs baseline: 1.7923x; 1.0416x over previous
//
#include <hip/hip_runtime.h>
#include <math.h>

#define BATCH 8
#define LSEQ 512
#define LAGENT 256
#define DMODEL 512
#define DINNER 1024
#define DSTATE 16
#define DTRANK 32
#define NHEAD 4
#define DHEAD 128
#define NLANES 6

typedef __attribute__((ext_vector_type(8))) short bf16x8;
typedef __attribute__((ext_vector_type(4))) float f32x4;

// Exact 3-way bf16 split: x = h + m + l + O(2^-24 |x|); all subtractions exact.
__device__ __forceinline__ void split3(float x, short& h, short& m, short& l)
{
    unsigned hb = __float_as_uint(x) & 0xFFFF0000u;
    h = (short)(hb >> 16);
    float r1 = x - __uint_as_float(hb);
    unsigned mb = __float_as_uint(r1) & 0xFFFF0000u;
    m = (short)(mb >> 16);
    float r2 = r1 - __uint_as_float(mb);
    l = (short)(__float_as_uint(r2) >> 16);
}

// ---------------- bf16x6 emulated-fp32 MFMA GEMM, fragment-linear LDS ----------------
template<int BM, int BN, int WM, int WN>
__global__ __launch_bounds__(256)
void gemm6(const float* __restrict__ A, int lda,
           const float* __restrict__ W,
           const float* __restrict__ bias,
           float* __restrict__ C, int ldc,
           int M, int N, int K, int act, int addC)
{
    constexpr int MT = BM / WM / 16;
    constexpr int NT = BN / WN / 16;
    constexpr int ASL = BM / 16;
    constexpr int BSL = BN / 16;
    __shared__ short Asl[3][ASL * 520];
    __shared__ short Bsl[3][BSL * 520];

    const int tid = threadIdx.x;
    const int w = tid >> 6, lane = tid & 63;
    const int lrow = lane & 15, quad = lane >> 4;
    const int aslab0 = (w % WM) * MT;
    const int bslab0 = (w / WM) * NT;
    const int m0 = blockIdx.y * BM, n0 = blockIdx.x * BN;

    f32x4 acc[MT][NT] = {};

    for (int k0 = 0; k0 < K; k0 += 32) {
        __syncthreads();
#pragma unroll
        for (int i = 0; i < BM / 32; ++i) {
            int v = tid + 256 * i;
            int row = v >> 3;
            int kq = (v & 7) * 4;
            float4 val = *(const float4*)&A[(size_t)(m0 + row) * lda + k0 + kq];
            int off = (row >> 4) * 520 + (((kq >> 3) << 4) + (row & 15)) * 8 + (kq & 7);
            short h[4], mm_[4], l[4];
            split3(val.x, h[0], mm_[0], l[0]);
            split3(val.y, h[1], mm_[1], l[1]);
            split3(val.z, h[2], mm_[2], l[2]);
            split3(val.w, h[3], mm_[3], l[3]);
            *(short4*)&Asl[0][off] = make_short4(h[0], h[1], h[2], h[3]);
            *(short4*)&Asl[1][off] = make_short4(mm_[0], mm_[1], mm_[2], mm_[3]);
            *(short4*)&Asl[2][off] = make_short4(l[0], l[1], l[2], l[3]);
        }
        constexpr int NPQS = (BN == 128) ? 5 : 4;
#pragma unroll
        for (int i = 0; i < BN / 64; ++i) {
            int v = tid + 256 * i;
            int kp = v >> NPQS;
            int nc = (v & ((1 << NPQS) - 1)) * 4;
            int k1 = kp * 2;
            float4 r0 = *(const float4*)&W[(size_t)(k0 + k1) * N + n0 + nc];
            float4 r1 = *(const float4*)&W[(size_t)(k0 + k1 + 1) * N + n0 + nc];
            const float e0[4] = {r0.x, r0.y, r0.z, r0.w};
            const float e1[4] = {r1.x, r1.y, r1.z, r1.w};
#pragma unroll
            for (int e = 0; e < 4; ++e) {
                int n = nc + e;
                int off = (n >> 4) * 520 + (((k1 >> 3) << 4) + (n & 15)) * 8 + (k1 & 7);
                short h0, m0_, l0, h1, m1_, l1;
                split3(e0[e], h0, m0_, l0);
                split3(e1[e], h1, m1_, l1);
                *(short2*)&Bsl[0][off] = make_short2(h0, h1);
                *(short2*)&Bsl[1][off] = make_short2(m0_, m1_);
                *(short2*)&Bsl[2][off] = make_short2(l0, l1);
            }
        }
        __syncthreads();

        bf16x8 af[3][MT];
#pragma unroll
        for (int p = 0; p < 3; ++p)
#pragma unroll
            for (int i = 0; i < MT; ++i)
                af[p][i] = *(const bf16x8*)&Asl[p][(aslab0 + i) * 520 + lane * 8];

#pragma unroll
        for (int pb = 0; pb < 3; ++pb) {
            bf16x8 bfr[NT];
#pragma unroll
            for (int j = 0; j < NT; ++j)
                bfr[j] = *(const bf16x8*)&Bsl[pb][(bslab0 + j) * 520 + lane * 8];
            const int npa = (pb == 0) ? 3 : (pb == 1 ? 2 : 1);
#pragma unroll
            for (int pa = 0; pa < 3; ++pa) {
                if (pa >= npa) break;
#pragma unroll
                for (int i = 0; i < MT; ++i)
#pragma unroll
                    for (int j = 0; j < NT; ++j)
                        acc[i][j] = __builtin_amdgcn_mfma_f32_16x16x32_bf16(
                            af[pa][i], bfr[j], acc[i][j], 0, 0, 0);
            }
        }
    }

#pragma unroll
    for (int i = 0; i < MT; ++i) {
        int mbase = m0 + (aslab0 + i) * 16 + quad * 4;
#pragma unroll
        for (int j = 0; j < NT; ++j) {
            int n = n0 + (bslab0 + j) * 16 + lrow;
            float bv = bias ? bias[n] : 0.f;
#pragma unroll
            for (int r = 0; r < 4; ++r) {
                size_t off = (size_t)(mbase + r) * ldc + n;
                float v = acc[i][j][r] + bv;
                if (act == 1) v = (v > 20.f) ? v : log1pf(__expf(v));
                if (addC) v += C[off];
                C[off] = v;
            }
        }
    }
}

// ---------------- generic tiled fp32 GEMM (x_proj only: N=64) ----------------
#define BKK 16
__global__ __launch_bounds__(256)
void gemm_k(const float* __restrict__ A, int lda,
            const float* __restrict__ W,
            const float* __restrict__ bias,
            float* __restrict__ C, int ldc,
            int M, int N, int K, int act, int addC)
{
    __shared__ float Asf[BKK][64 + 4];
    __shared__ float Bsf[BKK][64 + 4];
    const int tid = threadIdx.x;
    const int tx = tid & 15, ty = tid >> 4;
    const int m0 = blockIdx.y * 64, n0 = blockIdx.x * 64;
    float acc[4][4] = {{0.f}};

    for (int k0 = 0; k0 < K; k0 += BKK) {
#pragma unroll
        for (int j = 0; j < 4; ++j) {
            int idx = tid + 256 * j;
            int m = idx >> 4, kk = idx & 15;
            Asf[kk][m] = A[(size_t)(m0 + m) * lda + k0 + kk];
        }
#pragma unroll
        for (int j = 0; j < 4; ++j) {
            int idx = tid + 256 * j;
            int kk = idx >> 6, n = idx & 63;
            Bsf[kk][n] = W[(size_t)(k0 + kk) * N + n0 + n];
        }
        __syncthreads();
#pragma unroll
        for (int kk = 0; kk < BKK; ++kk) {
            float a[4], b[4];
#pragma unroll
            for (int e = 0; e < 4; ++e) a[e] = Asf[kk][ty * 4 + e];
#pragma unroll
            for (int e = 0; e < 4; ++e) b[e] = Bsf[kk][tx * 4 + e];
#pragma unroll
            for (int i = 0; i < 4; ++i)
#pragma unroll
                for (int j = 0; j < 4; ++j)
                    acc[i][j] = fmaf(a[i], b[j], acc[i][j]);
        }
        __syncthreads();
    }

#pragma unroll
    for (int i = 0; i < 4; ++i) {
        int row = m0 + ty * 4 + i;
#pragma unroll
        for (int j = 0; j < 4; ++j) {
            int col = n0 + tx * 4 + j;
            float v = acc[i][j];
            if (bias) v += bias[col];
            if (act == 1) v = (v > 20.f) ? v : log1pf(expf(v));
            size_t off = (size_t)row * ldc + col;
            if (addC) v += C[off];
            C[off] = v;
        }
    }
}

// ---------------- RMSNorm: one wave per row of 512 ----------------
__global__ __launch_bounds__(256)
void rmsnorm_k(const float* __restrict__ X, const float* __restrict__ w,
               float* __restrict__ O)
{
    int wid = threadIdx.x >> 6, lane = threadIdx.x & 63;
    int row = blockIdx.x * 4 + wid;
    const float* xr = X + (size_t)row * DMODEL;
    float v[8];
    float ss = 0.f;
#pragma unroll
    for (int j = 0; j < 8; ++j) { v[j] = xr[lane + 64 * j]; ss = fmaf(v[j], v[j], ss); }
#pragma unroll
    for (int off = 32; off >= 1; off >>= 1) ss += __shfl_xor(ss, off);
    float scale = rsqrtf(ss * (1.f / 512.f) + 1e-5f);
    float* orow = O + (size_t)row * DMODEL;
#pragma unroll
    for (int j = 0; j < 8; ++j) orow[lane + 64 * j] = v[j] * scale * w[lane + 64 * j];
}

// ---------------- causal depthwise conv (K=4) + SiLU, float4 over d ----------------
__global__ __launch_bounds__(256)
void conv_silu_k(const float* __restrict__ XZ, const float* __restrict__ cw,
                 const float* __restrict__ cb, float* __restrict__ XC)
{
    int idx = blockIdx.x * 256 + threadIdx.x;   // over b*L*256 d-groups
    int d4 = (idx & 255) * 4;
    int t = (idx >> 8) & 511;
    int b = idx >> 17;
    float4 wv[4];
#pragma unroll
    for (int e = 0; e < 4; ++e) wv[e] = *(const float4*)&cw[(d4 + e) * 4];
    float4 bv = *(const float4*)&cb[d4];
    float s[4] = {bv.x, bv.y, bv.z, bv.w};
#pragma unroll
    for (int k = 0; k < 4; ++k) {
        int tt = t + k - 3;
        if (tt >= 0) {
            float4 x = *(const float4*)&XZ[((size_t)(b * 512 + tt)) * 2048 + d4];
            const float xe[4] = {x.x, x.y, x.z, x.w};
            const float we[4] = {wv[0][k], wv[1][k], wv[2][k], wv[3][k]};
#pragma unroll
            for (int e = 0; e < 4; ++e) s[e] = fmaf(we[e], xe[e], s[e]);
        }
    }
    float4 o;
    o.x = s[0] / (1.f + __expf(-s[0]));
    o.y = s[1] / (1.f + __expf(-s[1]));
    o.z = s[2] / (1.f + __expf(-s[2]));
    o.w = s[3] / (1.f + __expf(-s[3]));
    *(float4*)&XC[((size_t)(b * 512 + t)) * 1024 + d4] = o;
}

// ---------------- chunked selective scan: thread per (b,chunk,d), 16 states in regs ----
__global__ __launch_bounds__(128)
void scan1_k(const float* __restrict__ DELTA, const float* __restrict__ XC,
             const float* __restrict__ DBL, const float* __restrict__ A_log,
             const float* __restrict__ Dsk, float* __restrict__ Y,
             float* __restrict__ SC, float* __restrict__ DS)
{
    __shared__ float BC[64][32];       // [t][0:16)=B, [16:32)=C  (broadcast reads)
    const int tid = threadIdx.x;
    const int d = blockIdx.x * 128 + tid;
    const int chunk = blockIdx.y;
    const int b = blockIdx.z;
    const int t0 = chunk * 64;

#pragma unroll
    for (int i = 0; i < 16; ++i) {
        int idx = tid + 128 * i;
        int t = idx >> 5, j = idx & 31;
        BC[t][j] = DBL[(size_t)(b * 512 + t0 + t) * 64 + 32 + j];
    }
    float Ac[16];
#pragma unroll
    for (int n = 0; n < 16; ++n) Ac[n] = -__expf(A_log[d * 16 + n]);
    float Dv = Dsk[d];
    __syncthreads();

    const float* dp = DELTA + ((size_t)(b * 512 + t0)) * 1024 + d;
    const float* up = XC    + ((size_t)(b * 512 + t0)) * 1024 + d;
    float* yp       = Y     + ((size_t)(b * 512 + t0)) * 1024 + d;

    float h[16];
#pragma unroll
    for (int n = 0; n < 16; ++n) h[n] = 0.f;
    float dsum = 0.f;

#pragma unroll 2
    for (int t = 0; t < 64; ++t) {
        float delta = dp[t * 1024];
        float u = up[t * 1024];
        dsum += delta;
        float du = delta * u;
        float y = 0.f;
#pragma unroll
        for (int n = 0; n < 16; ++n) {
            h[n] = fmaf(__expf(delta * Ac[n]), h[n], du * BC[t][n]);
            y = fmaf(h[n], BC[t][16 + n], y);
        }
        yp[t * 1024] = fmaf(u, Dv, y);
    }

    float* sc = SC + ((size_t)((b * 8 + chunk) * 1024 + d)) * 16;
#pragma unroll
    for (int n = 0; n < 16; ++n) sc[n] = h[n];
    DS[(size_t)(b * 8 + chunk) * 1024 + d] = dsum;
}

__global__ __launch_bounds__(256)
void scan2_k(const float* __restrict__ A_log, float* __restrict__ SC,
             const float* __restrict__ DS)
{
    int gid = blockIdx.x * 256 + threadIdx.x;   // b*16384 + d*16 + n
    int n = gid & 15;
    int d = (gid >> 4) & 1023;
    int b = gid >> 14;
    float Ac = -__expf(A_log[d * 16 + n]);
    float carry = 0.f;
#pragma unroll
    for (int c = 0; c < 8; ++c) {
        size_t off = ((size_t)((b * 8 + c) * 1024 + d)) * 16 + n;
        float s = SC[off];
        SC[off] = carry;
        carry = fmaf(__expf(Ac * DS[(size_t)(b * 8 + c) * 1024 + d]), carry, s);
    }
}

__global__ __launch_bounds__(128)
void scan3_k(const float* __restrict__ DELTA, const float* __restrict__ DBL,
             const float* __restrict__ A_log, const float* __restrict__ H0,
             const float* __restrict__ XZ, float* __restrict__ Y)
{
    __shared__ float Cs[64][16];
    const int tid = threadIdx.x;
    const int d = blockIdx.x * 128 + tid;
    const int chunk = blockIdx.y;
    const int b = blockIdx.z;
    const int t0 = chunk * 64;

#pragma unroll
    for (int i = 0; i < 8; ++i) {
        int idx = tid + 128 * i;
        int t = idx >> 4, j = idx & 15;
        Cs[t][j] = DBL[(size_t)(b * 512 + t0 + t) * 64 + 48 + j];
    }
    float Ac[16], h0[16];
#pragma unroll
    for (int n = 0; n < 16; ++n) Ac[n] = -__expf(A_log[d * 16 + n]);
    const float* h0p = H0 + ((size_t)((b * 8 + chunk) * 1024 + d)) * 16;
#pragma unroll
    for (int n = 0; n < 16; ++n) h0[n] = h0p[n];
    __syncthreads();

    const float* dp = DELTA + ((size_t)(b * 512 + t0)) * 1024 + d;
    const float* zp = XZ    + ((size_t)(b * 512 + t0)) * 2048 + 1024 + d;
    float* yp       = Y     + ((size_t)(b * 512 + t0)) * 1024 + d;

    float cum = 0.f;
    if (chunk == 0) {
#pragma unroll 2
        for (int t = 0; t < 64; ++t) {
            float z = zp[t * 2048];
            yp[t * 1024] *= z / (1.f + __expf(-z));
        }
    } else {
#pragma unroll 2
        for (int t = 0; t < 64; ++t) {
            float delta = dp[t * 1024];
            cum += delta;
            float p = 0.f;
#pragma unroll
            for (int n = 0; n < 16; ++n)
                p = fmaf(h0[n] * __expf(Ac[n] * cum), Cs[t][n], p);
            float z = zp[t * 2048];
            float yv = yp[t * 1024] + p;
            yp[t * 1024] = yv * (z / (1.f + __expf(-z)));
        }
    }
}

// ---------------- MFMA flash attention, exact fp32 via bf16x6 ----------------
// block per (b, h, 64 q-rows); 4 waves x 16 q each. K/V streamed in 64-kv chunks
// through fragment-linear LDS planes with register prefetch; S & O in registers.
__global__ __launch_bounds__(256, 1)
void attn_mfma(const float* __restrict__ Qm, const float* __restrict__ Km,
               const float* __restrict__ Vm, float* __restrict__ CTX)
{
    __shared__ short KVs[3][16 * 520];      // 16 frag-tiles per plane
    __shared__ float Ps[4][16 * 260];       // per-wave P strip (16 q x 256 kv, pad 260)
    const int tid = threadIdx.x;
    const int w = tid >> 6, lane = tid & 63;
    const int lrow = lane & 15, quad = lane >> 4;
    const int b = blockIdx.z, h = blockIdx.y;
    const int qw = blockIdx.x * 64 + w * 16;

    // ---- Q fragments in registers (3 planes x 4 k-frags) ----
    bf16x8 qf[3][4];
    {
        const float* qp = Qm + ((size_t)(b * 512 + qw + lrow)) * 512 + h * 128 + quad * 8;
#pragma unroll
        for (int kb = 0; kb < 4; ++kb) {
            float4 v0 = *(const float4*)(qp + kb * 32);
            float4 v1 = *(const float4*)(qp + kb * 32 + 4);
            const float e[8] = {v0.x, v0.y, v0.z, v0.w, v1.x, v1.y, v1.z, v1.w};
#pragma unroll
            for (int j = 0; j < 8; ++j) {
                short hh, mm, ll;
                split3(e[j], hh, mm, ll);
                qf[0][kb][j] = hh; qf[1][kb][j] = mm; qf[2][kb][j] = ll;
            }
        }
    }

    const int sdd = (tid & 31) * 4;        // K-staging: dd quad
    const int skvb = tid >> 5;             // K-staging: kv base
    f32x4 sa[4][4] = {};                   // S tiles [chunk][slab]

    // prefetch K chunk 0
    float4 kpre[8];
#pragma unroll
    for (int i = 0; i < 8; ++i)
        kpre[i] = *(const float4*)&Km[((size_t)(b * 256 + skvb + 8 * i)) * 512 + h * 128 + sdd];

    for (int c = 0; c < 4; ++c) {
        if (c) __syncthreads();
        // write prefetched K chunk into planes
        {
            const int kb = sdd >> 5, qd = (sdd >> 3) & 3, jd = sdd & 7;
#pragma unroll
            for (int i = 0; i < 8; ++i) {
                int kv = skvb + 8 * i;
                int off = ((kv >> 4) * 4 + kb) * 520 + ((kv & 15) + 16 * qd) * 8 + jd;
                short h0,m0,l0,h1,m1,l1,h2,m2,l2,h3,m3,l3;
                split3(kpre[i].x,h0,m0,l0); split3(kpre[i].y,h1,m1,l1);
                split3(kpre[i].z,h2,m2,l2); split3(kpre[i].w,h3,m3,l3);
                *(short4*)&KVs[0][off] = make_short4(h0,h1,h2,h3);
                *(short4*)&KVs[1][off] = make_short4(m0,m1,m2,m3);
                *(short4*)&KVs[2][off] = make_short4(l0,l1,l2,l3);
            }
        }
        if (c < 3) {
#pragma unroll
            for (int i = 0; i < 8; ++i)
                kpre[i] = *(const float4*)&Km[((size_t)(b * 256 + (c + 1) * 64 + skvb + 8 * i)) * 512 + h * 128 + sdd];
        }
        __syncthreads();
        // S chunk: 4 kv-slabs x 4 k-frags x 6 products
#pragma unroll
        for (int s = 0; s < 4; ++s) {
#pragma unroll
            for (int kb = 0; kb < 4; ++kb) {
                bf16x8 kf[3];
#pragma unroll
                for (int p = 0; p < 3; ++p)
                    kf[p] = *(const bf16x8*)&KVs[p][(s * 4 + kb) * 520 + lane * 8];
                sa[c][s] = __builtin_amdgcn_mfma_f32_16x16x32_bf16(qf[0][kb], kf[0], sa[c][s], 0, 0, 0);
                sa[c][s] = __builtin_amdgcn_mfma_f32_16x16x32_bf16(qf[0][kb], kf[1], sa[c][s], 0, 0, 0);
                sa[c][s] = __builtin_amdgcn_mfma_f32_16x16x32_bf16(qf[1][kb], kf[0], sa[c][s], 0, 0, 0);
                sa[c][s] = __builtin_amdgcn_mfma_f32_16x16x32_bf16(qf[0][kb], kf[2], sa[c][s], 0, 0, 0);
                sa[c][s] = __builtin_amdgcn_mfma_f32_16x16x32_bf16(qf[1][kb], kf[1], sa[c][s], 0, 0, 0);
                sa[c][s] = __builtin_amdgcn_mfma_f32_16x16x32_bf16(qf[2][kb], kf[0], sa[c][s], 0, 0, 0);
            }
        }
    }

    // ---- softmax in registers (rows = quad*4+r, cols distributed on lrow) ----
    const float scale = 0.08838834764831845f;
    float mx[4] = {-1e30f, -1e30f, -1e30f, -1e30f};
#pragma unroll
    for (int c = 0; c < 4; ++c)
#pragma unroll
        for (int s = 0; s < 4; ++s)
#pragma unroll
            for (int r = 0; r < 4; ++r) {
                sa[c][s][r] *= scale;
                mx[r] = fmaxf(mx[r], sa[c][s][r]);
            }
#pragma unroll
    for (int r = 0; r < 4; ++r) {
        mx[r] = fmaxf(mx[r], __shfl_xor(mx[r], 1));
        mx[r] = fmaxf(mx[r], __shfl_xor(mx[r], 2));
        mx[r] = fmaxf(mx[r], __shfl_xor(mx[r], 4));
        mx[r] = fmaxf(mx[r], __shfl_xor(mx[r], 8));
    }
    float sum[4] = {0.f, 0.f, 0.f, 0.f};
#pragma unroll
    for (int c = 0; c < 4; ++c)
#pragma unroll
        for (int s = 0; s < 4; ++s)
#pragma unroll
            for (int r = 0; r < 4; ++r) {
                float e = __expf(sa[c][s][r] - mx[r]);
                sa[c][s][r] = e;
                sum[r] += e;
            }
#pragma unroll
    for (int r = 0; r < 4; ++r) {
        sum[r] += __shfl_xor(sum[r], 1);
        sum[r] += __shfl_xor(sum[r], 2);
        sum[r] += __shfl_xor(sum[r], 4);
        sum[r] += __shfl_xor(sum[r], 8);
        sum[r] = 1.f / sum[r];
    }
    {
        float* ps = &Ps[w][0];
#pragma unroll
        for (int c = 0; c < 4; ++c)
#pragma unroll
            for (int s = 0; s < 4; ++s)
#pragma unroll
                for (int r = 0; r < 4; ++r)
                    ps[(quad * 4 + r) * 260 + c * 64 + s * 16 + lrow] = sa[c][s][r] * sum[r];
    }

    // ---- PV: stream V chunks; P read from own strip (no cross-wave dep) ----
    const int vdd4 = (tid & 31) * 4;
    const int vkvg = tid >> 5;
    f32x4 oa[8] = {};
    float4 vpre[8];
#pragma unroll
    for (int i = 0; i < 2; ++i) {
        int kv0 = (vkvg + 8 * i) * 4;
#pragma unroll
        for (int rr = 0; rr < 4; ++rr)
            vpre[i * 4 + rr] = *(const float4*)&Vm[((size_t)(b * 256 + kv0 + rr)) * 512 + h * 128 + vdd4];
    }

    for (int c = 0; c < 4; ++c) {
        __syncthreads();
        // write prefetched V chunk: element (dd, kv) -> plane[(dd>>4)*2 + kv>>5][...]
        {
#pragma unroll
            for (int i = 0; i < 2; ++i) {
                int kv0 = (vkvg + 8 * i) * 4;
                int kb2 = kv0 >> 5, qk = (kv0 >> 3) & 3, jb = kv0 & 7;
                const float4 r0 = vpre[i * 4 + 0], r1 = vpre[i * 4 + 1];
                const float4 r2 = vpre[i * 4 + 2], r3 = vpre[i * 4 + 3];
                const float ve[4][4] = {{r0.x, r1.x, r2.x, r3.x},
                                        {r0.y, r1.y, r2.y, r3.y},
                                        {r0.z, r1.z, r2.z, r3.z},
                                        {r0.w, r1.w, r2.w, r3.w}};
#pragma unroll
                for (int e = 0; e < 4; ++e) {
                    int dd = vdd4 + e;
                    int off = ((dd >> 4) * 2 + kb2) * 520 + ((dd & 15) + 16 * qk) * 8 + jb;
                    short h0,m0,l0,h1,m1,l1,h2,m2,l2,h3,m3,l3;
                    split3(ve[e][0],h0,m0,l0); split3(ve[e][1],h1,m1,l1);
                    split3(ve[e][2],h2,m2,l2); split3(ve[e][3],h3,m3,l3);
                    *(short4*)&KVs[0][off] = make_short4(h0,h1,h2,h3);
                    *(short4*)&KVs[1][off] = make_short4(m0,m1,m2,m3);
                    *(short4*)&KVs[2][off] = make_short4(l0,l1,l2,l3);
                }
            }
        }
        if (c < 3) {
#pragma unroll
            for (int i = 0; i < 2; ++i) {
                int kv0 = (vkvg + 8 * i) * 4;
#pragma unroll
                for (int rr = 0; rr < 4; ++rr)
                    vpre[i * 4 + rr] = *(const float4*)&Vm[((size_t)(b * 256 + (c + 1) * 64 + kv0 + rr)) * 512 + h * 128 + vdd4];
            }
        }
        __syncthreads();
        // O += P_c . V_c
#pragma unroll
        for (int kb2 = 0; kb2 < 2; ++kb2) {
            const float* pp = &Ps[w][lrow * 260 + c * 64 + kb2 * 32 + quad * 8];
            float4 a0 = *(const float4*)pp;
            float4 a1 = *(const float4*)(pp + 4);
            const float e[8] = {a0.x, a0.y, a0.z, a0.w, a1.x, a1.y, a1.z, a1.w};
            bf16x8 af[3];
#pragma unroll
            for (int j = 0; j < 8; ++j) {
                short hh, mm, ll;
                split3(e[j], hh, mm, ll);
                af[0][j] = hh; af[1][j] = mm; af[2][j] = ll;
            }
#pragma unroll
            for (int s = 0; s < 8; ++s) {
                bf16x8 vf[3];
#pragma unroll
                for (int p = 0; p < 3; ++p)
                    vf[p] = *(const bf16x8*)&KVs[p][(s * 2 + kb2) * 520 + lane * 8];
                oa[s] = __builtin_amdgcn_mfma_f32_16x16x32_bf16(af[0], vf[0], oa[s], 0, 0, 0);
                oa[s] = __builtin_amdgcn_mfma_f32_16x16x32_bf16(af[0], vf[1], oa[s], 0, 0, 0);
                oa[s] = __builtin_amdgcn_mfma_f32_16x16x32_bf16(af[1], vf[0], oa[s], 0, 0, 0);
                oa[s] = __builtin_amdgcn_mfma_f32_16x16x32_bf16(af[0], vf[2], oa[s], 0, 0, 0);
                oa[s] = __builtin_amdgcn_mfma_f32_16x16x32_bf16(af[1], vf[1], oa[s], 0, 0, 0);
                oa[s] = __builtin_amdgcn_mfma_f32_16x16x32_bf16(af[2], vf[0], oa[s], 0, 0, 0);
            }
        }
    }

#pragma unroll
    for (int s = 0; s < 8; ++s)
#pragma unroll
        for (int r = 0; r < 4; ++r)
            CTX[((size_t)(b * 512 + qw + quad * 4 + r)) * 512 + h * 128 + s * 16 + lrow] = oa[s][r];
}

// ---------------- final linear (512->6) + argmax, one wave per row ----------------
__global__ __launch_bounds__(256)
void head_k(const float* __restrict__ T2, const float* __restrict__ Wout,
            const float* __restrict__ bout, float* __restrict__ out)
{
    int wid = threadIdx.x >> 6, lane = threadIdx.x & 63;
    int row = blockIdx.x * 4 + wid;
    float acc[6] = {0.f, 0.f, 0.f, 0.f, 0.f, 0.f};
    const float* tr = T2 + (size_t)row * 512;
#pragma unroll
    for (int j = 0; j < 8; ++j) {
        int k = lane + 64 * j;
        float t = tr[k];
#pragma unroll
        for (int c = 0; c < 6; ++c) acc[c] = fmaf(t, Wout[k * 6 + c], acc[c]);
    }
#pragma unroll
    for (int c = 0; c < 6; ++c) {
#pragma unroll
        for (int off = 32; off >= 1; off >>= 1) acc[c] += __shfl_xor(acc[c], off);
    }
    if (lane == 0) {
        float best = -1e30f;
        int bi = 0;
#pragma unroll
        for (int c = 0; c < 6; ++c) {
            float v = acc[c] + bout[c];
            out[(size_t)row * 6 + c] = v;
            if (v > best) { best = v; bi = c; }
        }
        out[(size_t)4096 * 6 + row] = (float)bi;
    }
}

extern "C" void kernel_launch(void* const* d_in, const int* in_sizes, int n_in,
                              void* d_out, int out_size, void* d_ws, size_t ws_size,
                              hipStream_t stream)
{
    (void)in_sizes; (void)n_in; (void)out_size; (void)ws_size;
    const float* agent      = (const float*)d_in[0];
    const float* lane       = (const float*)d_in[1];
    const float* lane_in_W  = (const float*)d_in[2];
    const float* lane_in_b  = (const float*)d_in[3];
    const float* norm_w     = (const float*)d_in[4];
    const float* in_proj_W  = (const float*)d_in[5];
    const float* conv_w     = (const float*)d_in[6];
    const float* conv_b     = (const float*)d_in[7];
    const float* x_proj_W   = (const float*)d_in[8];
    const float* dt_proj_W  = (const float*)d_in[9];
    const float* dt_proj_b  = (const float*)d_in[10];
    const float* A_log      = (const float*)d_in[11];
    const float* D_skip     = (const float*)d_in[12];
    const float* out_proj_W = (const float*)d_in[13];
    const float* final_norm_w = (const float*)d_in[14];
    const float* Wq = (const float*)d_in[15];
    const float* Wk = (const float*)d_in[16];
    const float* Wv = (const float*)d_in[17];
    const float* Wo = (const float*)d_in[18];
    const float* bq = (const float*)d_in[19];
    const float* bk = (const float*)d_in[20];
    const float* bv = (const float*)d_in[21];
    const float* bo = (const float*)d_in[22];
    const float* lin_in_W  = (const float*)d_in[23];
    const float* lin_in_b  = (const float*)d_in[24];
    const float* lin_out_W = (const float*)d_in[25];
    const float* lin_out_b = (const float*)d_in[26];

    // Workspace: same 97 MB footprint that passed tripwires (rounds 1/3/4/5/6).
    float* ws = (float*)d_ws;
    float* X     = ws;                      // 2M floats (4096 x 512)
    float* H     = X + (1 << 21);           // 2M (rmsnorm out; dead during scans)
    float* XZ    = H + (1 << 21);           // 8M  (4096 x 2048)
    float* XC    = XZ + (1 << 23);          // 4M  (4096 x 1024)
    float* DELTA = XC + (1 << 22);          // 4M
    float* Y     = DELTA + (1 << 22);       // 4M
    float* DBL   = Y + (1 << 22);           // 256K (4096 x 64)
    float* SCb   = H;                       // 1M  SC[b][chunk][d][n] (aliases H)
    float* DSb   = H + (1 << 20);           // 64K DS[b][chunk][d]   (aliases H)
    float* Qb  = XZ;                        // 2M
    float* Kb  = XZ + (1 << 21);            // 1M (2048 x 512)
    float* Vb  = Kb + (1 << 20);            // 1M
    float* CTX = Vb + (1 << 20);            // 2M
    float* AO  = CTX + (1 << 21);           // 2M
    float* T2  = XC;                        // 2M

    dim3 blk(256);
    dim3 sblk(128);
    dim3 sgrid(8, 8, 8);                    // (d-group, chunk, b)

    // x = lane_features @ lane_in_W + b   (4096x128 @ 128x512)
    gemm6<128, 64, 2, 2><<<dim3(8, 32), blk, 0, stream>>>(
        lane, 128, lane_in_W, lane_in_b, X, 512, 4096, 512, 128, 0, 0);

    for (int i = 0; i < 4; ++i) {
        rmsnorm_k<<<1024, blk, 0, stream>>>(X, norm_w + i * 512, H);
        // xz = h @ in_proj  (4096x512 @ 512x2048)
        gemm6<128, 128, 2, 2><<<dim3(16, 32), blk, 0, stream>>>(
            H, 512, in_proj_W + (size_t)i * 512 * 2048, nullptr, XZ, 2048,
            4096, 2048, 512, 0, 0);
        conv_silu_k<<<4096, blk, 0, stream>>>(XZ, conv_w + i * 4096, conv_b + i * 1024, XC);
        // dbl = xc @ x_proj  (4096x1024 @ 1024x64)  -- N=64, fp32 kernel
        gemm_k<<<dim3(1, 64), blk, 0, stream>>>(XC, 1024, x_proj_W + (size_t)i * 1024 * 64,
                                                nullptr, DBL, 64, 4096, 64, 1024, 0, 0);
        // delta = softplus(dt @ dt_proj + b)  (4096x32 @ 32x1024)
        gemm6<128, 64, 2, 2><<<dim3(16, 32), blk, 0, stream>>>(
            DBL, 64, dt_proj_W + (size_t)i * 32 * 1024, dt_proj_b + i * 1024,
            DELTA, 1024, 4096, 1024, 32, 1, 0);
        // chunked scan (3 phases) + fused gating
        scan1_k<<<sgrid, sblk, 0, stream>>>(DELTA, XC, DBL, A_log + (size_t)i * 1024 * 16,
                                            D_skip + i * 1024, Y, SCb, DSb);
        scan2_k<<<512, blk, 0, stream>>>(A_log + (size_t)i * 1024 * 16, SCb, DSb);
        scan3_k<<<sgrid, sblk, 0, stream>>>(DELTA, DBL, A_log + (size_t)i * 1024 * 16,
                                            SCb, XZ, Y);
        // x += ygated @ out_proj  (4096x1024 @ 1024x512)
        gemm6<128, 64, 2, 2><<<dim3(8, 32), blk, 0, stream>>>(
            Y, 1024, out_proj_W + (size_t)i * 1024 * 512, nullptr, X, 512,
            4096, 512, 1024, 0, 1);
    }

    rmsnorm_k<<<1024, blk, 0, stream>>>(X, final_norm_w, H);   // enhanced

    gemm6<128, 64, 2, 2><<<dim3(8, 32), blk, 0, stream>>>(
        H, 512, Wq, bq, Qb, 512, 4096, 512, 512, 0, 0);
    gemm6<64, 64, 2, 2><<<dim3(8, 32), blk, 0, stream>>>(
        agent, 512, Wk, bk, Kb, 512, 2048, 512, 512, 0, 0);
    gemm6<64, 64, 2, 2><<<dim3(8, 32), blk, 0, stream>>>(
        agent, 512, Wv, bv, Vb, 512, 2048, 512, 512, 0, 0);
    attn_mfma<<<dim3(8, 4, 8), blk, 0, stream>>>(Qb, Kb, Vb, CTX);
    gemm6<128, 64, 2, 2><<<dim3(8, 32), blk, 0, stream>>>(
        CTX, 512, Wo, bo, AO, 512, 4096, 512, 512, 0, 0);
    gemm6<128, 64, 2, 2><<<dim3(8, 32), blk, 0, stream>>>(
        AO, 512, lin_in_W, lin_in_b, T2, 512, 4096, 512, 512, 0, 0);
    head_k<<<1024, blk, 0, stream>>>(T2, lin_out_W, lin_out_b, (float*)d_out);
}

// Round 8
// 1570.270 us; speedup vs baseline: 1.8020x; 1.0054x over previous
//
#include <hip/hip_runtime.h>
#include <math.h>

#define BATCH 8
#define LSEQ 512
#define LAGENT 256
#define DMODEL 512
#define DINNER 1024
#define DSTATE 16
#define DTRANK 32
#define NHEAD 4
#define DHEAD 128
#define NLANES 6

typedef __attribute__((ext_vector_type(8))) short bf16x8;
typedef __attribute__((ext_vector_type(4))) float f32x4;

// Exact 3-way bf16 split: x = h + m + l + O(2^-24 |x|); all subtractions exact.
__device__ __forceinline__ void split3(float x, short& h, short& m, short& l)
{
    unsigned hb = __float_as_uint(x) & 0xFFFF0000u;
    h = (short)(hb >> 16);
    float r1 = x - __uint_as_float(hb);
    unsigned mb = __float_as_uint(r1) & 0xFFFF0000u;
    m = (short)(mb >> 16);
    float r2 = r1 - __uint_as_float(mb);
    l = (short)(__float_as_uint(r2) >> 16);
}

// ---------------- bf16x6 emulated-fp32 MFMA GEMM, fragment-linear LDS ----------------
template<int BM, int BN, int WM, int WN>
__global__ __launch_bounds__(256)
void gemm6(const float* __restrict__ A, int lda,
           const float* __restrict__ W,
           const float* __restrict__ bias,
           float* __restrict__ C, int ldc,
           int M, int N, int K, int act, int addC)
{
    constexpr int MT = BM / WM / 16;
    constexpr int NT = BN / WN / 16;
    constexpr int ASL = BM / 16;
    constexpr int BSL = BN / 16;
    __shared__ short Asl[3][ASL * 520];
    __shared__ short Bsl[3][BSL * 520];

    const int tid = threadIdx.x;
    const int w = tid >> 6, lane = tid & 63;
    const int lrow = lane & 15, quad = lane >> 4;
    const int aslab0 = (w % WM) * MT;
    const int bslab0 = (w / WM) * NT;
    const int m0 = blockIdx.y * BM, n0 = blockIdx.x * BN;

    f32x4 acc[MT][NT] = {};

    for (int k0 = 0; k0 < K; k0 += 32) {
        __syncthreads();
#pragma unroll
        for (int i = 0; i < BM / 32; ++i) {
            int v = tid + 256 * i;
            int row = v >> 3;
            int kq = (v & 7) * 4;
            float4 val = *(const float4*)&A[(size_t)(m0 + row) * lda + k0 + kq];
            int off = (row >> 4) * 520 + (((kq >> 3) << 4) + (row & 15)) * 8 + (kq & 7);
            short h[4], mm_[4], l[4];
            split3(val.x, h[0], mm_[0], l[0]);
            split3(val.y, h[1], mm_[1], l[1]);
            split3(val.z, h[2], mm_[2], l[2]);
            split3(val.w, h[3], mm_[3], l[3]);
            *(short4*)&Asl[0][off] = make_short4(h[0], h[1], h[2], h[3]);
            *(short4*)&Asl[1][off] = make_short4(mm_[0], mm_[1], mm_[2], mm_[3]);
            *(short4*)&Asl[2][off] = make_short4(l[0], l[1], l[2], l[3]);
        }
        constexpr int NPQS = (BN == 128) ? 5 : 4;
#pragma unroll
        for (int i = 0; i < BN / 64; ++i) {
            int v = tid + 256 * i;
            int kp = v >> NPQS;
            int nc = (v & ((1 << NPQS) - 1)) * 4;
            int k1 = kp * 2;
            float4 r0 = *(const float4*)&W[(size_t)(k0 + k1) * N + n0 + nc];
            float4 r1 = *(const float4*)&W[(size_t)(k0 + k1 + 1) * N + n0 + nc];
            const float e0[4] = {r0.x, r0.y, r0.z, r0.w};
            const float e1[4] = {r1.x, r1.y, r1.z, r1.w};
#pragma unroll
            for (int e = 0; e < 4; ++e) {
                int n = nc + e;
                int off = (n >> 4) * 520 + (((k1 >> 3) << 4) + (n & 15)) * 8 + (k1 & 7);
                short h0, m0_, l0, h1, m1_, l1;
                split3(e0[e], h0, m0_, l0);
                split3(e1[e], h1, m1_, l1);
                *(short2*)&Bsl[0][off] = make_short2(h0, h1);
                *(short2*)&Bsl[1][off] = make_short2(m0_, m1_);
                *(short2*)&Bsl[2][off] = make_short2(l0, l1);
            }
        }
        __syncthreads();

        bf16x8 af[3][MT];
#pragma unroll
        for (int p = 0; p < 3; ++p)
#pragma unroll
            for (int i = 0; i < MT; ++i)
                af[p][i] = *(const bf16x8*)&Asl[p][(aslab0 + i) * 520 + lane * 8];

#pragma unroll
        for (int pb = 0; pb < 3; ++pb) {
            bf16x8 bfr[NT];
#pragma unroll
            for (int j = 0; j < NT; ++j)
                bfr[j] = *(const bf16x8*)&Bsl[pb][(bslab0 + j) * 520 + lane * 8];
            const int npa = (pb == 0) ? 3 : (pb == 1 ? 2 : 1);
#pragma unroll
            for (int pa = 0; pa < 3; ++pa) {
                if (pa >= npa) break;
#pragma unroll
                for (int i = 0; i < MT; ++i)
#pragma unroll
                    for (int j = 0; j < NT; ++j)
                        acc[i][j] = __builtin_amdgcn_mfma_f32_16x16x32_bf16(
                            af[pa][i], bfr[j], acc[i][j], 0, 0, 0);
            }
        }
    }

#pragma unroll
    for (int i = 0; i < MT; ++i) {
        int mbase = m0 + (aslab0 + i) * 16 + quad * 4;
#pragma unroll
        for (int j = 0; j < NT; ++j) {
            int n = n0 + (bslab0 + j) * 16 + lrow;
            float bv = bias ? bias[n] : 0.f;
#pragma unroll
            for (int r = 0; r < 4; ++r) {
                size_t off = (size_t)(mbase + r) * ldc + n;
                float v = acc[i][j][r] + bv;
                if (act == 1) v = (v > 20.f) ? v : log1pf(__expf(v));
                if (addC) v += C[off];
                C[off] = v;
            }
        }
    }
}

// ---------------- RMSNorm: one wave per row of 512 ----------------
__global__ __launch_bounds__(256)
void rmsnorm_k(const float* __restrict__ X, const float* __restrict__ w,
               float* __restrict__ O)
{
    int wid = threadIdx.x >> 6, lane = threadIdx.x & 63;
    int row = blockIdx.x * 4 + wid;
    const float* xr = X + (size_t)row * DMODEL;
    float v[8];
    float ss = 0.f;
#pragma unroll
    for (int j = 0; j < 8; ++j) { v[j] = xr[lane + 64 * j]; ss = fmaf(v[j], v[j], ss); }
#pragma unroll
    for (int off = 32; off >= 1; off >>= 1) ss += __shfl_xor(ss, off);
    float scale = rsqrtf(ss * (1.f / 512.f) + 1e-5f);
    float* orow = O + (size_t)row * DMODEL;
#pragma unroll
    for (int j = 0; j < 8; ++j) orow[lane + 64 * j] = v[j] * scale * w[lane + 64 * j];
}

// ---------------- causal depthwise conv (K=4) + SiLU, float4 over d ----------------
__global__ __launch_bounds__(256)
void conv_silu_k(const float* __restrict__ XZ, const float* __restrict__ cw,
                 const float* __restrict__ cb, float* __restrict__ XC)
{
    int idx = blockIdx.x * 256 + threadIdx.x;   // over b*L*256 d-groups
    int d4 = (idx & 255) * 4;
    int t = (idx >> 8) & 511;
    int b = idx >> 17;
    float4 wv[4];
#pragma unroll
    for (int e = 0; e < 4; ++e) wv[e] = *(const float4*)&cw[(d4 + e) * 4];
    float4 bv = *(const float4*)&cb[d4];
    float s[4] = {bv.x, bv.y, bv.z, bv.w};
#pragma unroll
    for (int k = 0; k < 4; ++k) {
        int tt = t + k - 3;
        if (tt >= 0) {
            float4 x = *(const float4*)&XZ[((size_t)(b * 512 + tt)) * 2048 + d4];
            const float xe[4] = {x.x, x.y, x.z, x.w};
            const float we[4] = {wv[0][k], wv[1][k], wv[2][k], wv[3][k]};
#pragma unroll
            for (int e = 0; e < 4; ++e) s[e] = fmaf(we[e], xe[e], s[e]);
        }
    }
    float4 o;
    o.x = s[0] / (1.f + __expf(-s[0]));
    o.y = s[1] / (1.f + __expf(-s[1]));
    o.z = s[2] / (1.f + __expf(-s[2]));
    o.w = s[3] / (1.f + __expf(-s[3]));
    *(float4*)&XC[((size_t)(b * 512 + t)) * 1024 + d4] = o;
}

// ---------------- chunked selective scan: thread per (b,chunk,d), 16 states in regs ----
__global__ __launch_bounds__(128)
void scan1_k(const float* __restrict__ DELTA, const float* __restrict__ XC,
             const float* __restrict__ DBL, const float* __restrict__ A_log,
             const float* __restrict__ Dsk, float* __restrict__ Y,
             float* __restrict__ SC, float* __restrict__ DS)
{
    __shared__ float BC[64][32];       // [t][0:16)=B, [16:32)=C  (broadcast reads)
    const int tid = threadIdx.x;
    const int d = blockIdx.x * 128 + tid;
    const int chunk = blockIdx.y;
    const int b = blockIdx.z;
    const int t0 = chunk * 64;

#pragma unroll
    for (int i = 0; i < 16; ++i) {
        int idx = tid + 128 * i;
        int t = idx >> 5, j = idx & 31;
        BC[t][j] = DBL[(size_t)(b * 512 + t0 + t) * 64 + 32 + j];
    }
    float Ac[16];
#pragma unroll
    for (int n = 0; n < 16; ++n) Ac[n] = -__expf(A_log[d * 16 + n]);
    float Dv = Dsk[d];
    __syncthreads();

    const float* dp = DELTA + ((size_t)(b * 512 + t0)) * 1024 + d;
    const float* up = XC    + ((size_t)(b * 512 + t0)) * 1024 + d;
    float* yp       = Y     + ((size_t)(b * 512 + t0)) * 1024 + d;

    float h[16];
#pragma unroll
    for (int n = 0; n < 16; ++n) h[n] = 0.f;
    float dsum = 0.f;

#pragma unroll 2
    for (int t = 0; t < 64; ++t) {
        float delta = dp[t * 1024];
        float u = up[t * 1024];
        dsum += delta;
        float du = delta * u;
        float y = 0.f;
#pragma unroll
        for (int n = 0; n < 16; ++n) {
            h[n] = fmaf(__expf(delta * Ac[n]), h[n], du * BC[t][n]);
            y = fmaf(h[n], BC[t][16 + n], y);
        }
        yp[t * 1024] = fmaf(u, Dv, y);
    }

    float* sc = SC + ((size_t)((b * 8 + chunk) * 1024 + d)) * 16;
#pragma unroll
    for (int n = 0; n < 16; ++n) sc[n] = h[n];
    DS[(size_t)(b * 8 + chunk) * 1024 + d] = dsum;
}

__global__ __launch_bounds__(256)
void scan2_k(const float* __restrict__ A_log, float* __restrict__ SC,
             const float* __restrict__ DS)
{
    int gid = blockIdx.x * 256 + threadIdx.x;   // b*16384 + d*16 + n
    int n = gid & 15;
    int d = (gid >> 4) & 1023;
    int b = gid >> 14;
    float Ac = -__expf(A_log[d * 16 + n]);
    float carry = 0.f;
#pragma unroll
    for (int c = 0; c < 8; ++c) {
        size_t off = ((size_t)((b * 8 + c) * 1024 + d)) * 16 + n;
        float s = SC[off];
        SC[off] = carry;
        carry = fmaf(__expf(Ac * DS[(size_t)(b * 8 + c) * 1024 + d]), carry, s);
    }
}

__global__ __launch_bounds__(128)
void scan3_k(const float* __restrict__ DELTA, const float* __restrict__ DBL,
             const float* __restrict__ A_log, const float* __restrict__ H0,
             const float* __restrict__ XZ, float* __restrict__ Y)
{
    __shared__ float Cs[64][16];
    const int tid = threadIdx.x;
    const int d = blockIdx.x * 128 + tid;
    const int chunk = blockIdx.y;
    const int b = blockIdx.z;
    const int t0 = chunk * 64;

#pragma unroll
    for (int i = 0; i < 8; ++i) {
        int idx = tid + 128 * i;
        int t = idx >> 4, j = idx & 15;
        Cs[t][j] = DBL[(size_t)(b * 512 + t0 + t) * 64 + 48 + j];
    }
    float Ac[16], h0[16];
#pragma unroll
    for (int n = 0; n < 16; ++n) Ac[n] = -__expf(A_log[d * 16 + n]);
    const float* h0p = H0 + ((size_t)((b * 8 + chunk) * 1024 + d)) * 16;
#pragma unroll
    for (int n = 0; n < 16; ++n) h0[n] = h0p[n];
    __syncthreads();

    const float* dp = DELTA + ((size_t)(b * 512 + t0)) * 1024 + d;
    const float* zp = XZ    + ((size_t)(b * 512 + t0)) * 2048 + 1024 + d;
    float* yp       = Y     + ((size_t)(b * 512 + t0)) * 1024 + d;

    float cum = 0.f;
    if (chunk == 0) {
#pragma unroll 2
        for (int t = 0; t < 64; ++t) {
            float z = zp[t * 2048];
            yp[t * 1024] *= z / (1.f + __expf(-z));
        }
    } else {
#pragma unroll 2
        for (int t = 0; t < 64; ++t) {
            float delta = dp[t * 1024];
            cum += delta;
            float p = 0.f;
#pragma unroll
            for (int n = 0; n < 16; ++n)
                p = fmaf(h0[n] * __expf(Ac[n] * cum), Cs[t][n], p);
            float z = zp[t * 2048];
            float yv = yp[t * 1024] + p;
            yp[t * 1024] = yv * (z / (1.f + __expf(-z)));
        }
    }
}

// ---------------- MFMA flash attention, exact fp32 via bf16x6 ----------------
__global__ __launch_bounds__(256, 1)
void attn_mfma(const float* __restrict__ Qm, const float* __restrict__ Km,
               const float* __restrict__ Vm, float* __restrict__ CTX)
{
    __shared__ short KVs[3][16 * 520];      // 16 frag-tiles per plane
    __shared__ float Ps[4][16 * 260];       // per-wave P strip (16 q x 256 kv, pad 260)
    const int tid = threadIdx.x;
    const int w = tid >> 6, lane = tid & 63;
    const int lrow = lane & 15, quad = lane >> 4;
    const int b = blockIdx.z, h = blockIdx.y;
    const int qw = blockIdx.x * 64 + w * 16;

    bf16x8 qf[3][4];
    {
        const float* qp = Qm + ((size_t)(b * 512 + qw + lrow)) * 512 + h * 128 + quad * 8;
#pragma unroll
        for (int kb = 0; kb < 4; ++kb) {
            float4 v0 = *(const float4*)(qp + kb * 32);
            float4 v1 = *(const float4*)(qp + kb * 32 + 4);
            const float e[8] = {v0.x, v0.y, v0.z, v0.w, v1.x, v1.y, v1.z, v1.w};
#pragma unroll
            for (int j = 0; j < 8; ++j) {
                short hh, mm, ll;
                split3(e[j], hh, mm, ll);
                qf[0][kb][j] = hh; qf[1][kb][j] = mm; qf[2][kb][j] = ll;
            }
        }
    }

    const int sdd = (tid & 31) * 4;
    const int skvb = tid >> 5;
    f32x4 sa[4][4] = {};

    float4 kpre[8];
#pragma unroll
    for (int i = 0; i < 8; ++i)
        kpre[i] = *(const float4*)&Km[((size_t)(b * 256 + skvb + 8 * i)) * 512 + h * 128 + sdd];

    for (int c = 0; c < 4; ++c) {
        if (c) __syncthreads();
        {
            const int kb = sdd >> 5, qd = (sdd >> 3) & 3, jd = sdd & 7;
#pragma unroll
            for (int i = 0; i < 8; ++i) {
                int kv = skvb + 8 * i;
                int off = ((kv >> 4) * 4 + kb) * 520 + ((kv & 15) + 16 * qd) * 8 + jd;
                short h0,m0,l0,h1,m1,l1,h2,m2,l2,h3,m3,l3;
                split3(kpre[i].x,h0,m0,l0); split3(kpre[i].y,h1,m1,l1);
                split3(kpre[i].z,h2,m2,l2); split3(kpre[i].w,h3,m3,l3);
                *(short4*)&KVs[0][off] = make_short4(h0,h1,h2,h3);
                *(short4*)&KVs[1][off] = make_short4(m0,m1,m2,m3);
                *(short4*)&KVs[2][off] = make_short4(l0,l1,l2,l3);
            }
        }
        if (c < 3) {
#pragma unroll
            for (int i = 0; i < 8; ++i)
                kpre[i] = *(const float4*)&Km[((size_t)(b * 256 + (c + 1) * 64 + skvb + 8 * i)) * 512 + h * 128 + sdd];
        }
        __syncthreads();
#pragma unroll
        for (int s = 0; s < 4; ++s) {
#pragma unroll
            for (int kb = 0; kb < 4; ++kb) {
                bf16x8 kf[3];
#pragma unroll
                for (int p = 0; p < 3; ++p)
                    kf[p] = *(const bf16x8*)&KVs[p][(s * 4 + kb) * 520 + lane * 8];
                sa[c][s] = __builtin_amdgcn_mfma_f32_16x16x32_bf16(qf[0][kb], kf[0], sa[c][s], 0, 0, 0);
                sa[c][s] = __builtin_amdgcn_mfma_f32_16x16x32_bf16(qf[0][kb], kf[1], sa[c][s], 0, 0, 0);
                sa[c][s] = __builtin_amdgcn_mfma_f32_16x16x32_bf16(qf[1][kb], kf[0], sa[c][s], 0, 0, 0);
                sa[c][s] = __builtin_amdgcn_mfma_f32_16x16x32_bf16(qf[0][kb], kf[2], sa[c][s], 0, 0, 0);
                sa[c][s] = __builtin_amdgcn_mfma_f32_16x16x32_bf16(qf[1][kb], kf[1], sa[c][s], 0, 0, 0);
                sa[c][s] = __builtin_amdgcn_mfma_f32_16x16x32_bf16(qf[2][kb], kf[0], sa[c][s], 0, 0, 0);
            }
        }
    }

    const float scale = 0.08838834764831845f;
    float mx[4] = {-1e30f, -1e30f, -1e30f, -1e30f};
#pragma unroll
    for (int c = 0; c < 4; ++c)
#pragma unroll
        for (int s = 0; s < 4; ++s)
#pragma unroll
            for (int r = 0; r < 4; ++r) {
                sa[c][s][r] *= scale;
                mx[r] = fmaxf(mx[r], sa[c][s][r]);
            }
#pragma unroll
    for (int r = 0; r < 4; ++r) {
        mx[r] = fmaxf(mx[r], __shfl_xor(mx[r], 1));
        mx[r] = fmaxf(mx[r], __shfl_xor(mx[r], 2));
        mx[r] = fmaxf(mx[r], __shfl_xor(mx[r], 4));
        mx[r] = fmaxf(mx[r], __shfl_xor(mx[r], 8));
    }
    float sum[4] = {0.f, 0.f, 0.f, 0.f};
#pragma unroll
    for (int c = 0; c < 4; ++c)
#pragma unroll
        for (int s = 0; s < 4; ++s)
#pragma unroll
            for (int r = 0; r < 4; ++r) {
                float e = __expf(sa[c][s][r] - mx[r]);
                sa[c][s][r] = e;
                sum[r] += e;
            }
#pragma unroll
    for (int r = 0; r < 4; ++r) {
        sum[r] += __shfl_xor(sum[r], 1);
        sum[r] += __shfl_xor(sum[r], 2);
        sum[r] += __shfl_xor(sum[r], 4);
        sum[r] += __shfl_xor(sum[r], 8);
        sum[r] = 1.f / sum[r];
    }
    {
        float* ps = &Ps[w][0];
#pragma unroll
        for (int c = 0; c < 4; ++c)
#pragma unroll
            for (int s = 0; s < 4; ++s)
#pragma unroll
                for (int r = 0; r < 4; ++r)
                    ps[(quad * 4 + r) * 260 + c * 64 + s * 16 + lrow] = sa[c][s][r] * sum[r];
    }

    const int vdd4 = (tid & 31) * 4;
    const int vkvg = tid >> 5;
    f32x4 oa[8] = {};
    float4 vpre[8];
#pragma unroll
    for (int i = 0; i < 2; ++i) {
        int kv0 = (vkvg + 8 * i) * 4;
#pragma unroll
        for (int rr = 0; rr < 4; ++rr)
            vpre[i * 4 + rr] = *(const float4*)&Vm[((size_t)(b * 256 + kv0 + rr)) * 512 + h * 128 + vdd4];
    }

    for (int c = 0; c < 4; ++c) {
        __syncthreads();
        {
#pragma unroll
            for (int i = 0; i < 2; ++i) {
                int kv0 = (vkvg + 8 * i) * 4;
                int kb2 = kv0 >> 5, qk = (kv0 >> 3) & 3, jb = kv0 & 7;
                const float4 r0 = vpre[i * 4 + 0], r1 = vpre[i * 4 + 1];
                const float4 r2 = vpre[i * 4 + 2], r3 = vpre[i * 4 + 3];
                const float ve[4][4] = {{r0.x, r1.x, r2.x, r3.x},
                                        {r0.y, r1.y, r2.y, r3.y},
                                        {r0.z, r1.z, r2.z, r3.z},
                                        {r0.w, r1.w, r2.w, r3.w}};
#pragma unroll
                for (int e = 0; e < 4; ++e) {
                    int dd = vdd4 + e;
                    int off = ((dd >> 4) * 2 + kb2) * 520 + ((dd & 15) + 16 * qk) * 8 + jb;
                    short h0,m0,l0,h1,m1,l1,h2,m2,l2,h3,m3,l3;
                    split3(ve[e][0],h0,m0,l0); split3(ve[e][1],h1,m1,l1);
                    split3(ve[e][2],h2,m2,l2); split3(ve[e][3],h3,m3,l3);
                    *(short4*)&KVs[0][off] = make_short4(h0,h1,h2,h3);
                    *(short4*)&KVs[1][off] = make_short4(m0,m1,m2,m3);
                    *(short4*)&KVs[2][off] = make_short4(l0,l1,l2,l3);
                }
            }
        }
        if (c < 3) {
#pragma unroll
            for (int i = 0; i < 2; ++i) {
                int kv0 = (vkvg + 8 * i) * 4;
#pragma unroll
                for (int rr = 0; rr < 4; ++rr)
                    vpre[i * 4 + rr] = *(const float4*)&Vm[((size_t)(b * 256 + (c + 1) * 64 + kv0 + rr)) * 512 + h * 128 + vdd4];
            }
        }
        __syncthreads();
#pragma unroll
        for (int kb2 = 0; kb2 < 2; ++kb2) {
            const float* pp = &Ps[w][lrow * 260 + c * 64 + kb2 * 32 + quad * 8];
            float4 a0 = *(const float4*)pp;
            float4 a1 = *(const float4*)(pp + 4);
            const float e[8] = {a0.x, a0.y, a0.z, a0.w, a1.x, a1.y, a1.z, a1.w};
            bf16x8 af[3];
#pragma unroll
            for (int j = 0; j < 8; ++j) {
                short hh, mm, ll;
                split3(e[j], hh, mm, ll);
                af[0][j] = hh; af[1][j] = mm; af[2][j] = ll;
            }
#pragma unroll
            for (int s = 0; s < 8; ++s) {
                bf16x8 vf[3];
#pragma unroll
                for (int p = 0; p < 3; ++p)
                    vf[p] = *(const bf16x8*)&KVs[p][(s * 2 + kb2) * 520 + lane * 8];
                oa[s] = __builtin_amdgcn_mfma_f32_16x16x32_bf16(af[0], vf[0], oa[s], 0, 0, 0);
                oa[s] = __builtin_amdgcn_mfma_f32_16x16x32_bf16(af[0], vf[1], oa[s], 0, 0, 0);
                oa[s] = __builtin_amdgcn_mfma_f32_16x16x32_bf16(af[1], vf[0], oa[s], 0, 0, 0);
                oa[s] = __builtin_amdgcn_mfma_f32_16x16x32_bf16(af[0], vf[2], oa[s], 0, 0, 0);
                oa[s] = __builtin_amdgcn_mfma_f32_16x16x32_bf16(af[1], vf[1], oa[s], 0, 0, 0);
                oa[s] = __builtin_amdgcn_mfma_f32_16x16x32_bf16(af[2], vf[0], oa[s], 0, 0, 0);
            }
        }
    }

#pragma unroll
    for (int s = 0; s < 8; ++s)
#pragma unroll
        for (int r = 0; r < 4; ++r)
            CTX[((size_t)(b * 512 + qw + quad * 4 + r)) * 512 + h * 128 + s * 16 + lrow] = oa[s][r];
}

// ---------------- final linear (512->6) + argmax, one wave per row ----------------
__global__ __launch_bounds__(256)
void head_k(const float* __restrict__ T2, const float* __restrict__ Wout,
            const float* __restrict__ bout, float* __restrict__ out)
{
    int wid = threadIdx.x >> 6, lane = threadIdx.x & 63;
    int row = blockIdx.x * 4 + wid;
    float acc[6] = {0.f, 0.f, 0.f, 0.f, 0.f, 0.f};
    const float* tr = T2 + (size_t)row * 512;
#pragma unroll
    for (int j = 0; j < 8; ++j) {
        int k = lane + 64 * j;
        float t = tr[k];
#pragma unroll
        for (int c = 0; c < 6; ++c) acc[c] = fmaf(t, Wout[k * 6 + c], acc[c]);
    }
#pragma unroll
    for (int c = 0; c < 6; ++c) {
#pragma unroll
        for (int off = 32; off >= 1; off >>= 1) acc[c] += __shfl_xor(acc[c], off);
    }
    if (lane == 0) {
        float best = -1e30f;
        int bi = 0;
#pragma unroll
        for (int c = 0; c < 6; ++c) {
            float v = acc[c] + bout[c];
            out[(size_t)row * 6 + c] = v;
            if (v > best) { best = v; bi = c; }
        }
        out[(size_t)4096 * 6 + row] = (float)bi;
    }
}

extern "C" void kernel_launch(void* const* d_in, const int* in_sizes, int n_in,
                              void* d_out, int out_size, void* d_ws, size_t ws_size,
                              hipStream_t stream)
{
    (void)in_sizes; (void)n_in; (void)out_size; (void)ws_size;
    const float* agent      = (const float*)d_in[0];
    const float* lane       = (const float*)d_in[1];
    const float* lane_in_W  = (const float*)d_in[2];
    const float* lane_in_b  = (const float*)d_in[3];
    const float* norm_w     = (const float*)d_in[4];
    const float* in_proj_W  = (const float*)d_in[5];
    const float* conv_w     = (const float*)d_in[6];
    const float* conv_b     = (const float*)d_in[7];
    const float* x_proj_W   = (const float*)d_in[8];
    const float* dt_proj_W  = (const float*)d_in[9];
    const float* dt_proj_b  = (const float*)d_in[10];
    const float* A_log      = (const float*)d_in[11];
    const float* D_skip     = (const float*)d_in[12];
    const float* out_proj_W = (const float*)d_in[13];
    const float* final_norm_w = (const float*)d_in[14];
    const float* Wq = (const float*)d_in[15];
    const float* Wk = (const float*)d_in[16];
    const float* Wv = (const float*)d_in[17];
    const float* Wo = (const float*)d_in[18];
    const float* bq = (const float*)d_in[19];
    const float* bk = (const float*)d_in[20];
    const float* bv = (const float*)d_in[21];
    const float* bo = (const float*)d_in[22];
    const float* lin_in_W  = (const float*)d_in[23];
    const float* lin_in_b  = (const float*)d_in[24];
    const float* lin_out_W = (const float*)d_in[25];
    const float* lin_out_b = (const float*)d_in[26];

    // Workspace: same 97 MB footprint that passed tripwires (rounds 1/3-7).
    float* ws = (float*)d_ws;
    float* X     = ws;                      // 2M floats (4096 x 512)
    float* H     = X + (1 << 21);           // 2M (rmsnorm out; dead during scans)
    float* XZ    = H + (1 << 21);           // 8M  (4096 x 2048)
    float* XC    = XZ + (1 << 23);          // 4M  (4096 x 1024)
    float* DELTA = XC + (1 << 22);          // 4M
    float* Y     = DELTA + (1 << 22);       // 4M
    float* DBL   = Y + (1 << 22);           // 256K (4096 x 64)
    float* SCb   = H;                       // 1M  SC[b][chunk][d][n] (aliases H)
    float* DSb   = H + (1 << 20);           // 64K DS[b][chunk][d]   (aliases H)
    float* Qb  = XZ;                        // 2M
    float* Kb  = XZ + (1 << 21);            // 1M (2048 x 512)
    float* Vb  = Kb + (1 << 20);            // 1M
    float* CTX = Vb + (1 << 20);            // 2M
    float* AO  = CTX + (1 << 21);           // 2M
    float* T2  = XC;                        // 2M

    dim3 blk(256);
    dim3 sblk(128);
    dim3 sgrid(8, 8, 8);                    // (d-group, chunk, b)

    // x = lane_features @ lane_in_W + b   (4096x128 @ 128x512)
    gemm6<128, 64, 2, 2><<<dim3(8, 32), blk, 0, stream>>>(
        lane, 128, lane_in_W, lane_in_b, X, 512, 4096, 512, 128, 0, 0);

    for (int i = 0; i < 4; ++i) {
        rmsnorm_k<<<1024, blk, 0, stream>>>(X, norm_w + i * 512, H);
        // xz = h @ in_proj  (4096x512 @ 512x2048)
        gemm6<128, 128, 2, 2><<<dim3(16, 32), blk, 0, stream>>>(
            H, 512, in_proj_W + (size_t)i * 512 * 2048, nullptr, XZ, 2048,
            4096, 2048, 512, 0, 0);
        conv_silu_k<<<4096, blk, 0, stream>>>(XZ, conv_w + i * 4096, conv_b + i * 1024, XC);
        // dbl = xc @ x_proj  (4096x1024 @ 1024x64)  -- now MFMA (was fp32 gemm_k @ 74us)
        gemm6<64, 64, 2, 2><<<dim3(1, 64), blk, 0, stream>>>(
            XC, 1024, x_proj_W + (size_t)i * 1024 * 64, nullptr, DBL, 64,
            4096, 64, 1024, 0, 0);
        // delta = softplus(dt @ dt_proj + b)  (4096x32 @ 32x1024)
        gemm6<128, 64, 2, 2><<<dim3(16, 32), blk, 0, stream>>>(
            DBL, 64, dt_proj_W + (size_t)i * 32 * 1024, dt_proj_b + i * 1024,
            DELTA, 1024, 4096, 1024, 32, 1, 0);
        // chunked scan (3 phases) + fused gating
        scan1_k<<<sgrid, sblk, 0, stream>>>(DELTA, XC, DBL, A_log + (size_t)i * 1024 * 16,
                                            D_skip + i * 1024, Y, SCb, DSb);
        scan2_k<<<512, blk, 0, stream>>>(A_log + (size_t)i * 1024 * 16, SCb, DSb);
        scan3_k<<<sgrid, sblk, 0, stream>>>(DELTA, DBL, A_log + (size_t)i * 1024 * 16,
                                            SCb, XZ, Y);
        // x += ygated @ out_proj  (4096x1024 @ 1024x512)
        gemm6<128, 64, 2, 2><<<dim3(8, 32), blk, 0, stream>>>(
            Y, 1024, out_proj_W + (size_t)i * 1024 * 512, nullptr, X, 512,
            4096, 512, 1024, 0, 1);
    }

    rmsnorm_k<<<1024, blk, 0, stream>>>(X, final_norm_w, H);   // enhanced

    gemm6<128, 64, 2, 2><<<dim3(8, 32), blk, 0, stream>>>(
        H, 512, Wq, bq, Qb, 512, 4096, 512, 512, 0, 0);
    gemm6<64, 64, 2, 2><<<dim3(8, 32), blk, 0, stream>>>(
        agent, 512, Wk, bk, Kb, 512, 2048, 512, 512, 0, 0);
    gemm6<64, 64, 2, 2><<<dim3(8, 32), blk, 0, stream>>>(
        agent, 512, Wv, bv, Vb, 512, 2048, 512, 512, 0, 0);
    attn_mfma<<<dim3(8, 4, 8), blk, 0, stream>>>(Qb, Kb, Vb, CTX);
    gemm6<128, 64, 2, 2><<<dim3(8, 32), blk, 0, stream>>>(
        CTX, 512, Wo, bo, AO, 512, 4096, 512, 512, 0, 0);
    gemm6<128, 64, 2, 2><<<dim3(8, 32), blk, 0, stream>>>(
        AO, 512, lin_in_W, lin_in_b, T2, 512, 4096, 512, 512, 0, 0);
    head_k<<<1024, blk, 0, stream>>>(T2, lin_out_W, lin_out_b, (float*)d_out);
}

// Round 9
// 1366.875 us; speedup vs baseline: 2.0702x; 1.1488x over previous
//
#include <hip/hip_runtime.h>
#include <math.h>

#define BATCH 8
#define LSEQ 512
#define LAGENT 256
#define DMODEL 512
#define DINNER 1024
#define DSTATE 16
#define DTRANK 32
#define NHEAD 4
#define DHEAD 128
#define NLANES 6

typedef __attribute__((ext_vector_type(8))) short bf16x8;
typedef __attribute__((ext_vector_type(4))) float f32x4;

// Exact 3-way bf16 split: x = h + m + l + O(2^-24 |x|); all subtractions exact.
__device__ __forceinline__ void split3(float x, short& h, short& m, short& l)
{
    unsigned hb = __float_as_uint(x) & 0xFFFF0000u;
    h = (short)(hb >> 16);
    float r1 = x - __uint_as_float(hb);
    unsigned mb = __float_as_uint(r1) & 0xFFFF0000u;
    m = (short)(mb >> 16);
    float r2 = r1 - __uint_as_float(mb);
    l = (short)(__float_as_uint(r2) >> 16);
}

// ---------------- bf16x6 emulated-fp32 MFMA GEMM, fragment-linear LDS ----------------
template<int BM, int BN, int WM, int WN>
__global__ __launch_bounds__(256)
void gemm6(const float* __restrict__ A, int lda,
           const float* __restrict__ W,
           const float* __restrict__ bias,
           float* __restrict__ C, int ldc,
           int M, int N, int K, int act, int addC)
{
    constexpr int MT = BM / WM / 16;
    constexpr int NT = BN / WN / 16;
    constexpr int ASL = BM / 16;
    constexpr int BSL = BN / 16;
    __shared__ short Asl[3][ASL * 520];
    __shared__ short Bsl[3][BSL * 520];

    const int tid = threadIdx.x;
    const int w = tid >> 6, lane = tid & 63;
    const int lrow = lane & 15, quad = lane >> 4;
    const int aslab0 = (w % WM) * MT;
    const int bslab0 = (w / WM) * NT;
    const int m0 = blockIdx.y * BM, n0 = blockIdx.x * BN;

    f32x4 acc[MT][NT] = {};

    for (int k0 = 0; k0 < K; k0 += 32) {
        __syncthreads();
#pragma unroll
        for (int i = 0; i < BM / 32; ++i) {
            int v = tid + 256 * i;
            int row = v >> 3;
            int kq = (v & 7) * 4;
            float4 val = *(const float4*)&A[(size_t)(m0 + row) * lda + k0 + kq];
            int off = (row >> 4) * 520 + (((kq >> 3) << 4) + (row & 15)) * 8 + (kq & 7);
            short h[4], mm_[4], l[4];
            split3(val.x, h[0], mm_[0], l[0]);
            split3(val.y, h[1], mm_[1], l[1]);
            split3(val.z, h[2], mm_[2], l[2]);
            split3(val.w, h[3], mm_[3], l[3]);
            *(short4*)&Asl[0][off] = make_short4(h[0], h[1], h[2], h[3]);
            *(short4*)&Asl[1][off] = make_short4(mm_[0], mm_[1], mm_[2], mm_[3]);
            *(short4*)&Asl[2][off] = make_short4(l[0], l[1], l[2], l[3]);
        }
        constexpr int NPQS = (BN == 128) ? 5 : 4;
#pragma unroll
        for (int i = 0; i < BN / 64; ++i) {
            int v = tid + 256 * i;
            int kp = v >> NPQS;
            int nc = (v & ((1 << NPQS) - 1)) * 4;
            int k1 = kp * 2;
            float4 r0 = *(const float4*)&W[(size_t)(k0 + k1) * N + n0 + nc];
            float4 r1 = *(const float4*)&W[(size_t)(k0 + k1 + 1) * N + n0 + nc];
            const float e0[4] = {r0.x, r0.y, r0.z, r0.w};
            const float e1[4] = {r1.x, r1.y, r1.z, r1.w};
#pragma unroll
            for (int e = 0; e < 4; ++e) {
                int n = nc + e;
                int off = (n >> 4) * 520 + (((k1 >> 3) << 4) + (n & 15)) * 8 + (k1 & 7);
                short h0, m0_, l0, h1, m1_, l1;
                split3(e0[e], h0, m0_, l0);
                split3(e1[e], h1, m1_, l1);
                *(short2*)&Bsl[0][off] = make_short2(h0, h1);
                *(short2*)&Bsl[1][off] = make_short2(m0_, m1_);
                *(short2*)&Bsl[2][off] = make_short2(l0, l1);
            }
        }
        __syncthreads();

        bf16x8 af[3][MT];
#pragma unroll
        for (int p = 0; p < 3; ++p)
#pragma unroll
            for (int i = 0; i < MT; ++i)
                af[p][i] = *(const bf16x8*)&Asl[p][(aslab0 + i) * 520 + lane * 8];

#pragma unroll
        for (int pb = 0; pb < 3; ++pb) {
            bf16x8 bfr[NT];
#pragma unroll
            for (int j = 0; j < NT; ++j)
                bfr[j] = *(const bf16x8*)&Bsl[pb][(bslab0 + j) * 520 + lane * 8];
            const int npa = (pb == 0) ? 3 : (pb == 1 ? 2 : 1);
#pragma unroll
            for (int pa = 0; pa < 3; ++pa) {
                if (pa >= npa) break;
#pragma unroll
                for (int i = 0; i < MT; ++i)
#pragma unroll
                    for (int j = 0; j < NT; ++j)
                        acc[i][j] = __builtin_amdgcn_mfma_f32_16x16x32_bf16(
                            af[pa][i], bfr[j], acc[i][j], 0, 0, 0);
            }
        }
    }

#pragma unroll
    for (int i = 0; i < MT; ++i) {
        int mbase = m0 + (aslab0 + i) * 16 + quad * 4;
#pragma unroll
        for (int j = 0; j < NT; ++j) {
            int n = n0 + (bslab0 + j) * 16 + lrow;
            float bv = bias ? bias[n] : 0.f;
#pragma unroll
            for (int r = 0; r < 4; ++r) {
                size_t off = (size_t)(mbase + r) * ldc + n;
                float v = acc[i][j][r] + bv;
                if (act == 1) v = (v > 20.f) ? v : log1pf(__expf(v));
                if (addC) v += C[off];
                C[off] = v;
            }
        }
    }
}

// ---- variant: A supplied as 3 pre-split bf16 planes (no A split3 in kernel) ----
template<int BM, int BN, int WM, int WN>
__global__ __launch_bounds__(256)
void gemm6p(const unsigned short* __restrict__ Ap0,
            const unsigned short* __restrict__ Ap1,
            const unsigned short* __restrict__ Ap2, int lda,
            const float* __restrict__ W,
            const float* __restrict__ bias,
            float* __restrict__ C, int ldc,
            int M, int N, int K, int act, int addC)
{
    constexpr int MT = BM / WM / 16;
    constexpr int NT = BN / WN / 16;
    constexpr int ASL = BM / 16;
    constexpr int BSL = BN / 16;
    __shared__ short Asl[3][ASL * 520];
    __shared__ short Bsl[3][BSL * 520];

    const int tid = threadIdx.x;
    const int w = tid >> 6, lane = tid & 63;
    const int lrow = lane & 15, quad = lane >> 4;
    const int aslab0 = (w % WM) * MT;
    const int bslab0 = (w / WM) * NT;
    const int m0 = blockIdx.y * BM, n0 = blockIdx.x * BN;

    f32x4 acc[MT][NT] = {};

    for (int k0 = 0; k0 < K; k0 += 32) {
        __syncthreads();
#pragma unroll
        for (int i = 0; i < BM / 32; ++i) {
            int v = tid + 256 * i;
            int row = v >> 3;
            int kq = (v & 7) * 4;
            size_t g = (size_t)(m0 + row) * lda + k0 + kq;
            int off = (row >> 4) * 520 + (((kq >> 3) << 4) + (row & 15)) * 8 + (kq & 7);
            *(short4*)&Asl[0][off] = *(const short4*)&Ap0[g];
            *(short4*)&Asl[1][off] = *(const short4*)&Ap1[g];
            *(short4*)&Asl[2][off] = *(const short4*)&Ap2[g];
        }
        constexpr int NPQS = (BN == 128) ? 5 : 4;
#pragma unroll
        for (int i = 0; i < BN / 64; ++i) {
            int v = tid + 256 * i;
            int kp = v >> NPQS;
            int nc = (v & ((1 << NPQS) - 1)) * 4;
            int k1 = kp * 2;
            float4 r0 = *(const float4*)&W[(size_t)(k0 + k1) * N + n0 + nc];
            float4 r1 = *(const float4*)&W[(size_t)(k0 + k1 + 1) * N + n0 + nc];
            const float e0[4] = {r0.x, r0.y, r0.z, r0.w};
            const float e1[4] = {r1.x, r1.y, r1.z, r1.w};
#pragma unroll
            for (int e = 0; e < 4; ++e) {
                int n = nc + e;
                int off = (n >> 4) * 520 + (((k1 >> 3) << 4) + (n & 15)) * 8 + (k1 & 7);
                short h0, m0_, l0, h1, m1_, l1;
                split3(e0[e], h0, m0_, l0);
                split3(e1[e], h1, m1_, l1);
                *(short2*)&Bsl[0][off] = make_short2(h0, h1);
                *(short2*)&Bsl[1][off] = make_short2(m0_, m1_);
                *(short2*)&Bsl[2][off] = make_short2(l0, l1);
            }
        }
        __syncthreads();

        bf16x8 af[3][MT];
#pragma unroll
        for (int p = 0; p < 3; ++p)
#pragma unroll
            for (int i = 0; i < MT; ++i)
                af[p][i] = *(const bf16x8*)&Asl[p][(aslab0 + i) * 520 + lane * 8];

#pragma unroll
        for (int pb = 0; pb < 3; ++pb) {
            bf16x8 bfr[NT];
#pragma unroll
            for (int j = 0; j < NT; ++j)
                bfr[j] = *(const bf16x8*)&Bsl[pb][(bslab0 + j) * 520 + lane * 8];
            const int npa = (pb == 0) ? 3 : (pb == 1 ? 2 : 1);
#pragma unroll
            for (int pa = 0; pa < 3; ++pa) {
                if (pa >= npa) break;
#pragma unroll
                for (int i = 0; i < MT; ++i)
#pragma unroll
                    for (int j = 0; j < NT; ++j)
                        acc[i][j] = __builtin_amdgcn_mfma_f32_16x16x32_bf16(
                            af[pa][i], bfr[j], acc[i][j], 0, 0, 0);
            }
        }
    }

#pragma unroll
    for (int i = 0; i < MT; ++i) {
        int mbase = m0 + (aslab0 + i) * 16 + quad * 4;
#pragma unroll
        for (int j = 0; j < NT; ++j) {
            int n = n0 + (bslab0 + j) * 16 + lrow;
            float bv = bias ? bias[n] : 0.f;
#pragma unroll
            for (int r = 0; r < 4; ++r) {
                size_t off = (size_t)(mbase + r) * ldc + n;
                float v = acc[i][j][r] + bv;
                if (act == 1) v = (v > 20.f) ? v : log1pf(__expf(v));
                if (addC) v += C[off];
                C[off] = v;
            }
        }
    }
}

// ---- split-K variant for x_proj: 64x64 tile, K-chunk per blockIdx.z, partials out ----
__global__ __launch_bounds__(256)
void gemm6sk(const float* __restrict__ A, int lda,
             const float* __restrict__ W, int N,
             float* __restrict__ P, int M, int KC)
{
    constexpr int BM = 64, BN = 64, WM = 2, WN = 2;
    constexpr int MT = BM / WM / 16, NT = BN / WN / 16;
    __shared__ short Asl[3][4 * 520];
    __shared__ short Bsl[3][4 * 520];

    const int tid = threadIdx.x;
    const int w = tid >> 6, lane = tid & 63;
    const int lrow = lane & 15, quad = lane >> 4;
    const int aslab0 = (w % WM) * MT;
    const int bslab0 = (w / WM) * NT;
    const int m0 = blockIdx.y * BM, n0 = blockIdx.x * BN;
    const int kbeg = blockIdx.z * KC;

    f32x4 acc[MT][NT] = {};

    for (int k0 = kbeg; k0 < kbeg + KC; k0 += 32) {
        __syncthreads();
#pragma unroll
        for (int i = 0; i < BM / 32; ++i) {
            int v = tid + 256 * i;
            int row = v >> 3;
            int kq = (v & 7) * 4;
            float4 val = *(const float4*)&A[(size_t)(m0 + row) * lda + k0 + kq];
            int off = (row >> 4) * 520 + (((kq >> 3) << 4) + (row & 15)) * 8 + (kq & 7);
            short h[4], mm_[4], l[4];
            split3(val.x, h[0], mm_[0], l[0]);
            split3(val.y, h[1], mm_[1], l[1]);
            split3(val.z, h[2], mm_[2], l[2]);
            split3(val.w, h[3], mm_[3], l[3]);
            *(short4*)&Asl[0][off] = make_short4(h[0], h[1], h[2], h[3]);
            *(short4*)&Asl[1][off] = make_short4(mm_[0], mm_[1], mm_[2], mm_[3]);
            *(short4*)&Asl[2][off] = make_short4(l[0], l[1], l[2], l[3]);
        }
        {
            int v = tid;
            int kp = v >> 4;
            int nc = (v & 15) * 4;
            int k1 = kp * 2;
            float4 r0 = *(const float4*)&W[(size_t)(k0 + k1) * N + n0 + nc];
            float4 r1 = *(const float4*)&W[(size_t)(k0 + k1 + 1) * N + n0 + nc];
            const float e0[4] = {r0.x, r0.y, r0.z, r0.w};
            const float e1[4] = {r1.x, r1.y, r1.z, r1.w};
#pragma unroll
            for (int e = 0; e < 4; ++e) {
                int n = nc + e;
                int off = (n >> 4) * 520 + (((k1 >> 3) << 4) + (n & 15)) * 8 + (k1 & 7);
                short h0, m0_, l0, h1, m1_, l1;
                split3(e0[e], h0, m0_, l0);
                split3(e1[e], h1, m1_, l1);
                *(short2*)&Bsl[0][off] = make_short2(h0, h1);
                *(short2*)&Bsl[1][off] = make_short2(m0_, m1_);
                *(short2*)&Bsl[2][off] = make_short2(l0, l1);
            }
        }
        __syncthreads();

        bf16x8 af[3][MT];
#pragma unroll
        for (int p = 0; p < 3; ++p)
#pragma unroll
            for (int i = 0; i < MT; ++i)
                af[p][i] = *(const bf16x8*)&Asl[p][(aslab0 + i) * 520 + lane * 8];

#pragma unroll
        for (int pb = 0; pb < 3; ++pb) {
            bf16x8 bfr[NT];
#pragma unroll
            for (int j = 0; j < NT; ++j)
                bfr[j] = *(const bf16x8*)&Bsl[pb][(bslab0 + j) * 520 + lane * 8];
            const int npa = (pb == 0) ? 3 : (pb == 1 ? 2 : 1);
#pragma unroll
            for (int pa = 0; pa < 3; ++pa) {
                if (pa >= npa) break;
#pragma unroll
                for (int i = 0; i < MT; ++i)
#pragma unroll
                    for (int j = 0; j < NT; ++j)
                        acc[i][j] = __builtin_amdgcn_mfma_f32_16x16x32_bf16(
                            af[pa][i], bfr[j], acc[i][j], 0, 0, 0);
            }
        }
    }

    float* Pz = P + (size_t)blockIdx.z * M * N;
#pragma unroll
    for (int i = 0; i < MT; ++i) {
        int mbase = m0 + (aslab0 + i) * 16 + quad * 4;
#pragma unroll
        for (int j = 0; j < NT; ++j) {
            int n = n0 + (bslab0 + j) * 16 + lrow;
#pragma unroll
            for (int r = 0; r < 4; ++r)
                Pz[(size_t)(mbase + r) * N + n] = acc[i][j][r];
        }
    }
}

// reduce 8 K-chunk partials -> DBL (float4 over 4096x64)
__global__ __launch_bounds__(256)
void xred_k(const float* __restrict__ P, float* __restrict__ D)
{
    int i = blockIdx.x * 256 + threadIdx.x;     // 65536 float4 groups
    const float4* p = (const float4*)P;
    float4 a = p[i];
#pragma unroll
    for (int z = 1; z < 8; ++z) {
        float4 b = p[(size_t)z * 65536 + i];
        a.x += b.x; a.y += b.y; a.z += b.z; a.w += b.w;
    }
    ((float4*)D)[i] = a;
}

// ---------------- RMSNorm -> 3 pre-split bf16 planes ----------------
__global__ __launch_bounds__(256)
void rmsnorm3_k(const float* __restrict__ X, const float* __restrict__ w,
                unsigned short* __restrict__ P0, unsigned short* __restrict__ P1,
                unsigned short* __restrict__ P2)
{
    int wid = threadIdx.x >> 6, lane = threadIdx.x & 63;
    int row = blockIdx.x * 4 + wid;
    const float* xr = X + (size_t)row * DMODEL;
    float v[8];
    float ss = 0.f;
#pragma unroll
    for (int j = 0; j < 8; ++j) { v[j] = xr[lane + 64 * j]; ss = fmaf(v[j], v[j], ss); }
#pragma unroll
    for (int off = 32; off >= 1; off >>= 1) ss += __shfl_xor(ss, off);
    float scale = rsqrtf(ss * (1.f / 512.f) + 1e-5f);
#pragma unroll
    for (int j = 0; j < 8; ++j) {
        int col = lane + 64 * j;
        float val = v[j] * scale * w[col];
        short hh, mm, ll;
        split3(val, hh, mm, ll);
        size_t o = (size_t)row * DMODEL + col;
        P0[o] = (unsigned short)hh;
        P1[o] = (unsigned short)mm;
        P2[o] = (unsigned short)ll;
    }
}

// ---------------- causal depthwise conv (K=4) + SiLU, float4 over d ----------------
__global__ __launch_bounds__(256)
void conv_silu_k(const float* __restrict__ XZ, const float* __restrict__ cw,
                 const float* __restrict__ cb, float* __restrict__ XC)
{
    int idx = blockIdx.x * 256 + threadIdx.x;   // over b*L*256 d-groups
    int d4 = (idx & 255) * 4;
    int t = (idx >> 8) & 511;
    int b = idx >> 17;
    float4 wv[4];
#pragma unroll
    for (int e = 0; e < 4; ++e) wv[e] = *(const float4*)&cw[(d4 + e) * 4];
    float4 bv = *(const float4*)&cb[d4];
    float s[4] = {bv.x, bv.y, bv.z, bv.w};
#pragma unroll
    for (int k = 0; k < 4; ++k) {
        int tt = t + k - 3;
        if (tt >= 0) {
            float4 x = *(const float4*)&XZ[((size_t)(b * 512 + tt)) * 2048 + d4];
            const float xe[4] = {x.x, x.y, x.z, x.w};
            const float we[4] = {wv[0][k], wv[1][k], wv[2][k], wv[3][k]};
#pragma unroll
            for (int e = 0; e < 4; ++e) s[e] = fmaf(we[e], xe[e], s[e]);
        }
    }
    float4 o;
    o.x = s[0] / (1.f + __expf(-s[0]));
    o.y = s[1] / (1.f + __expf(-s[1]));
    o.z = s[2] / (1.f + __expf(-s[2]));
    o.w = s[3] / (1.f + __expf(-s[3]));
    *(float4*)&XC[((size_t)(b * 512 + t)) * 1024 + d4] = o;
}

// ---------------- chunked selective scan: thread per (b,chunk,d), 16 states in regs ----
__global__ __launch_bounds__(128)
void scan1_k(const float* __restrict__ DELTA, const float* __restrict__ XC,
             const float* __restrict__ DBL, const float* __restrict__ A_log,
             const float* __restrict__ Dsk, float* __restrict__ Y,
             float* __restrict__ SC, float* __restrict__ DS)
{
    __shared__ float BC[64][32];       // [t][0:16)=B, [16:32)=C  (broadcast reads)
    const int tid = threadIdx.x;
    const int d = blockIdx.x * 128 + tid;
    const int chunk = blockIdx.y;
    const int b = blockIdx.z;
    const int t0 = chunk * 64;

#pragma unroll
    for (int i = 0; i < 16; ++i) {
        int idx = tid + 128 * i;
        int t = idx >> 5, j = idx & 31;
        BC[t][j] = DBL[(size_t)(b * 512 + t0 + t) * 64 + 32 + j];
    }
    float Ac[16];
#pragma unroll
    for (int n = 0; n < 16; ++n) Ac[n] = -__expf(A_log[d * 16 + n]);
    float Dv = Dsk[d];
    __syncthreads();

    const float* dp = DELTA + ((size_t)(b * 512 + t0)) * 1024 + d;
    const float* up = XC    + ((size_t)(b * 512 + t0)) * 1024 + d;
    float* yp       = Y     + ((size_t)(b * 512 + t0)) * 1024 + d;

    float h[16];
#pragma unroll
    for (int n = 0; n < 16; ++n) h[n] = 0.f;
    float dsum = 0.f;

#pragma unroll 2
    for (int t = 0; t < 64; ++t) {
        float delta = dp[t * 1024];
        float u = up[t * 1024];
        dsum += delta;
        float du = delta * u;
        float y = 0.f;
#pragma unroll
        for (int n = 0; n < 16; ++n) {
            h[n] = fmaf(__expf(delta * Ac[n]), h[n], du * BC[t][n]);
            y = fmaf(h[n], BC[t][16 + n], y);
        }
        yp[t * 1024] = fmaf(u, Dv, y);
    }

    float* sc = SC + ((size_t)((b * 8 + chunk) * 1024 + d)) * 16;
#pragma unroll
    for (int n = 0; n < 16; ++n) sc[n] = h[n];
    DS[(size_t)(b * 8 + chunk) * 1024 + d] = dsum;
}

__global__ __launch_bounds__(256)
void scan2_k(const float* __restrict__ A_log, float* __restrict__ SC,
             const float* __restrict__ DS)
{
    int gid = blockIdx.x * 256 + threadIdx.x;   // b*16384 + d*16 + n
    int n = gid & 15;
    int d = (gid >> 4) & 1023;
    int b = gid >> 14;
    float Ac = -__expf(A_log[d * 16 + n]);
    float carry = 0.f;
#pragma unroll
    for (int c = 0; c < 8; ++c) {
        size_t off = ((size_t)((b * 8 + c) * 1024 + d)) * 16 + n;
        float s = SC[off];
        SC[off] = carry;
        carry = fmaf(__expf(Ac * DS[(size_t)(b * 8 + c) * 1024 + d]), carry, s);
    }
}

__global__ __launch_bounds__(128)
void scan3_k(const float* __restrict__ DELTA, const float* __restrict__ DBL,
             const float* __restrict__ A_log, const float* __restrict__ H0,
             const float* __restrict__ XZ, float* __restrict__ Y)
{
    __shared__ float Cs[64][16];
    const int tid = threadIdx.x;
    const int d = blockIdx.x * 128 + tid;
    const int chunk = blockIdx.y;
    const int b = blockIdx.z;
    const int t0 = chunk * 64;

#pragma unroll
    for (int i = 0; i < 8; ++i) {
        int idx = tid + 128 * i;
        int t = idx >> 4, j = idx & 15;
        Cs[t][j] = DBL[(size_t)(b * 512 + t0 + t) * 64 + 48 + j];
    }
    float Ac[16], h0[16];
#pragma unroll
    for (int n = 0; n < 16; ++n) Ac[n] = -__expf(A_log[d * 16 + n]);
    const float* h0p = H0 + ((size_t)((b * 8 + chunk) * 1024 + d)) * 16;
#pragma unroll
    for (int n = 0; n < 16; ++n) h0[n] = h0p[n];
    __syncthreads();

    const float* dp = DELTA + ((size_t)(b * 512 + t0)) * 1024 + d;
    const float* zp = XZ    + ((size_t)(b * 512 + t0)) * 2048 + 1024 + d;
    float* yp       = Y     + ((size_t)(b * 512 + t0)) * 1024 + d;

    float cum = 0.f;
    if (chunk == 0) {
#pragma unroll 2
        for (int t = 0; t < 64; ++t) {
            float z = zp[t * 2048];
            yp[t * 1024] *= z / (1.f + __expf(-z));
        }
    } else {
#pragma unroll 2
        for (int t = 0; t < 64; ++t) {
            float delta = dp[t * 1024];
            cum += delta;
            float p = 0.f;
#pragma unroll
            for (int n = 0; n < 16; ++n)
                p = fmaf(h0[n] * __expf(Ac[n] * cum), Cs[t][n], p);
            float z = zp[t * 2048];
            float yv = yp[t * 1024] + p;
            yp[t * 1024] = yv * (z / (1.f + __expf(-z)));
        }
    }
}

// ---------------- MFMA flash attention, exact fp32 via bf16x6 ----------------
__global__ __launch_bounds__(256, 1)
void attn_mfma(const float* __restrict__ Qm, const float* __restrict__ Km,
               const float* __restrict__ Vm, float* __restrict__ CTX)
{
    __shared__ short KVs[3][16 * 520];      // 16 frag-tiles per plane
    __shared__ float Ps[4][16 * 260];       // per-wave P strip (16 q x 256 kv, pad 260)
    const int tid = threadIdx.x;
    const int w = tid >> 6, lane = tid & 63;
    const int lrow = lane & 15, quad = lane >> 4;
    const int b = blockIdx.z, h = blockIdx.y;
    const int qw = blockIdx.x * 64 + w * 16;

    bf16x8 qf[3][4];
    {
        const float* qp = Qm + ((size_t)(b * 512 + qw + lrow)) * 512 + h * 128 + quad * 8;
#pragma unroll
        for (int kb = 0; kb < 4; ++kb) {
            float4 v0 = *(const float4*)(qp + kb * 32);
            float4 v1 = *(const float4*)(qp + kb * 32 + 4);
            const float e[8] = {v0.x, v0.y, v0.z, v0.w, v1.x, v1.y, v1.z, v1.w};
#pragma unroll
            for (int j = 0; j < 8; ++j) {
                short hh, mm, ll;
                split3(e[j], hh, mm, ll);
                qf[0][kb][j] = hh; qf[1][kb][j] = mm; qf[2][kb][j] = ll;
            }
        }
    }

    const int sdd = (tid & 31) * 4;
    const int skvb = tid >> 5;
    f32x4 sa[4][4] = {};

    float4 kpre[8];
#pragma unroll
    for (int i = 0; i < 8; ++i)
        kpre[i] = *(const float4*)&Km[((size_t)(b * 256 + skvb + 8 * i)) * 512 + h * 128 + sdd];

    for (int c = 0; c < 4; ++c) {
        if (c) __syncthreads();
        {
            const int kb = sdd >> 5, qd = (sdd >> 3) & 3, jd = sdd & 7;
#pragma unroll
            for (int i = 0; i < 8; ++i) {
                int kv = skvb + 8 * i;
                int off = ((kv >> 4) * 4 + kb) * 520 + ((kv & 15) + 16 * qd) * 8 + jd;
                short h0,m0,l0,h1,m1,l1,h2,m2,l2,h3,m3,l3;
                split3(kpre[i].x,h0,m0,l0); split3(kpre[i].y,h1,m1,l1);
                split3(kpre[i].z,h2,m2,l2); split3(kpre[i].w,h3,m3,l3);
                *(short4*)&KVs[0][off] = make_short4(h0,h1,h2,h3);
                *(short4*)&KVs[1][off] = make_short4(m0,m1,m2,m3);
                *(short4*)&KVs[2][off] = make_short4(l0,l1,l2,l3);
            }
        }
        if (c < 3) {
#pragma unroll
            for (int i = 0; i < 8; ++i)
                kpre[i] = *(const float4*)&Km[((size_t)(b * 256 + (c + 1) * 64 + skvb + 8 * i)) * 512 + h * 128 + sdd];
        }
        __syncthreads();
#pragma unroll
        for (int s = 0; s < 4; ++s) {
#pragma unroll
            for (int kb = 0; kb < 4; ++kb) {
                bf16x8 kf[3];
#pragma unroll
                for (int p = 0; p < 3; ++p)
                    kf[p] = *(const bf16x8*)&KVs[p][(s * 4 + kb) * 520 + lane * 8];
                sa[c][s] = __builtin_amdgcn_mfma_f32_16x16x32_bf16(qf[0][kb], kf[0], sa[c][s], 0, 0, 0);
                sa[c][s] = __builtin_amdgcn_mfma_f32_16x16x32_bf16(qf[0][kb], kf[1], sa[c][s], 0, 0, 0);
                sa[c][s] = __builtin_amdgcn_mfma_f32_16x16x32_bf16(qf[1][kb], kf[0], sa[c][s], 0, 0, 0);
                sa[c][s] = __builtin_amdgcn_mfma_f32_16x16x32_bf16(qf[0][kb], kf[2], sa[c][s], 0, 0, 0);
                sa[c][s] = __builtin_amdgcn_mfma_f32_16x16x32_bf16(qf[1][kb], kf[1], sa[c][s], 0, 0, 0);
                sa[c][s] = __builtin_amdgcn_mfma_f32_16x16x32_bf16(qf[2][kb], kf[0], sa[c][s], 0, 0, 0);
            }
        }
    }

    const float scale = 0.08838834764831845f;
    float mx[4] = {-1e30f, -1e30f, -1e30f, -1e30f};
#pragma unroll
    for (int c = 0; c < 4; ++c)
#pragma unroll
        for (int s = 0; s < 4; ++s)
#pragma unroll
            for (int r = 0; r < 4; ++r) {
                sa[c][s][r] *= scale;
                mx[r] = fmaxf(mx[r], sa[c][s][r]);
            }
#pragma unroll
    for (int r = 0; r < 4; ++r) {
        mx[r] = fmaxf(mx[r], __shfl_xor(mx[r], 1));
        mx[r] = fmaxf(mx[r], __shfl_xor(mx[r], 2));
        mx[r] = fmaxf(mx[r], __shfl_xor(mx[r], 4));
        mx[r] = fmaxf(mx[r], __shfl_xor(mx[r], 8));
    }
    float sum[4] = {0.f, 0.f, 0.f, 0.f};
#pragma unroll
    for (int c = 0; c < 4; ++c)
#pragma unroll
        for (int s = 0; s < 4; ++s)
#pragma unroll
            for (int r = 0; r < 4; ++r) {
                float e = __expf(sa[c][s][r] - mx[r]);
                sa[c][s][r] = e;
                sum[r] += e;
            }
#pragma unroll
    for (int r = 0; r < 4; ++r) {
        sum[r] += __shfl_xor(sum[r], 1);
        sum[r] += __shfl_xor(sum[r], 2);
        sum[r] += __shfl_xor(sum[r], 4);
        sum[r] += __shfl_xor(sum[r], 8);
        sum[r] = 1.f / sum[r];
    }
    {
        float* ps = &Ps[w][0];
#pragma unroll
        for (int c = 0; c < 4; ++c)
#pragma unroll
            for (int s = 0; s < 4; ++s)
#pragma unroll
                for (int r = 0; r < 4; ++r)
                    ps[(quad * 4 + r) * 260 + c * 64 + s * 16 + lrow] = sa[c][s][r] * sum[r];
    }

    const int vdd4 = (tid & 31) * 4;
    const int vkvg = tid >> 5;
    f32x4 oa[8] = {};
    float4 vpre[8];
#pragma unroll
    for (int i = 0; i < 2; ++i) {
        int kv0 = (vkvg + 8 * i) * 4;
#pragma unroll
        for (int rr = 0; rr < 4; ++rr)
            vpre[i * 4 + rr] = *(const float4*)&Vm[((size_t)(b * 256 + kv0 + rr)) * 512 + h * 128 + vdd4];
    }

    for (int c = 0; c < 4; ++c) {
        __syncthreads();
        {
#pragma unroll
            for (int i = 0; i < 2; ++i) {
                int kv0 = (vkvg + 8 * i) * 4;
                int kb2 = kv0 >> 5, qk = (kv0 >> 3) & 3, jb = kv0 & 7;
                const float4 r0 = vpre[i * 4 + 0], r1 = vpre[i * 4 + 1];
                const float4 r2 = vpre[i * 4 + 2], r3 = vpre[i * 4 + 3];
                const float ve[4][4] = {{r0.x, r1.x, r2.x, r3.x},
                                        {r0.y, r1.y, r2.y, r3.y},
                                        {r0.z, r1.z, r2.z, r3.z},
                                        {r0.w, r1.w, r2.w, r3.w}};
#pragma unroll
                for (int e = 0; e < 4; ++e) {
                    int dd = vdd4 + e;
                    int off = ((dd >> 4) * 2 + kb2) * 520 + ((dd & 15) + 16 * qk) * 8 + jb;
                    short h0,m0,l0,h1,m1,l1,h2,m2,l2,h3,m3,l3;
                    split3(ve[e][0],h0,m0,l0); split3(ve[e][1],h1,m1,l1);
                    split3(ve[e][2],h2,m2,l2); split3(ve[e][3],h3,m3,l3);
                    *(short4*)&KVs[0][off] = make_short4(h0,h1,h2,h3);
                    *(short4*)&KVs[1][off] = make_short4(m0,m1,m2,m3);
                    *(short4*)&KVs[2][off] = make_short4(l0,l1,l2,l3);
                }
            }
        }
        if (c < 3) {
#pragma unroll
            for (int i = 0; i < 2; ++i) {
                int kv0 = (vkvg + 8 * i) * 4;
#pragma unroll
                for (int rr = 0; rr < 4; ++rr)
                    vpre[i * 4 + rr] = *(const float4*)&Vm[((size_t)(b * 256 + (c + 1) * 64 + kv0 + rr)) * 512 + h * 128 + vdd4];
            }
        }
        __syncthreads();
#pragma unroll
        for (int kb2 = 0; kb2 < 2; ++kb2) {
            const float* pp = &Ps[w][lrow * 260 + c * 64 + kb2 * 32 + quad * 8];
            float4 a0 = *(const float4*)pp;
            float4 a1 = *(const float4*)(pp + 4);
            const float e[8] = {a0.x, a0.y, a0.z, a0.w, a1.x, a1.y, a1.z, a1.w};
            bf16x8 af[3];
#pragma unroll
            for (int j = 0; j < 8; ++j) {
                short hh, mm, ll;
                split3(e[j], hh, mm, ll);
                af[0][j] = hh; af[1][j] = mm; af[2][j] = ll;
            }
#pragma unroll
            for (int s = 0; s < 8; ++s) {
                bf16x8 vf[3];
#pragma unroll
                for (int p = 0; p < 3; ++p)
                    vf[p] = *(const bf16x8*)&KVs[p][(s * 2 + kb2) * 520 + lane * 8];
                oa[s] = __builtin_amdgcn_mfma_f32_16x16x32_bf16(af[0], vf[0], oa[s], 0, 0, 0);
                oa[s] = __builtin_amdgcn_mfma_f32_16x16x32_bf16(af[0], vf[1], oa[s], 0, 0, 0);
                oa[s] = __builtin_amdgcn_mfma_f32_16x16x32_bf16(af[1], vf[0], oa[s], 0, 0, 0);
                oa[s] = __builtin_amdgcn_mfma_f32_16x16x32_bf16(af[0], vf[2], oa[s], 0, 0, 0);
                oa[s] = __builtin_amdgcn_mfma_f32_16x16x32_bf16(af[1], vf[1], oa[s], 0, 0, 0);
                oa[s] = __builtin_amdgcn_mfma_f32_16x16x32_bf16(af[2], vf[0], oa[s], 0, 0, 0);
            }
        }
    }

#pragma unroll
    for (int s = 0; s < 8; ++s)
#pragma unroll
        for (int r = 0; r < 4; ++r)
            CTX[((size_t)(b * 512 + qw + quad * 4 + r)) * 512 + h * 128 + s * 16 + lrow] = oa[s][r];
}

// ---------------- final linear (512->6) + argmax, one wave per row ----------------
__global__ __launch_bounds__(256)
void head_k(const float* __restrict__ T2, const float* __restrict__ Wout,
            const float* __restrict__ bout, float* __restrict__ out)
{
    int wid = threadIdx.x >> 6, lane = threadIdx.x & 63;
    int row = blockIdx.x * 4 + wid;
    float acc[6] = {0.f, 0.f, 0.f, 0.f, 0.f, 0.f};
    const float* tr = T2 + (size_t)row * 512;
#pragma unroll
    for (int j = 0; j < 8; ++j) {
        int k = lane + 64 * j;
        float t = tr[k];
#pragma unroll
        for (int c = 0; c < 6; ++c) acc[c] = fmaf(t, Wout[k * 6 + c], acc[c]);
    }
#pragma unroll
    for (int c = 0; c < 6; ++c) {
#pragma unroll
        for (int off = 32; off >= 1; off >>= 1) acc[c] += __shfl_xor(acc[c], off);
    }
    if (lane == 0) {
        float best = -1e30f;
        int bi = 0;
#pragma unroll
        for (int c = 0; c < 6; ++c) {
            float v = acc[c] + bout[c];
            out[(size_t)row * 6 + c] = v;
            if (v > best) { best = v; bi = c; }
        }
        out[(size_t)4096 * 6 + row] = (float)bi;
    }
}

extern "C" void kernel_launch(void* const* d_in, const int* in_sizes, int n_in,
                              void* d_out, int out_size, void* d_ws, size_t ws_size,
                              hipStream_t stream)
{
    (void)in_sizes; (void)n_in; (void)out_size; (void)ws_size;
    const float* agent      = (const float*)d_in[0];
    const float* lane       = (const float*)d_in[1];
    const float* lane_in_W  = (const float*)d_in[2];
    const float* lane_in_b  = (const float*)d_in[3];
    const float* norm_w     = (const float*)d_in[4];
    const float* in_proj_W  = (const float*)d_in[5];
    const float* conv_w     = (const float*)d_in[6];
    const float* conv_b     = (const float*)d_in[7];
    const float* x_proj_W   = (const float*)d_in[8];
    const float* dt_proj_W  = (const float*)d_in[9];
    const float* dt_proj_b  = (const float*)d_in[10];
    const float* A_log      = (const float*)d_in[11];
    const float* D_skip     = (const float*)d_in[12];
    const float* out_proj_W = (const float*)d_in[13];
    const float* final_norm_w = (const float*)d_in[14];
    const float* Wq = (const float*)d_in[15];
    const float* Wk = (const float*)d_in[16];
    const float* Wv = (const float*)d_in[17];
    const float* Wo = (const float*)d_in[18];
    const float* bq = (const float*)d_in[19];
    const float* bk = (const float*)d_in[20];
    const float* bv = (const float*)d_in[21];
    const float* bo = (const float*)d_in[22];
    const float* lin_in_W  = (const float*)d_in[23];
    const float* lin_in_b  = (const float*)d_in[24];
    const float* lin_out_W = (const float*)d_in[25];
    const float* lin_out_b = (const float*)d_in[26];

    // Workspace: same 97 MB footprint that passed tripwires (rounds 1/3-8).
    float* ws = (float*)d_ws;
    float* X     = ws;                      // 2M floats (4096 x 512)
    float* H     = X + (1 << 21);           // 2M
    float* XZ    = H + (1 << 21);           // 8M  (4096 x 2048)
    float* XC    = XZ + (1 << 23);          // 4M  (4096 x 1024)
    float* DELTA = XC + (1 << 22);          // 4M
    float* Y     = DELTA + (1 << 22);       // 4M
    float* DBL   = Y + (1 << 22);           // 256K (4096 x 64)
    // aliases with disjoint lifetimes within a layer:
    unsigned short* Hp0 = (unsigned short*)H;              // 2M shorts (rmsnorm->in_proj)
    unsigned short* Hp1 = (unsigned short*)(H + (1 << 20));// 2M shorts
    unsigned short* Hp2 = (unsigned short*)Y;              // 2M shorts (dead until scan1)
    float* PART  = Y + (1 << 20);           // 2M floats: x_proj split-K partials
    float* SCb   = H;                       // 1M  SC[b][chunk][d][n] (scan phase)
    float* DSb   = H + (1 << 20);           // 64K DS[b][chunk][d]   (scan phase)
    float* Qb  = XZ;                        // 2M (MHA phase)
    float* Kb  = XZ + (1 << 21);            // 1M (2048 x 512)
    float* Vb  = Kb + (1 << 20);            // 1M
    float* CTX = Vb + (1 << 20);            // 2M
    float* AO  = CTX + (1 << 21);           // 2M
    float* T2  = XC;                        // 2M

    dim3 blk(256);
    dim3 sblk(128);
    dim3 sgrid(8, 8, 8);                    // (d-group, chunk, b)

    // x = lane_features @ lane_in_W + b   (4096x128 @ 128x512)
    gemm6<128, 64, 2, 2><<<dim3(8, 32), blk, 0, stream>>>(
        lane, 128, lane_in_W, lane_in_b, X, 512, 4096, 512, 128, 0, 0);

    for (int i = 0; i < 4; ++i) {
        rmsnorm3_k<<<1024, blk, 0, stream>>>(X, norm_w + i * 512, Hp0, Hp1, Hp2);
        // xz = h @ in_proj  (4096x512 @ 512x2048), A pre-split
        gemm6p<128, 128, 2, 2><<<dim3(16, 32), blk, 0, stream>>>(
            Hp0, Hp1, Hp2, 512, in_proj_W + (size_t)i * 512 * 2048, nullptr, XZ, 2048,
            4096, 2048, 512, 0, 0);
        conv_silu_k<<<4096, blk, 0, stream>>>(XZ, conv_w + i * 4096, conv_b + i * 1024, XC);
        // dbl = xc @ x_proj  (4096x1024 @ 1024x64): split-K over 8 chunks + reduce
        gemm6sk<<<dim3(1, 64, 8), blk, 0, stream>>>(
            XC, 1024, x_proj_W + (size_t)i * 1024 * 64, 64, PART, 4096, 128);
        xred_k<<<256, blk, 0, stream>>>(PART, DBL);
        // delta = softplus(dt @ dt_proj + b)  (4096x32 @ 32x1024)
        gemm6<128, 64, 2, 2><<<dim3(16, 32), blk, 0, stream>>>(
            DBL, 64, dt_proj_W + (size_t)i * 32 * 1024, dt_proj_b + i * 1024,
            DELTA, 1024, 4096, 1024, 32, 1, 0);
        // chunked scan (3 phases) + fused gating
        scan1_k<<<sgrid, sblk, 0, stream>>>(DELTA, XC, DBL, A_log + (size_t)i * 1024 * 16,
                                            D_skip + i * 1024, Y, SCb, DSb);
        scan2_k<<<512, blk, 0, stream>>>(A_log + (size_t)i * 1024 * 16, SCb, DSb);
        scan3_k<<<sgrid, sblk, 0, stream>>>(DELTA, DBL, A_log + (size_t)i * 1024 * 16,
                                            SCb, XZ, Y);
        // x += ygated @ out_proj  (4096x1024 @ 1024x512)
        gemm6<128, 64, 2, 2><<<dim3(8, 32), blk, 0, stream>>>(
            Y, 1024, out_proj_W + (size_t)i * 1024 * 512, nullptr, X, 512,
            4096, 512, 1024, 0, 1);
    }

    rmsnorm3_k<<<1024, blk, 0, stream>>>(X, final_norm_w, Hp0, Hp1, Hp2);   // enhanced

    gemm6p<128, 64, 2, 2><<<dim3(8, 32), blk, 0, stream>>>(
        Hp0, Hp1, Hp2, 512, Wq, bq, Qb, 512, 4096, 512, 512, 0, 0);
    gemm6<64, 64, 2, 2><<<dim3(8, 32), blk, 0, stream>>>(
        agent, 512, Wk, bk, Kb, 512, 2048, 512, 512, 0, 0);
    gemm6<64, 64, 2, 2><<<dim3(8, 32), blk, 0, stream>>>(
        agent, 512, Wv, bv, Vb, 512, 2048, 512, 512, 0, 0);
    attn_mfma<<<dim3(8, 4, 8), blk, 0, stream>>>(Qb, Kb, Vb, CTX);
    gemm6<128, 64, 2, 2><<<dim3(8, 32), blk, 0, stream>>>(
        CTX, 512, Wo, bo, AO, 512, 4096, 512, 512, 0, 0);
    gemm6<128, 64, 2, 2><<<dim3(8, 32), blk, 0, stream>>>(
        AO, 512, lin_in_W, lin_in_b, T2, 512, 4096, 512, 512, 0, 0);
    head_k<<<1024, blk, 0, stream>>>(T2, lin_out_W, lin_out_b, (float*)d_out);
}

// Round 10
// 1296.579 us; speedup vs baseline: 2.1824x; 1.0542x over previous
//
#include <hip/hip_runtime.h>
#include <math.h>

#define BATCH 8
#define LSEQ 512
#define LAGENT 256
#define DMODEL 512
#define DINNER 1024
#define DSTATE 16
#define DTRANK 32
#define NHEAD 4
#define DHEAD 128
#define NLANES 6

typedef __attribute__((ext_vector_type(8))) short bf16x8;
typedef __attribute__((ext_vector_type(4))) float f32x4;

// Exact 3-way bf16 split: x = h + m + l + O(2^-24 |x|); all subtractions exact.
__device__ __forceinline__ void split3(float x, short& h, short& m, short& l)
{
    unsigned hb = __float_as_uint(x) & 0xFFFF0000u;
    h = (short)(hb >> 16);
    float r1 = x - __uint_as_float(hb);
    unsigned mb = __float_as_uint(r1) & 0xFFFF0000u;
    m = (short)(mb >> 16);
    float r2 = r1 - __uint_as_float(mb);
    l = (short)(__float_as_uint(r2) >> 16);
}

// ---- JIT weight presplit: W[K][N] fp32 -> 3 bf16 planes, fragment-linear ----
// plane layout: [k0/32][n/16][lane*8+j] with lane=(quad= (k&31)>>3)*16 + (n&15), j=k&7
__global__ __launch_bounds__(256)
void wsplit_k(const float* __restrict__ W, short* __restrict__ Wp, int K, int N)
{
    int gid = blockIdx.x * 256 + threadIdx.x;
    int lane = gid & 63;
    int rest = gid >> 6;
    int nsl = N >> 4;
    int ns = rest % nsl, kc = rest / nsl;
    int lrow = lane & 15, quad = lane >> 4;
    const float* src = W + (size_t)(kc * 32 + quad * 8) * N + ns * 16 + lrow;
    bf16x8 h, m, l;
#pragma unroll
    for (int j = 0; j < 8; ++j) {
        short hh, mm, ll;
        split3(src[(size_t)j * N], hh, mm, ll);
        h[j] = hh; m[j] = mm; l[j] = ll;
    }
    size_t planeS = (size_t)K * N;
    size_t base = ((size_t)(kc * nsl + ns)) * 512 + lane * 8;
    *(bf16x8*)&Wp[base] = h;
    *(bf16x8*)&Wp[planeS + base] = m;
    *(bf16x8*)&Wp[2 * planeS + base] = l;
}

// ---------------- gemm6: A fp32 in-kernel split, B fp32 in-kernel split ----------------
// (kept for dt_proj where K=32 makes staging negligible)
template<int BM, int BN, int WM, int WN>
__global__ __launch_bounds__(256)
void gemm6(const float* __restrict__ A, int lda,
           const float* __restrict__ W,
           const float* __restrict__ bias,
           float* __restrict__ C, int ldc,
           int M, int N, int K, int act, int addC)
{
    constexpr int MT = BM / WM / 16;
    constexpr int NT = BN / WN / 16;
    constexpr int ASL = BM / 16;
    constexpr int BSL = BN / 16;
    __shared__ short Asl[3][ASL * 520];
    __shared__ short Bsl[3][BSL * 520];

    const int tid = threadIdx.x;
    const int w = tid >> 6, lane = tid & 63;
    const int lrow = lane & 15, quad = lane >> 4;
    const int aslab0 = (w % WM) * MT;
    const int bslab0 = (w / WM) * NT;
    const int m0 = blockIdx.y * BM, n0 = blockIdx.x * BN;

    f32x4 acc[MT][NT] = {};

    for (int k0 = 0; k0 < K; k0 += 32) {
        __syncthreads();
#pragma unroll
        for (int i = 0; i < BM / 32; ++i) {
            int v = tid + 256 * i;
            int row = v >> 3;
            int kq = (v & 7) * 4;
            float4 val = *(const float4*)&A[(size_t)(m0 + row) * lda + k0 + kq];
            int off = (row >> 4) * 520 + (((kq >> 3) << 4) + (row & 15)) * 8 + (kq & 7);
            short h[4], mm_[4], l[4];
            split3(val.x, h[0], mm_[0], l[0]);
            split3(val.y, h[1], mm_[1], l[1]);
            split3(val.z, h[2], mm_[2], l[2]);
            split3(val.w, h[3], mm_[3], l[3]);
            *(short4*)&Asl[0][off] = make_short4(h[0], h[1], h[2], h[3]);
            *(short4*)&Asl[1][off] = make_short4(mm_[0], mm_[1], mm_[2], mm_[3]);
            *(short4*)&Asl[2][off] = make_short4(l[0], l[1], l[2], l[3]);
        }
        constexpr int NPQS = (BN == 128) ? 5 : 4;
#pragma unroll
        for (int i = 0; i < BN / 64; ++i) {
            int v = tid + 256 * i;
            int kp = v >> NPQS;
            int nc = (v & ((1 << NPQS) - 1)) * 4;
            int k1 = kp * 2;
            float4 r0 = *(const float4*)&W[(size_t)(k0 + k1) * N + n0 + nc];
            float4 r1 = *(const float4*)&W[(size_t)(k0 + k1 + 1) * N + n0 + nc];
            const float e0[4] = {r0.x, r0.y, r0.z, r0.w};
            const float e1[4] = {r1.x, r1.y, r1.z, r1.w};
#pragma unroll
            for (int e = 0; e < 4; ++e) {
                int n = nc + e;
                int off = (n >> 4) * 520 + (((k1 >> 3) << 4) + (n & 15)) * 8 + (k1 & 7);
                short h0, m0_, l0, h1, m1_, l1;
                split3(e0[e], h0, m0_, l0);
                split3(e1[e], h1, m1_, l1);
                *(short2*)&Bsl[0][off] = make_short2(h0, h1);
                *(short2*)&Bsl[1][off] = make_short2(m0_, m1_);
                *(short2*)&Bsl[2][off] = make_short2(l0, l1);
            }
        }
        __syncthreads();

        bf16x8 af[3][MT];
#pragma unroll
        for (int p = 0; p < 3; ++p)
#pragma unroll
            for (int i = 0; i < MT; ++i)
                af[p][i] = *(const bf16x8*)&Asl[p][(aslab0 + i) * 520 + lane * 8];

#pragma unroll
        for (int pb = 0; pb < 3; ++pb) {
            bf16x8 bfr[NT];
#pragma unroll
            for (int j = 0; j < NT; ++j)
                bfr[j] = *(const bf16x8*)&Bsl[pb][(bslab0 + j) * 520 + lane * 8];
            const int npa = (pb == 0) ? 3 : (pb == 1 ? 2 : 1);
#pragma unroll
            for (int pa = 0; pa < 3; ++pa) {
                if (pa >= npa) break;
#pragma unroll
                for (int i = 0; i < MT; ++i)
#pragma unroll
                    for (int j = 0; j < NT; ++j)
                        acc[i][j] = __builtin_amdgcn_mfma_f32_16x16x32_bf16(
                            af[pa][i], bfr[j], acc[i][j], 0, 0, 0);
            }
        }
    }

#pragma unroll
    for (int i = 0; i < MT; ++i) {
        int mbase = m0 + (aslab0 + i) * 16 + quad * 4;
#pragma unroll
        for (int j = 0; j < NT; ++j) {
            int n = n0 + (bslab0 + j) * 16 + lrow;
            float bv = bias ? bias[n] : 0.f;
#pragma unroll
            for (int r = 0; r < 4; ++r) {
                size_t off = (size_t)(mbase + r) * ldc + n;
                float v = acc[i][j][r] + bv;
                if (act == 1) v = (v > 20.f) ? v : log1pf(__expf(v));
                if (addC) v += C[off];
                C[off] = v;
            }
        }
    }
}

// ---- gemm6f: A = 3 pre-split bf16 planes (row-linear), B = pre-split fragment-linear ----
template<int BM, int BN, int WM, int WN>
__global__ __launch_bounds__(256)
void gemm6f(const unsigned short* __restrict__ Ap0,
            const unsigned short* __restrict__ Ap1,
            const unsigned short* __restrict__ Ap2, int lda,
            const short* __restrict__ Wp,
            const float* __restrict__ bias,
            float* __restrict__ C, int ldc,
            int M, int N, int K, int act, int addC)
{
    constexpr int MT = BM / WM / 16;
    constexpr int NT = BN / WN / 16;
    constexpr int ASL = BM / 16;
    constexpr int BSL = BN / 16;
    constexpr int BITER = (3 * BSL) / 4;          // ushort8 copies per thread
    constexpr int PSH = (BSL == 8) ? 9 : 8;       // idx -> plane shift
    __shared__ short Asl[3][ASL * 520];
    __shared__ short Bsl[3][BSL * 512];

    const int tid = threadIdx.x;
    const int w = tid >> 6, lane = tid & 63;
    const int lrow = lane & 15, quad = lane >> 4;
    const int aslab0 = (w % WM) * MT;
    const int bslab0 = (w / WM) * NT;
    const int m0 = blockIdx.y * BM, n0 = blockIdx.x * BN;
    const size_t planeS = (size_t)K * N;

    f32x4 acc[MT][NT] = {};

    for (int k0 = 0; k0 < K; k0 += 32) {
        __syncthreads();
#pragma unroll
        for (int i = 0; i < BM / 32; ++i) {
            int v = tid + 256 * i;
            int row = v >> 3;
            int kq = (v & 7) * 4;
            size_t g = (size_t)(m0 + row) * lda + k0 + kq;
            int off = (row >> 4) * 520 + (((kq >> 3) << 4) + (row & 15)) * 8 + (kq & 7);
            *(short4*)&Asl[0][off] = *(const short4*)&Ap0[g];
            *(short4*)&Asl[1][off] = *(const short4*)&Ap1[g];
            *(short4*)&Asl[2][off] = *(const short4*)&Ap2[g];
        }
        {
            const short* wb = Wp + ((size_t)(k0 >> 5) * (N >> 4) + (n0 >> 4)) * 512;
#pragma unroll
            for (int i = 0; i < BITER; ++i) {
                int idx = tid + 256 * i;
                int p = idx >> PSH;
                int r = idx & ((1 << PSH) - 1);
                *(int4*)&Bsl[p][r * 8] = *(const int4*)(wb + p * planeS + r * 8);
            }
        }
        __syncthreads();

        bf16x8 af[3][MT];
#pragma unroll
        for (int p = 0; p < 3; ++p)
#pragma unroll
            for (int i = 0; i < MT; ++i)
                af[p][i] = *(const bf16x8*)&Asl[p][(aslab0 + i) * 520 + lane * 8];

#pragma unroll
        for (int pb = 0; pb < 3; ++pb) {
            bf16x8 bfr[NT];
#pragma unroll
            for (int j = 0; j < NT; ++j)
                bfr[j] = *(const bf16x8*)&Bsl[pb][(bslab0 + j) * 512 + lane * 8];
            const int npa = (pb == 0) ? 3 : (pb == 1 ? 2 : 1);
#pragma unroll
            for (int pa = 0; pa < 3; ++pa) {
                if (pa >= npa) break;
#pragma unroll
                for (int i = 0; i < MT; ++i)
#pragma unroll
                    for (int j = 0; j < NT; ++j)
                        acc[i][j] = __builtin_amdgcn_mfma_f32_16x16x32_bf16(
                            af[pa][i], bfr[j], acc[i][j], 0, 0, 0);
            }
        }
    }

#pragma unroll
    for (int i = 0; i < MT; ++i) {
        int mbase = m0 + (aslab0 + i) * 16 + quad * 4;
#pragma unroll
        for (int j = 0; j < NT; ++j) {
            int n = n0 + (bslab0 + j) * 16 + lrow;
            float bv = bias ? bias[n] : 0.f;
#pragma unroll
            for (int r = 0; r < 4; ++r) {
                size_t off = (size_t)(mbase + r) * ldc + n;
                float v = acc[i][j][r] + bv;
                if (act == 1) v = (v > 20.f) ? v : log1pf(__expf(v));
                if (addC) v += C[off];
                C[off] = v;
            }
        }
    }
}

// ---- gemm6g: A fp32 (in-kernel split), B pre-split fragment-linear ----
template<int BM, int BN, int WM, int WN>
__global__ __launch_bounds__(256)
void gemm6g(const float* __restrict__ A, int lda,
            const short* __restrict__ Wp,
            const float* __restrict__ bias,
            float* __restrict__ C, int ldc,
            int M, int N, int K, int act, int addC)
{
    constexpr int MT = BM / WM / 16;
    constexpr int NT = BN / WN / 16;
    constexpr int ASL = BM / 16;
    constexpr int BSL = BN / 16;
    constexpr int BITER = (3 * BSL) / 4;
    constexpr int PSH = (BSL == 8) ? 9 : 8;
    __shared__ short Asl[3][ASL * 520];
    __shared__ short Bsl[3][BSL * 512];

    const int tid = threadIdx.x;
    const int w = tid >> 6, lane = tid & 63;
    const int lrow = lane & 15, quad = lane >> 4;
    const int aslab0 = (w % WM) * MT;
    const int bslab0 = (w / WM) * NT;
    const int m0 = blockIdx.y * BM, n0 = blockIdx.x * BN;
    const size_t planeS = (size_t)K * N;

    f32x4 acc[MT][NT] = {};

    for (int k0 = 0; k0 < K; k0 += 32) {
        __syncthreads();
#pragma unroll
        for (int i = 0; i < BM / 32; ++i) {
            int v = tid + 256 * i;
            int row = v >> 3;
            int kq = (v & 7) * 4;
            float4 val = *(const float4*)&A[(size_t)(m0 + row) * lda + k0 + kq];
            int off = (row >> 4) * 520 + (((kq >> 3) << 4) + (row & 15)) * 8 + (kq & 7);
            short h[4], mm_[4], l[4];
            split3(val.x, h[0], mm_[0], l[0]);
            split3(val.y, h[1], mm_[1], l[1]);
            split3(val.z, h[2], mm_[2], l[2]);
            split3(val.w, h[3], mm_[3], l[3]);
            *(short4*)&Asl[0][off] = make_short4(h[0], h[1], h[2], h[3]);
            *(short4*)&Asl[1][off] = make_short4(mm_[0], mm_[1], mm_[2], mm_[3]);
            *(short4*)&Asl[2][off] = make_short4(l[0], l[1], l[2], l[3]);
        }
        {
            const short* wb = Wp + ((size_t)(k0 >> 5) * (N >> 4) + (n0 >> 4)) * 512;
#pragma unroll
            for (int i = 0; i < BITER; ++i) {
                int idx = tid + 256 * i;
                int p = idx >> PSH;
                int r = idx & ((1 << PSH) - 1);
                *(int4*)&Bsl[p][r * 8] = *(const int4*)(wb + p * planeS + r * 8);
            }
        }
        __syncthreads();

        bf16x8 af[3][MT];
#pragma unroll
        for (int p = 0; p < 3; ++p)
#pragma unroll
            for (int i = 0; i < MT; ++i)
                af[p][i] = *(const bf16x8*)&Asl[p][(aslab0 + i) * 520 + lane * 8];

#pragma unroll
        for (int pb = 0; pb < 3; ++pb) {
            bf16x8 bfr[NT];
#pragma unroll
            for (int j = 0; j < NT; ++j)
                bfr[j] = *(const bf16x8*)&Bsl[pb][(bslab0 + j) * 512 + lane * 8];
            const int npa = (pb == 0) ? 3 : (pb == 1 ? 2 : 1);
#pragma unroll
            for (int pa = 0; pa < 3; ++pa) {
                if (pa >= npa) break;
#pragma unroll
                for (int i = 0; i < MT; ++i)
#pragma unroll
                    for (int j = 0; j < NT; ++j)
                        acc[i][j] = __builtin_amdgcn_mfma_f32_16x16x32_bf16(
                            af[pa][i], bfr[j], acc[i][j], 0, 0, 0);
            }
        }
    }

#pragma unroll
    for (int i = 0; i < MT; ++i) {
        int mbase = m0 + (aslab0 + i) * 16 + quad * 4;
#pragma unroll
        for (int j = 0; j < NT; ++j) {
            int n = n0 + (bslab0 + j) * 16 + lrow;
            float bv = bias ? bias[n] : 0.f;
#pragma unroll
            for (int r = 0; r < 4; ++r) {
                size_t off = (size_t)(mbase + r) * ldc + n;
                float v = acc[i][j][r] + bv;
                if (act == 1) v = (v > 20.f) ? v : log1pf(__expf(v));
                if (addC) v += C[off];
                C[off] = v;
            }
        }
    }
}

// ---- split-K variant for x_proj: 64x64 tile, K-chunk per blockIdx.z, partials out ----
__global__ __launch_bounds__(256)
void gemm6sk(const float* __restrict__ A, int lda,
             const float* __restrict__ W, int N,
             float* __restrict__ P, int M, int KC)
{
    constexpr int BM = 64, BN = 64, WM = 2, WN = 2;
    constexpr int MT = BM / WM / 16, NT = BN / WN / 16;
    __shared__ short Asl[3][4 * 520];
    __shared__ short Bsl[3][4 * 520];

    const int tid = threadIdx.x;
    const int w = tid >> 6, lane = tid & 63;
    const int lrow = lane & 15, quad = lane >> 4;
    const int aslab0 = (w % WM) * MT;
    const int bslab0 = (w / WM) * NT;
    const int m0 = blockIdx.y * BM, n0 = blockIdx.x * BN;
    const int kbeg = blockIdx.z * KC;

    f32x4 acc[MT][NT] = {};

    for (int k0 = kbeg; k0 < kbeg + KC; k0 += 32) {
        __syncthreads();
#pragma unroll
        for (int i = 0; i < BM / 32; ++i) {
            int v = tid + 256 * i;
            int row = v >> 3;
            int kq = (v & 7) * 4;
            float4 val = *(const float4*)&A[(size_t)(m0 + row) * lda + k0 + kq];
            int off = (row >> 4) * 520 + (((kq >> 3) << 4) + (row & 15)) * 8 + (kq & 7);
            short h[4], mm_[4], l[4];
            split3(val.x, h[0], mm_[0], l[0]);
            split3(val.y, h[1], mm_[1], l[1]);
            split3(val.z, h[2], mm_[2], l[2]);
            split3(val.w, h[3], mm_[3], l[3]);
            *(short4*)&Asl[0][off] = make_short4(h[0], h[1], h[2], h[3]);
            *(short4*)&Asl[1][off] = make_short4(mm_[0], mm_[1], mm_[2], mm_[3]);
            *(short4*)&Asl[2][off] = make_short4(l[0], l[1], l[2], l[3]);
        }
        {
            int v = tid;
            int kp = v >> 4;
            int nc = (v & 15) * 4;
            int k1 = kp * 2;
            float4 r0 = *(const float4*)&W[(size_t)(k0 + k1) * N + n0 + nc];
            float4 r1 = *(const float4*)&W[(size_t)(k0 + k1 + 1) * N + n0 + nc];
            const float e0[4] = {r0.x, r0.y, r0.z, r0.w};
            const float e1[4] = {r1.x, r1.y, r1.z, r1.w};
#pragma unroll
            for (int e = 0; e < 4; ++e) {
                int n = nc + e;
                int off = (n >> 4) * 520 + (((k1 >> 3) << 4) + (n & 15)) * 8 + (k1 & 7);
                short h0, m0_, l0, h1, m1_, l1;
                split3(e0[e], h0, m0_, l0);
                split3(e1[e], h1, m1_, l1);
                *(short2*)&Bsl[0][off] = make_short2(h0, h1);
                *(short2*)&Bsl[1][off] = make_short2(m0_, m1_);
                *(short2*)&Bsl[2][off] = make_short2(l0, l1);
            }
        }
        __syncthreads();

        bf16x8 af[3][MT];
#pragma unroll
        for (int p = 0; p < 3; ++p)
#pragma unroll
            for (int i = 0; i < MT; ++i)
                af[p][i] = *(const bf16x8*)&Asl[p][(aslab0 + i) * 520 + lane * 8];

#pragma unroll
        for (int pb = 0; pb < 3; ++pb) {
            bf16x8 bfr[NT];
#pragma unroll
            for (int j = 0; j < NT; ++j)
                bfr[j] = *(const bf16x8*)&Bsl[pb][(bslab0 + j) * 520 + lane * 8];
            const int npa = (pb == 0) ? 3 : (pb == 1 ? 2 : 1);
#pragma unroll
            for (int pa = 0; pa < 3; ++pa) {
                if (pa >= npa) break;
#pragma unroll
                for (int i = 0; i < MT; ++i)
#pragma unroll
                    for (int j = 0; j < NT; ++j)
                        acc[i][j] = __builtin_amdgcn_mfma_f32_16x16x32_bf16(
                            af[pa][i], bfr[j], acc[i][j], 0, 0, 0);
            }
        }
    }

    float* Pz = P + (size_t)blockIdx.z * M * 64;
#pragma unroll
    for (int i = 0; i < MT; ++i) {
        int mbase = m0 + (aslab0 + i) * 16 + quad * 4;
#pragma unroll
        for (int j = 0; j < NT; ++j) {
            int n = n0 + (bslab0 + j) * 16 + lrow;
#pragma unroll
            for (int r = 0; r < 4; ++r)
                Pz[(size_t)(mbase + r) * 64 + n] = acc[i][j][r];
        }
    }
}

// reduce 8 K-chunk partials -> DBL (float4 over 4096x64)
__global__ __launch_bounds__(256)
void xred_k(const float* __restrict__ P, float* __restrict__ D)
{
    int i = blockIdx.x * 256 + threadIdx.x;     // 65536 float4 groups
    const float4* p = (const float4*)P;
    float4 a = p[i];
#pragma unroll
    for (int z = 1; z < 8; ++z) {
        float4 b = p[(size_t)z * 65536 + i];
        a.x += b.x; a.y += b.y; a.z += b.z; a.w += b.w;
    }
    ((float4*)D)[i] = a;
}

// ---------------- RMSNorm -> 3 pre-split bf16 planes ----------------
__global__ __launch_bounds__(256)
void rmsnorm3_k(const float* __restrict__ X, const float* __restrict__ w,
                unsigned short* __restrict__ P0, unsigned short* __restrict__ P1,
                unsigned short* __restrict__ P2)
{
    int wid = threadIdx.x >> 6, lane = threadIdx.x & 63;
    int row = blockIdx.x * 4 + wid;
    const float* xr = X + (size_t)row * DMODEL;
    float v[8];
    float ss = 0.f;
#pragma unroll
    for (int j = 0; j < 8; ++j) { v[j] = xr[lane + 64 * j]; ss = fmaf(v[j], v[j], ss); }
#pragma unroll
    for (int off = 32; off >= 1; off >>= 1) ss += __shfl_xor(ss, off);
    float scale = rsqrtf(ss * (1.f / 512.f) + 1e-5f);
#pragma unroll
    for (int j = 0; j < 8; ++j) {
        int col = lane + 64 * j;
        float val = v[j] * scale * w[col];
        short hh, mm, ll;
        split3(val, hh, mm, ll);
        size_t o = (size_t)row * DMODEL + col;
        P0[o] = (unsigned short)hh;
        P1[o] = (unsigned short)mm;
        P2[o] = (unsigned short)ll;
    }
}

// ---------------- causal depthwise conv (K=4) + SiLU, float4 over d ----------------
__global__ __launch_bounds__(256)
void conv_silu_k(const float* __restrict__ XZ, const float* __restrict__ cw,
                 const float* __restrict__ cb, float* __restrict__ XC)
{
    int idx = blockIdx.x * 256 + threadIdx.x;   // over b*L*256 d-groups
    int d4 = (idx & 255) * 4;
    int t = (idx >> 8) & 511;
    int b = idx >> 17;
    float4 wv[4];
#pragma unroll
    for (int e = 0; e < 4; ++e) wv[e] = *(const float4*)&cw[(d4 + e) * 4];
    float4 bv = *(const float4*)&cb[d4];
    float s[4] = {bv.x, bv.y, bv.z, bv.w};
#pragma unroll
    for (int k = 0; k < 4; ++k) {
        int tt = t + k - 3;
        if (tt >= 0) {
            float4 x = *(const float4*)&XZ[((size_t)(b * 512 + tt)) * 2048 + d4];
            const float xe[4] = {x.x, x.y, x.z, x.w};
            const float we[4] = {wv[0][k], wv[1][k], wv[2][k], wv[3][k]};
#pragma unroll
            for (int e = 0; e < 4; ++e) s[e] = fmaf(we[e], xe[e], s[e]);
        }
    }
    float4 o;
    o.x = s[0] / (1.f + __expf(-s[0]));
    o.y = s[1] / (1.f + __expf(-s[1]));
    o.z = s[2] / (1.f + __expf(-s[2]));
    o.w = s[3] / (1.f + __expf(-s[3]));
    *(float4*)&XC[((size_t)(b * 512 + t)) * 1024 + d4] = o;
}

// ---------------- chunked selective scan: thread per (b,chunk,d), 16 states in regs ----
__global__ __launch_bounds__(128)
void scan1_k(const float* __restrict__ DELTA, const float* __restrict__ XC,
             const float* __restrict__ DBL, const float* __restrict__ A_log,
             const float* __restrict__ Dsk, float* __restrict__ Y,
             float* __restrict__ SC, float* __restrict__ DS)
{
    __shared__ float BC[64][32];       // [t][0:16)=B, [16:32)=C  (broadcast reads)
    const int tid = threadIdx.x;
    const int d = blockIdx.x * 128 + tid;
    const int chunk = blockIdx.y;
    const int b = blockIdx.z;
    const int t0 = chunk * 64;

#pragma unroll
    for (int i = 0; i < 16; ++i) {
        int idx = tid + 128 * i;
        int t = idx >> 5, j = idx & 31;
        BC[t][j] = DBL[(size_t)(b * 512 + t0 + t) * 64 + 32 + j];
    }
    float Ac[16];
#pragma unroll
    for (int n = 0; n < 16; ++n) Ac[n] = -__expf(A_log[d * 16 + n]);
    float Dv = Dsk[d];
    __syncthreads();

    const float* dp = DELTA + ((size_t)(b * 512 + t0)) * 1024 + d;
    const float* up = XC    + ((size_t)(b * 512 + t0)) * 1024 + d;
    float* yp       = Y     + ((size_t)(b * 512 + t0)) * 1024 + d;

    float h[16];
#pragma unroll
    for (int n = 0; n < 16; ++n) h[n] = 0.f;
    float dsum = 0.f;

#pragma unroll 2
    for (int t = 0; t < 64; ++t) {
        float delta = dp[t * 1024];
        float u = up[t * 1024];
        dsum += delta;
        float du = delta * u;
        float y = 0.f;
#pragma unroll
        for (int n = 0; n < 16; ++n) {
            h[n] = fmaf(__expf(delta * Ac[n]), h[n], du * BC[t][n]);
            y = fmaf(h[n], BC[t][16 + n], y);
        }
        yp[t * 1024] = fmaf(u, Dv, y);
    }

    float* sc = SC + ((size_t)((b * 8 + chunk) * 1024 + d)) * 16;
#pragma unroll
    for (int n = 0; n < 16; ++n) sc[n] = h[n];
    DS[(size_t)(b * 8 + chunk) * 1024 + d] = dsum;
}

__global__ __launch_bounds__(256)
void scan2_k(const float* __restrict__ A_log, float* __restrict__ SC,
             const float* __restrict__ DS)
{
    int gid = blockIdx.x * 256 + threadIdx.x;   // b*16384 + d*16 + n
    int n = gid & 15;
    int d = (gid >> 4) & 1023;
    int b = gid >> 14;
    float Ac = -__expf(A_log[d * 16 + n]);
    float carry = 0.f;
#pragma unroll
    for (int c = 0; c < 8; ++c) {
        size_t off = ((size_t)((b * 8 + c) * 1024 + d)) * 16 + n;
        float s = SC[off];
        SC[off] = carry;
        carry = fmaf(__expf(Ac * DS[(size_t)(b * 8 + c) * 1024 + d]), carry, s);
    }
}

__global__ __launch_bounds__(128)
void scan3_k(const float* __restrict__ DELTA, const float* __restrict__ DBL,
             const float* __restrict__ A_log, const float* __restrict__ H0,
             const float* __restrict__ XZ, float* __restrict__ Y)
{
    __shared__ float Cs[64][16];
    const int tid = threadIdx.x;
    const int d = blockIdx.x * 128 + tid;
    const int chunk = blockIdx.y;
    const int b = blockIdx.z;
    const int t0 = chunk * 64;

#pragma unroll
    for (int i = 0; i < 8; ++i) {
        int idx = tid + 128 * i;
        int t = idx >> 4, j = idx & 15;
        Cs[t][j] = DBL[(size_t)(b * 512 + t0 + t) * 64 + 48 + j];
    }
    float Ac[16], h0[16];
#pragma unroll
    for (int n = 0; n < 16; ++n) Ac[n] = -__expf(A_log[d * 16 + n]);
    const float* h0p = H0 + ((size_t)((b * 8 + chunk) * 1024 + d)) * 16;
#pragma unroll
    for (int n = 0; n < 16; ++n) h0[n] = h0p[n];
    __syncthreads();

    const float* dp = DELTA + ((size_t)(b * 512 + t0)) * 1024 + d;
    const float* zp = XZ    + ((size_t)(b * 512 + t0)) * 2048 + 1024 + d;
    float* yp       = Y     + ((size_t)(b * 512 + t0)) * 1024 + d;

    float cum = 0.f;
    if (chunk == 0) {
#pragma unroll 2
        for (int t = 0; t < 64; ++t) {
            float z = zp[t * 2048];
            yp[t * 1024] *= z / (1.f + __expf(-z));
        }
    } else {
#pragma unroll 2
        for (int t = 0; t < 64; ++t) {
            float delta = dp[t * 1024];
            cum += delta;
            float p = 0.f;
#pragma unroll
            for (int n = 0; n < 16; ++n)
                p = fmaf(h0[n] * __expf(Ac[n] * cum), Cs[t][n], p);
            float z = zp[t * 2048];
            float yv = yp[t * 1024] + p;
            yp[t * 1024] = yv * (z / (1.f + __expf(-z)));
        }
    }
}

// ---------------- MFMA flash attention, exact fp32 via bf16x6 ----------------
__global__ __launch_bounds__(256, 1)
void attn_mfma(const float* __restrict__ Qm, const float* __restrict__ Km,
               const float* __restrict__ Vm, float* __restrict__ CTX)
{
    __shared__ short KVs[3][16 * 520];      // 16 frag-tiles per plane
    __shared__ float Ps[4][16 * 260];       // per-wave P strip (16 q x 256 kv, pad 260)
    const int tid = threadIdx.x;
    const int w = tid >> 6, lane = tid & 63;
    const int lrow = lane & 15, quad = lane >> 4;
    const int b = blockIdx.z, h = blockIdx.y;
    const int qw = blockIdx.x * 64 + w * 16;

    bf16x8 qf[3][4];
    {
        const float* qp = Qm + ((size_t)(b * 512 + qw + lrow)) * 512 + h * 128 + quad * 8;
#pragma unroll
        for (int kb = 0; kb < 4; ++kb) {
            float4 v0 = *(const float4*)(qp + kb * 32);
            float4 v1 = *(const float4*)(qp + kb * 32 + 4);
            const float e[8] = {v0.x, v0.y, v0.z, v0.w, v1.x, v1.y, v1.z, v1.w};
#pragma unroll
            for (int j = 0; j < 8; ++j) {
                short hh, mm, ll;
                split3(e[j], hh, mm, ll);
                qf[0][kb][j] = hh; qf[1][kb][j] = mm; qf[2][kb][j] = ll;
            }
        }
    }

    const int sdd = (tid & 31) * 4;
    const int skvb = tid >> 5;
    f32x4 sa[4][4] = {};

    float4 kpre[8];
#pragma unroll
    for (int i = 0; i < 8; ++i)
        kpre[i] = *(const float4*)&Km[((size_t)(b * 256 + skvb + 8 * i)) * 512 + h * 128 + sdd];

    for (int c = 0; c < 4; ++c) {
        if (c) __syncthreads();
        {
            const int kb = sdd >> 5, qd = (sdd >> 3) & 3, jd = sdd & 7;
#pragma unroll
            for (int i = 0; i < 8; ++i) {
                int kv = skvb + 8 * i;
                int off = ((kv >> 4) * 4 + kb) * 520 + ((kv & 15) + 16 * qd) * 8 + jd;
                short h0,m0,l0,h1,m1,l1,h2,m2,l2,h3,m3,l3;
                split3(kpre[i].x,h0,m0,l0); split3(kpre[i].y,h1,m1,l1);
                split3(kpre[i].z,h2,m2,l2); split3(kpre[i].w,h3,m3,l3);
                *(short4*)&KVs[0][off] = make_short4(h0,h1,h2,h3);
                *(short4*)&KVs[1][off] = make_short4(m0,m1,m2,m3);
                *(short4*)&KVs[2][off] = make_short4(l0,l1,l2,l3);
            }
        }
        if (c < 3) {
#pragma unroll
            for (int i = 0; i < 8; ++i)
                kpre[i] = *(const float4*)&Km[((size_t)(b * 256 + (c + 1) * 64 + skvb + 8 * i)) * 512 + h * 128 + sdd];
        }
        __syncthreads();
#pragma unroll
        for (int s = 0; s < 4; ++s) {
#pragma unroll
            for (int kb = 0; kb < 4; ++kb) {
                bf16x8 kf[3];
#pragma unroll
                for (int p = 0; p < 3; ++p)
                    kf[p] = *(const bf16x8*)&KVs[p][(s * 4 + kb) * 520 + lane * 8];
                sa[c][s] = __builtin_amdgcn_mfma_f32_16x16x32_bf16(qf[0][kb], kf[0], sa[c][s], 0, 0, 0);
                sa[c][s] = __builtin_amdgcn_mfma_f32_16x16x32_bf16(qf[0][kb], kf[1], sa[c][s], 0, 0, 0);
                sa[c][s] = __builtin_amdgcn_mfma_f32_16x16x32_bf16(qf[1][kb], kf[0], sa[c][s], 0, 0, 0);
                sa[c][s] = __builtin_amdgcn_mfma_f32_16x16x32_bf16(qf[0][kb], kf[2], sa[c][s], 0, 0, 0);
                sa[c][s] = __builtin_amdgcn_mfma_f32_16x16x32_bf16(qf[1][kb], kf[1], sa[c][s], 0, 0, 0);
                sa[c][s] = __builtin_amdgcn_mfma_f32_16x16x32_bf16(qf[2][kb], kf[0], sa[c][s], 0, 0, 0);
            }
        }
    }

    const float scale = 0.08838834764831845f;
    float mx[4] = {-1e30f, -1e30f, -1e30f, -1e30f};
#pragma unroll
    for (int c = 0; c < 4; ++c)
#pragma unroll
        for (int s = 0; s < 4; ++s)
#pragma unroll
            for (int r = 0; r < 4; ++r) {
                sa[c][s][r] *= scale;
                mx[r] = fmaxf(mx[r], sa[c][s][r]);
            }
#pragma unroll
    for (int r = 0; r < 4; ++r) {
        mx[r] = fmaxf(mx[r], __shfl_xor(mx[r], 1));
        mx[r] = fmaxf(mx[r], __shfl_xor(mx[r], 2));
        mx[r] = fmaxf(mx[r], __shfl_xor(mx[r], 4));
        mx[r] = fmaxf(mx[r], __shfl_xor(mx[r], 8));
    }
    float sum[4] = {0.f, 0.f, 0.f, 0.f};
#pragma unroll
    for (int c = 0; c < 4; ++c)
#pragma unroll
        for (int s = 0; s < 4; ++s)
#pragma unroll
            for (int r = 0; r < 4; ++r) {
                float e = __expf(sa[c][s][r] - mx[r]);
                sa[c][s][r] = e;
                sum[r] += e;
            }
#pragma unroll
    for (int r = 0; r < 4; ++r) {
        sum[r] += __shfl_xor(sum[r], 1);
        sum[r] += __shfl_xor(sum[r], 2);
        sum[r] += __shfl_xor(sum[r], 4);
        sum[r] += __shfl_xor(sum[r], 8);
        sum[r] = 1.f / sum[r];
    }
    {
        float* ps = &Ps[w][0];
#pragma unroll
        for (int c = 0; c < 4; ++c)
#pragma unroll
            for (int s = 0; s < 4; ++s)
#pragma unroll
                for (int r = 0; r < 4; ++r)
                    ps[(quad * 4 + r) * 260 + c * 64 + s * 16 + lrow] = sa[c][s][r] * sum[r];
    }

    const int vdd4 = (tid & 31) * 4;
    const int vkvg = tid >> 5;
    f32x4 oa[8] = {};
    float4 vpre[8];
#pragma unroll
    for (int i = 0; i < 2; ++i) {
        int kv0 = (vkvg + 8 * i) * 4;
#pragma unroll
        for (int rr = 0; rr < 4; ++rr)
            vpre[i * 4 + rr] = *(const float4*)&Vm[((size_t)(b * 256 + kv0 + rr)) * 512 + h * 128 + vdd4];
    }

    for (int c = 0; c < 4; ++c) {
        __syncthreads();
        {
#pragma unroll
            for (int i = 0; i < 2; ++i) {
                int kv0 = (vkvg + 8 * i) * 4;
                int kb2 = kv0 >> 5, qk = (kv0 >> 3) & 3, jb = kv0 & 7;
                const float4 r0 = vpre[i * 4 + 0], r1 = vpre[i * 4 + 1];
                const float4 r2 = vpre[i * 4 + 2], r3 = vpre[i * 4 + 3];
                const float ve[4][4] = {{r0.x, r1.x, r2.x, r3.x},
                                        {r0.y, r1.y, r2.y, r3.y},
                                        {r0.z, r1.z, r2.z, r3.z},
                                        {r0.w, r1.w, r2.w, r3.w}};
#pragma unroll
                for (int e = 0; e < 4; ++e) {
                    int dd = vdd4 + e;
                    int off = ((dd >> 4) * 2 + kb2) * 520 + ((dd & 15) + 16 * qk) * 8 + jb;
                    short h0,m0,l0,h1,m1,l1,h2,m2,l2,h3,m3,l3;
                    split3(ve[e][0],h0,m0,l0); split3(ve[e][1],h1,m1,l1);
                    split3(ve[e][2],h2,m2,l2); split3(ve[e][3],h3,m3,l3);
                    *(short4*)&KVs[0][off] = make_short4(h0,h1,h2,h3);
                    *(short4*)&KVs[1][off] = make_short4(m0,m1,m2,m3);
                    *(short4*)&KVs[2][off] = make_short4(l0,l1,l2,l3);
                }
            }
        }
        if (c < 3) {
#pragma unroll
            for (int i = 0; i < 2; ++i) {
                int kv0 = (vkvg + 8 * i) * 4;
#pragma unroll
                for (int rr = 0; rr < 4; ++rr)
                    vpre[i * 4 + rr] = *(const float4*)&Vm[((size_t)(b * 256 + (c + 1) * 64 + kv0 + rr)) * 512 + h * 128 + vdd4];
            }
        }
        __syncthreads();
#pragma unroll
        for (int kb2 = 0; kb2 < 2; ++kb2) {
            const float* pp = &Ps[w][lrow * 260 + c * 64 + kb2 * 32 + quad * 8];
            float4 a0 = *(const float4*)pp;
            float4 a1 = *(const float4*)(pp + 4);
            const float e[8] = {a0.x, a0.y, a0.z, a0.w, a1.x, a1.y, a1.z, a1.w};
            bf16x8 af[3];
#pragma unroll
            for (int j = 0; j < 8; ++j) {
                short hh, mm, ll;
                split3(e[j], hh, mm, ll);
                af[0][j] = hh; af[1][j] = mm; af[2][j] = ll;
            }
#pragma unroll
            for (int s = 0; s < 8; ++s) {
                bf16x8 vf[3];
#pragma unroll
                for (int p = 0; p < 3; ++p)
                    vf[p] = *(const bf16x8*)&KVs[p][(s * 2 + kb2) * 520 + lane * 8];
                oa[s] = __builtin_amdgcn_mfma_f32_16x16x32_bf16(af[0], vf[0], oa[s], 0, 0, 0);
                oa[s] = __builtin_amdgcn_mfma_f32_16x16x32_bf16(af[0], vf[1], oa[s], 0, 0, 0);
                oa[s] = __builtin_amdgcn_mfma_f32_16x16x32_bf16(af[1], vf[0], oa[s], 0, 0, 0);
                oa[s] = __builtin_amdgcn_mfma_f32_16x16x32_bf16(af[0], vf[2], oa[s], 0, 0, 0);
                oa[s] = __builtin_amdgcn_mfma_f32_16x16x32_bf16(af[1], vf[1], oa[s], 0, 0, 0);
                oa[s] = __builtin_amdgcn_mfma_f32_16x16x32_bf16(af[2], vf[0], oa[s], 0, 0, 0);
            }
        }
    }

#pragma unroll
    for (int s = 0; s < 8; ++s)
#pragma unroll
        for (int r = 0; r < 4; ++r)
            CTX[((size_t)(b * 512 + qw + quad * 4 + r)) * 512 + h * 128 + s * 16 + lrow] = oa[s][r];
}

// ---------------- final linear (512->6) + argmax, one wave per row ----------------
__global__ __launch_bounds__(256)
void head_k(const float* __restrict__ T2, const float* __restrict__ Wout,
            const float* __restrict__ bout, float* __restrict__ out)
{
    int wid = threadIdx.x >> 6, lane = threadIdx.x & 63;
    int row = blockIdx.x * 4 + wid;
    float acc[6] = {0.f, 0.f, 0.f, 0.f, 0.f, 0.f};
    const float* tr = T2 + (size_t)row * 512;
#pragma unroll
    for (int j = 0; j < 8; ++j) {
        int k = lane + 64 * j;
        float t = tr[k];
#pragma unroll
        for (int c = 0; c < 6; ++c) acc[c] = fmaf(t, Wout[k * 6 + c], acc[c]);
    }
#pragma unroll
    for (int c = 0; c < 6; ++c) {
#pragma unroll
        for (int off = 32; off >= 1; off >>= 1) acc[c] += __shfl_xor(acc[c], off);
    }
    if (lane == 0) {
        float best = -1e30f;
        int bi = 0;
#pragma unroll
        for (int c = 0; c < 6; ++c) {
            float v = acc[c] + bout[c];
            out[(size_t)row * 6 + c] = v;
            if (v > best) { best = v; bi = c; }
        }
        out[(size_t)4096 * 6 + row] = (float)bi;
    }
}

extern "C" void kernel_launch(void* const* d_in, const int* in_sizes, int n_in,
                              void* d_out, int out_size, void* d_ws, size_t ws_size,
                              hipStream_t stream)
{
    (void)in_sizes; (void)n_in; (void)out_size; (void)ws_size;
    const float* agent      = (const float*)d_in[0];
    const float* lane       = (const float*)d_in[1];
    const float* lane_in_W  = (const float*)d_in[2];
    const float* lane_in_b  = (const float*)d_in[3];
    const float* norm_w     = (const float*)d_in[4];
    const float* in_proj_W  = (const float*)d_in[5];
    const float* conv_w     = (const float*)d_in[6];
    const float* conv_b     = (const float*)d_in[7];
    const float* x_proj_W   = (const float*)d_in[8];
    const float* dt_proj_W  = (const float*)d_in[9];
    const float* dt_proj_b  = (const float*)d_in[10];
    const float* A_log      = (const float*)d_in[11];
    const float* D_skip     = (const float*)d_in[12];
    const float* out_proj_W = (const float*)d_in[13];
    const float* final_norm_w = (const float*)d_in[14];
    const float* Wq = (const float*)d_in[15];
    const float* Wk = (const float*)d_in[16];
    const float* Wv = (const float*)d_in[17];
    const float* Wo = (const float*)d_in[18];
    const float* bq = (const float*)d_in[19];
    const float* bk = (const float*)d_in[20];
    const float* bv = (const float*)d_in[21];
    const float* bo = (const float*)d_in[22];
    const float* lin_in_W  = (const float*)d_in[23];
    const float* lin_in_b  = (const float*)d_in[24];
    const float* lin_out_W = (const float*)d_in[25];
    const float* lin_out_b = (const float*)d_in[26];

    // Workspace: same 97 MB footprint (rounds 1/3-9). JIT weight planes alias XC
    // (dead at each use point); T2 moved to DELTA so MHA Wp's can live in XC.
    float* ws = (float*)d_ws;
    float* X     = ws;                      // 2M floats (4096 x 512)
    float* H     = X + (1 << 21);           // 2M
    float* XZ    = H + (1 << 21);           // 8M  (4096 x 2048)
    float* XC    = XZ + (1 << 23);          // 4M  (4096 x 1024)
    float* DELTA = XC + (1 << 22);          // 4M
    float* Y     = DELTA + (1 << 22);       // 4M
    float* DBL   = Y + (1 << 22);           // 256K (4096 x 64)
    // aliases with disjoint lifetimes:
    unsigned short* Hp0 = (unsigned short*)H;               // rmsnorm planes
    unsigned short* Hp1 = (unsigned short*)(H + (1 << 20));
    unsigned short* Hp2 = (unsigned short*)Y;               // dead until scan1
    float* PART  = Y + (1 << 20);           // x_proj split-K partials (8MB)
    float* SCb   = H;                       // scan phase
    float* DSb   = H + (1 << 20);
    short* WPL   = (short*)XC;              // JIT weight planes (<=8MB of 16MB region)
    float* Qb  = XZ;                        // MHA phase
    float* Kb  = XZ + (1 << 21);
    float* Vb  = Kb + (1 << 20);
    float* CTX = Vb + (1 << 20);
    float* AO  = CTX + (1 << 21);
    float* T2  = DELTA;                     // MHA phase (DELTA dead after scans)

    dim3 blk(256);
    dim3 sblk(128);
    dim3 sgrid(8, 8, 8);                    // (d-group, chunk, b)

    // x = lane_features @ lane_in_W + b   (4096x128 @ 128x512)
    wsplit_k<<<32, blk, 0, stream>>>(lane_in_W, WPL, 128, 512);
    gemm6g<128, 64, 2, 2><<<dim3(8, 32), blk, 0, stream>>>(
        lane, 128, WPL, lane_in_b, X, 512, 4096, 512, 128, 0, 0);

    for (int i = 0; i < 4; ++i) {
        rmsnorm3_k<<<1024, blk, 0, stream>>>(X, norm_w + i * 512, Hp0, Hp1, Hp2);
        // xz = h @ in_proj  (4096x512 @ 512x2048): JIT W presplit -> pure-copy staging
        wsplit_k<<<512, blk, 0, stream>>>(in_proj_W + (size_t)i * 512 * 2048, WPL, 512, 2048);
        gemm6f<128, 128, 2, 2><<<dim3(16, 32), blk, 0, stream>>>(
            Hp0, Hp1, Hp2, 512, WPL, nullptr, XZ, 2048, 4096, 2048, 512, 0, 0);
        conv_silu_k<<<4096, blk, 0, stream>>>(XZ, conv_w + i * 4096, conv_b + i * 1024, XC);
        // dbl = xc @ x_proj: split-K over 8 chunks + reduce
        gemm6sk<<<dim3(1, 64, 8), blk, 0, stream>>>(
            XC, 1024, x_proj_W + (size_t)i * 1024 * 64, 64, PART, 4096, 128);
        xred_k<<<256, blk, 0, stream>>>(PART, DBL);
        // delta = softplus(dt @ dt_proj + b)  (4096x32 @ 32x1024)
        gemm6<128, 64, 2, 2><<<dim3(16, 32), blk, 0, stream>>>(
            DBL, 64, dt_proj_W + (size_t)i * 32 * 1024, dt_proj_b + i * 1024,
            DELTA, 1024, 4096, 1024, 32, 1, 0);
        // chunked scan (3 phases) + fused gating
        scan1_k<<<sgrid, sblk, 0, stream>>>(DELTA, XC, DBL, A_log + (size_t)i * 1024 * 16,
                                            D_skip + i * 1024, Y, SCb, DSb);
        scan2_k<<<512, blk, 0, stream>>>(A_log + (size_t)i * 1024 * 16, SCb, DSb);
        // XC dead after scan1 -> presplit out_proj W there
        wsplit_k<<<256, blk, 0, stream>>>(out_proj_W + (size_t)i * 1024 * 512, WPL, 1024, 512);
        scan3_k<<<sgrid, sblk, 0, stream>>>(DELTA, DBL, A_log + (size_t)i * 1024 * 16,
                                            SCb, XZ, Y);
        // x += ygated @ out_proj  (4096x1024 @ 1024x512): 512 blocks, B pre-split
        gemm6g<64, 64, 2, 2><<<dim3(8, 64), blk, 0, stream>>>(
            Y, 1024, WPL, nullptr, X, 512, 4096, 512, 1024, 0, 1);
    }

    rmsnorm3_k<<<1024, blk, 0, stream>>>(X, final_norm_w, Hp0, Hp1, Hp2);   // enhanced

    // MHA weight presplits into XC (free; T2 lives in DELTA now)
    short* WPq = WPL;
    short* WPk = WPL + 786432;
    short* WPv = WPL + 2 * 786432;
    short* WPo = WPL + 3 * 786432;
    short* WPn = WPL + 4 * 786432;
    wsplit_k<<<128, blk, 0, stream>>>(Wq, WPq, 512, 512);
    wsplit_k<<<128, blk, 0, stream>>>(Wk, WPk, 512, 512);
    wsplit_k<<<128, blk, 0, stream>>>(Wv, WPv, 512, 512);
    wsplit_k<<<128, blk, 0, stream>>>(Wo, WPo, 512, 512);
    wsplit_k<<<128, blk, 0, stream>>>(lin_in_W, WPn, 512, 512);

    gemm6f<128, 64, 2, 2><<<dim3(8, 32), blk, 0, stream>>>(
        Hp0, Hp1, Hp2, 512, WPq, bq, Qb, 512, 4096, 512, 512, 0, 0);
    gemm6g<64, 64, 2, 2><<<dim3(8, 32), blk, 0, stream>>>(
        agent, 512, WPk, bk, Kb, 512, 2048, 512, 512, 0, 0);
    gemm6g<64, 64, 2, 2><<<dim3(8, 32), blk, 0, stream>>>(
        agent, 512, WPv, bv, Vb, 512, 2048, 512, 512, 0, 0);
    attn_mfma<<<dim3(8, 4, 8), blk, 0, stream>>>(Qb, Kb, Vb, CTX);
    gemm6g<64, 64, 2, 2><<<dim3(8, 64), blk, 0, stream>>>(
        CTX, 512, WPo, bo, AO, 512, 4096, 512, 512, 0, 0);
    gemm6g<64, 64, 2, 2><<<dim3(8, 64), blk, 0, stream>>>(
        AO, 512, WPn, lin_in_b, T2, 512, 4096, 512, 512, 0, 0);
    head_k<<<1024, blk, 0, stream>>>(T2, lin_out_W, lin_out_b, (float*)d_out);
}